// Round 9
// baseline (1927.913 us; speedup 1.0000x reference)
//
#include <hip/hip_runtime.h>
#include <hip/hip_bf16.h>

#define NBUS    1024
#define BATCHSZ 4096
#define NNODES  (NBUS*BATCHSZ)      // 4194304 = 2^22
#define NEDGES  (4*NNODES)          // 16777216
#define FIN     7
#define FF1     12
#define FF2     12
#define HIDD    128
#define KDIM    (NBUS*FF2)          // 12288
#define ODIM    (NBUS*2)            // 2048
#define NBKT    4096                // buckets of 1024 dst nodes
#define CAP     4608                // bucket capacity (mean 4096 + 8 sigma)

#define SZ_YP   ((size_t)NNODES * 16 * 2)               // 134,217,728 (xb -> y1p)
#define SZ_HB   ((size_t)NNODES * FF1 * 2)              // 100,663,296 (h1b -> h2b)
#define SZ_HID  ((size_t)BATCHSZ * HIDD * sizeof(float))//   2,097,152
#define SZ_BB   (SZ_HB + 9 * SZ_HID)                    // h2b + hidp(8) + hid
#define SZ_E    ((size_t)NBKT * CAP * sizeof(unsigned)) //  75,497,472
#define SZ_OFF  ((size_t)NNODES * sizeof(int))          //  16,777,216

typedef unsigned u32x2v  __attribute__((ext_vector_type(2)));

__device__ __forceinline__ float bflo(unsigned p){ return __uint_as_float(p << 16); }
__device__ __forceinline__ float bfhi(unsigned p){ return __uint_as_float(p & 0xffff0000u); }
__device__ __forceinline__ unsigned short f2bf(float f) {
    unsigned u = __float_as_uint(f);
    return (unsigned short)((u + 0x7fffu + ((u >> 16) & 1u)) >> 16);
}
__device__ __forceinline__ void nts_u2(unsigned* p, unsigned a, unsigned b) {
    u32x2v w; w.x = a; w.y = b;
    __builtin_nontemporal_store(w, (u32x2v*)p);
}

// ---------------------------------------------------------------------------
__global__ void k_diag(float* __restrict__ out, int n, float v) {
    size_t i = (size_t)blockIdx.x * blockDim.x + threadIdx.x;
    if (i < (size_t)n) out[i] = v;
}

__global__ void k_detect(const int* __restrict__ w, int* __restrict__ flag) {
    __shared__ int any;
    if (threadIdx.x == 0) any = 0;
    __syncthreads();
    int acc = 0;
    #pragma unroll
    for (int u = 0; u < 4; ++u) acc |= w[1 + 2 * (threadIdx.x * 4 + u)];
    if (acc) atomicOr(&any, 1);
    __syncthreads();
    if (threadIdx.x == 0) *flag = (any == 0) ? 2 : 1;
}

__global__ void k_binit(int* __restrict__ bcur) {
    int u = blockIdx.x * 256 + threadIdx.x;
    if (u < NBKT) bcur[u] = u * CAP;
}

// ---------------------------------------------------------------------------
// partition into fixed-capacity bucket slots; bcur[bk] ends at bucket end.
// 128 blocks x 131072 edges -> 32-edge (128B) runs per bucket per block.
__global__ __launch_bounds__(512) void k_bpart(const int* __restrict__ ei,
                                               const int* __restrict__ flag,
                                               int* __restrict__ bcur,
                                               unsigned* __restrict__ ebuf) {
    __shared__ int hist[NBKT];
    __shared__ int lbase[NBKT];
    for (int u = threadIdx.x; u < NBKT; u += 512) hist[u] = 0;
    __syncthreads();
    int mult = *flag;
    size_t base = (size_t)blockIdx.x * 131072;         // 128 blocks
    #pragma unroll 4
    for (int u = 0; u < 256; ++u) {
        size_t e = base + (size_t)u * 512 + threadIdx.x;
        int d = __builtin_nontemporal_load(ei + ((size_t)NEDGES + e) * mult);
        atomicAdd(&hist[d >> 10], 1);
    }
    __syncthreads();
    for (int u = threadIdx.x; u < NBKT; u += 512) {
        int c = hist[u];
        lbase[u] = c ? atomicAdd(&bcur[u], c) : 0;
        hist[u] = 0;
    }
    __syncthreads();
    #pragma unroll 4
    for (int u = 0; u < 256; ++u) {
        size_t e = base + (size_t)u * 512 + threadIdx.x;
        int s = __builtin_nontemporal_load(ei + e * mult);
        int d = __builtin_nontemporal_load(ei + ((size_t)NEDGES + e) * mult);
        int bk = d >> 10;
        int pos = lbase[bk] + atomicAdd(&hist[bk], 1);
        if (pos < (bk + 1) * CAP)
            ebuf[pos] = ((unsigned)s << 10) | (unsigned)(d & 1023);
    }
}

// ---------------------------------------------------------------------------
// per-bucket counting sort by dstLocal; ebuf becomes src-only sorted by dst.
__global__ __launch_bounds__(256) void k_bsort(const int* __restrict__ bend,
                                               unsigned* __restrict__ ebuf,
                                               int* __restrict__ off) {
    __shared__ unsigned stage[CAP];        // 18KB
    __shared__ int hist[1024];
    __shared__ int wsum[4];
    int t = threadIdx.x;
    int bk = blockIdx.x;
    int ebeg = bk * CAP;
    int n = bend[bk] - ebeg;
    if (n > CAP) n = CAP;
    for (int k = t; k < n; k += 256) stage[k] = __builtin_nontemporal_load(ebuf + ebeg + k);
    for (int u = t; u < 1024; u += 256) hist[u] = 0;
    __syncthreads();
    for (int k = t; k < n; k += 256) atomicAdd(&hist[stage[k] & 1023u], 1);
    __syncthreads();
    int v[4]; int s = 0;
    #pragma unroll
    for (int u = 0; u < 4; ++u) { v[u] = hist[t * 4 + u]; s += v[u]; }
    int lane = t & 63, w = t >> 6;
    int iv = s;
    for (int o = 1; o < 64; o <<= 1) { int uu = __shfl_up(iv, o); if (lane >= o) iv += uu; }
    if (lane == 63) wsum[w] = iv;
    __syncthreads();
    int basep = 0;
    #pragma unroll
    for (int ww = 0; ww < 4; ++ww) if (ww < w) basep += wsum[ww];
    int run = basep + iv - s;
    #pragma unroll
    for (int u = 0; u < 4; ++u) {
        off[(size_t)bk * 1024 + t * 4 + u] = ebeg + run;
        hist[t * 4 + u] = run;
        run += v[u];
    }
    __syncthreads();
    for (int k = t; k < n; k += 256) {
        unsigned p = stage[k];
        int pos = atomicAdd(&hist[p & 1023u], 1);
        ebuf[ebeg + pos] = p >> 10;
    }
}

// ---------------------------------------------------------------------------
__global__ __launch_bounds__(256) void k_padx(const float* __restrict__ x,
                                              uint4* __restrict__ xb) {
    size_t q = (size_t)blockIdx.x * blockDim.x + threadIdx.x;
    if (q >= NNODES / 4) return;
    const float4* xr = (const float4*)(x + q * 28);
    float v[28];
    #pragma unroll
    for (int u = 0; u < 7; ++u) {
        float4 f = xr[u];
        v[4*u] = f.x; v[4*u+1] = f.y; v[4*u+2] = f.z; v[4*u+3] = f.w;
    }
    #pragma unroll
    for (int n = 0; n < 4; ++n) {
        unsigned short h[8];
        #pragma unroll
        for (int j = 0; j < 7; ++j) h[j] = f2bf(v[7*n + j]);
        h[7] = 0;
        uint4 o;
        o.x = (unsigned)h[0] | ((unsigned)h[1] << 16);
        o.y = (unsigned)h[2] | ((unsigned)h[3] << 16);
        o.z = (unsigned)h[4] | ((unsigned)h[5] << 16);
        o.w = (unsigned)h[6] | ((unsigned)h[7] << 16);
        xb[q * 4 + n] = o;
    }
}

// ---------------------------------------------------------------------------
// conv1: block per bucket; gather xb (16B rows); root also from xb; h1 bf16 out.
__global__ __launch_bounds__(256, 4) void k_conv1(const int* __restrict__ off,
                                                  const int* __restrict__ bend,
                                                  const unsigned* __restrict__ lst,
                                                  const uint4* __restrict__ xb,
                                                  const float* __restrict__ Wrel,
                                                  const float* __restrict__ brel,
                                                  const float* __restrict__ Wroot,
                                                  unsigned* __restrict__ h1b) {
    __shared__ float sWr[FF1 * FIN], sWo[FF1 * FIN], sb[FF1];
    int t = threadIdx.x;
    if (t < FF1 * FIN) { sWr[t] = Wrel[t]; sWo[t] = Wroot[t]; }
    if (t < FF1) sb[t] = brel[t];
    __syncthreads();
    int bk = blockIdx.x;
    int be = bend[bk];
    #pragma unroll
    for (int n = 0; n < 4; ++n) {
        int li = n * 256 + t;
        size_t i = (size_t)bk * 1024 + li;
        int beg = off[i];
        int end = (li == 1023) ? be : off[i + 1];
        float agg[FIN] = {0.f, 0.f, 0.f, 0.f, 0.f, 0.f, 0.f};
        int k = beg;
        for (; k + 1 < end; k += 2) {
            unsigned s0 = __builtin_nontemporal_load(lst + k);
            unsigned s1 = __builtin_nontemporal_load(lst + k + 1);
            uint4 a0 = xb[s0], a1 = xb[s1];
            agg[0] += bflo(a0.x) + bflo(a1.x);
            agg[1] += bfhi(a0.x) + bfhi(a1.x);
            agg[2] += bflo(a0.y) + bflo(a1.y);
            agg[3] += bfhi(a0.y) + bfhi(a1.y);
            agg[4] += bflo(a0.z) + bflo(a1.z);
            agg[5] += bfhi(a0.z) + bfhi(a1.z);
            agg[6] += bflo(a0.w) + bflo(a1.w);
        }
        if (k < end) {
            uint4 a0 = xb[__builtin_nontemporal_load(lst + k)];
            agg[0] += bflo(a0.x); agg[1] += bfhi(a0.x);
            agg[2] += bflo(a0.y); agg[3] += bfhi(a0.y);
            agg[4] += bflo(a0.z); agg[5] += bfhi(a0.z);
            agg[6] += bflo(a0.w);
        }
        uint4 ow = xb[i];
        float xv[FIN] = {bflo(ow.x), bfhi(ow.x), bflo(ow.y), bfhi(ow.y),
                         bflo(ow.z), bfhi(ow.z), bflo(ow.w)};
        unsigned short hh[FF1];
        #pragma unroll
        for (int j = 0; j < FF1; ++j) {
            float h = sb[j];
            #pragma unroll
            for (int q = 0; q < FIN; ++q) h += sWr[j * FIN + q] * agg[q] + sWo[j * FIN + q] * xv[q];
            hh[j] = f2bf(h);
        }
        unsigned* p = h1b + i * 6;
        nts_u2(p,     (unsigned)hh[0] | ((unsigned)hh[1] << 16),
                      (unsigned)hh[2] | ((unsigned)hh[3] << 16));
        nts_u2(p + 2, (unsigned)hh[4] | ((unsigned)hh[5] << 16),
                      (unsigned)hh[6] | ((unsigned)hh[7] << 16));
        nts_u2(p + 4, (unsigned)hh[8] | ((unsigned)hh[9] << 16),
                      (unsigned)hh[10]| ((unsigned)hh[11] << 16));
    }
}

// ---------------------------------------------------------------------------
// stats over bf16 24B rows (N x 12 packed in 6 dwords)
__global__ __launch_bounds__(256) void k_statsb(const unsigned* __restrict__ hb,
                                                double* __restrict__ stats) {
    __shared__ float red[4][FF1], redq[4][FF1];
    int t = threadIdx.x;
    float ps[FF1], pq[FF1];
    #pragma unroll
    for (int j = 0; j < FF1; ++j) { ps[j] = 0.f; pq[j] = 0.f; }
    for (size_t i = (size_t)blockIdx.x * 256 + t; i < NNODES; i += 256 * 256) {
        const uint2* r = (const uint2*)(hb + i * 6);
        uint2 u0 = r[0], u1 = r[1], u2 = r[2];
        float v[FF1] = {bflo(u0.x), bfhi(u0.x), bflo(u0.y), bfhi(u0.y),
                        bflo(u1.x), bfhi(u1.x), bflo(u1.y), bfhi(u1.y),
                        bflo(u2.x), bfhi(u2.x), bflo(u2.y), bfhi(u2.y)};
        #pragma unroll
        for (int j = 0; j < FF1; ++j) { ps[j] += v[j]; pq[j] += v[j] * v[j]; }
    }
    #pragma unroll
    for (int j = 0; j < FF1; ++j)
        for (int o = 1; o < 64; o <<= 1) { ps[j] += __shfl_xor(ps[j], o); pq[j] += __shfl_xor(pq[j], o); }
    int lane = t & 63, wv = t >> 6;
    if (lane == 0) {
        #pragma unroll
        for (int j = 0; j < FF1; ++j) { red[wv][j] = ps[j]; redq[wv][j] = pq[j]; }
    }
    __syncthreads();
    if (t < FF1) {
        float s = red[0][t] + red[1][t] + red[2][t] + red[3][t];
        float q = redq[0][t] + redq[1][t] + redq[2][t] + redq[3][t];
        atomicAdd(&stats[t], (double)s);
        atomicAdd(&stats[FF1 + t], (double)q);
    }
}

// ---------------------------------------------------------------------------
__global__ void k_finalize(const double* __restrict__ stats, const float* __restrict__ g,
                           const float* __restrict__ b, float* __restrict__ ss) {
    int j = threadIdx.x;
    if (j < FF1) {
        double mean = stats[j] * (1.0 / NNODES);
        double var  = stats[FF1 + j] * (1.0 / NNODES) - mean * mean;
        float sc = (float)((double)g[j] / sqrt(var + 1e-5));
        ss[j] = sc;
        ss[FF1 + j] = b[j] - (float)mean * sc;
    }
}

// ---------------------------------------------------------------------------
// y1p = relu(bn1(h1b)) as 16 bf16 (32B row, 4 pad); one node per thread.
__global__ __launch_bounds__(256) void k_y1(const unsigned* __restrict__ h1b,
                                            const float* __restrict__ ss,
                                            uint4* __restrict__ y1p) {
    __shared__ float sc[FF1], sh[FF1];
    int t = threadIdx.x;
    if (t < FF1) { sc[t] = ss[t]; sh[t] = ss[FF1 + t]; }
    __syncthreads();
    size_t i = (size_t)blockIdx.x * blockDim.x + t;
    if (i >= NNODES) return;
    const uint2* r = (const uint2*)(h1b + i * 6);
    uint2 u0 = r[0], u1 = r[1], u2 = r[2];
    float v[FF1] = {bflo(u0.x), bfhi(u0.x), bflo(u0.y), bfhi(u0.y),
                    bflo(u1.x), bfhi(u1.x), bflo(u1.y), bfhi(u1.y),
                    bflo(u2.x), bfhi(u2.x), bflo(u2.y), bfhi(u2.y)};
    unsigned short hh[FF1];
    #pragma unroll
    for (int j = 0; j < FF1; ++j) {
        float w = v[j] * sc[j] + sh[j];
        hh[j] = f2bf(w > 0.f ? w : 0.f);
    }
    uint4 w1, w2;
    w1.x = (unsigned)hh[0] | ((unsigned)hh[1] << 16);
    w1.y = (unsigned)hh[2] | ((unsigned)hh[3] << 16);
    w1.z = (unsigned)hh[4] | ((unsigned)hh[5] << 16);
    w1.w = (unsigned)hh[6] | ((unsigned)hh[7] << 16);
    w2.x = (unsigned)hh[8] | ((unsigned)hh[9] << 16);
    w2.y = (unsigned)hh[10]| ((unsigned)hh[11] << 16);
    w2.z = 0u; w2.w = 0u;
    y1p[i * 2]     = w1;
    y1p[i * 2 + 1] = w2;
}

// ---------------------------------------------------------------------------
// conv2: block per bucket; gather y1p (32B rows, no straddle); h2 bf16 out.
__global__ __launch_bounds__(256, 4) void k_conv2(const int* __restrict__ off,
                                                  const int* __restrict__ bend,
                                                  const unsigned* __restrict__ lst,
                                                  const uint4* __restrict__ y1p,
                                                  const float* __restrict__ Wrel,
                                                  const float* __restrict__ brel,
                                                  const float* __restrict__ Wroot,
                                                  unsigned* __restrict__ h2b) {
    __shared__ float sWr[FF2 * FF1], sWo[FF2 * FF1], sb[FF2];
    int t = threadIdx.x;
    if (t < FF2 * FF1) { sWr[t] = Wrel[t]; sWo[t] = Wroot[t]; }
    if (t < FF2) sb[t] = brel[t];
    __syncthreads();
    int bk = blockIdx.x;
    int be = bend[bk];
    #pragma unroll
    for (int n = 0; n < 4; ++n) {
        int li = n * 256 + t;
        size_t i = (size_t)bk * 1024 + li;
        int beg = off[i];
        int end = (li == 1023) ? be : off[i + 1];
        float agg[FF1];
        #pragma unroll
        for (int j = 0; j < FF1; ++j) agg[j] = 0.f;
        int k = beg;
        for (; k + 1 < end; k += 2) {
            unsigned s0 = __builtin_nontemporal_load(lst + k);
            unsigned s1 = __builtin_nontemporal_load(lst + k + 1);
            uint4 a0 = y1p[(size_t)s0 * 2], a1 = y1p[(size_t)s0 * 2 + 1];
            uint4 b0 = y1p[(size_t)s1 * 2], b1 = y1p[(size_t)s1 * 2 + 1];
            agg[0] += bflo(a0.x) + bflo(b0.x); agg[1]  += bfhi(a0.x) + bfhi(b0.x);
            agg[2] += bflo(a0.y) + bflo(b0.y); agg[3]  += bfhi(a0.y) + bfhi(b0.y);
            agg[4] += bflo(a0.z) + bflo(b0.z); agg[5]  += bfhi(a0.z) + bfhi(b0.z);
            agg[6] += bflo(a0.w) + bflo(b0.w); agg[7]  += bfhi(a0.w) + bfhi(b0.w);
            agg[8] += bflo(a1.x) + bflo(b1.x); agg[9]  += bfhi(a1.x) + bfhi(b1.x);
            agg[10]+= bflo(a1.y) + bflo(b1.y); agg[11] += bfhi(a1.y) + bfhi(b1.y);
        }
        if (k < end) {
            unsigned s0 = __builtin_nontemporal_load(lst + k);
            uint4 a0 = y1p[(size_t)s0 * 2], a1 = y1p[(size_t)s0 * 2 + 1];
            agg[0] += bflo(a0.x); agg[1]  += bfhi(a0.x);
            agg[2] += bflo(a0.y); agg[3]  += bfhi(a0.y);
            agg[4] += bflo(a0.z); agg[5]  += bfhi(a0.z);
            agg[6] += bflo(a0.w); agg[7]  += bfhi(a0.w);
            agg[8] += bflo(a1.x); agg[9]  += bfhi(a1.x);
            agg[10]+= bflo(a1.y); agg[11] += bfhi(a1.y);
        }
        uint4 o0 = y1p[i * 2], o1 = y1p[i * 2 + 1];
        float y[FF1] = {bflo(o0.x), bfhi(o0.x), bflo(o0.y), bfhi(o0.y),
                        bflo(o0.z), bfhi(o0.z), bflo(o0.w), bfhi(o0.w),
                        bflo(o1.x), bfhi(o1.x), bflo(o1.y), bfhi(o1.y)};
        unsigned short hh[FF2];
        #pragma unroll
        for (int j = 0; j < FF2; ++j) {
            float h = sb[j];
            #pragma unroll
            for (int q = 0; q < FF1; ++q) h += sWr[j * FF1 + q] * agg[q] + sWo[j * FF1 + q] * y[q];
            hh[j] = f2bf(h);
        }
        unsigned* p = h2b + i * 6;
        nts_u2(p,     (unsigned)hh[0] | ((unsigned)hh[1] << 16),
                      (unsigned)hh[2] | ((unsigned)hh[3] << 16));
        nts_u2(p + 2, (unsigned)hh[4] | ((unsigned)hh[5] << 16),
                      (unsigned)hh[6] | ((unsigned)hh[7] << 16));
        nts_u2(p + 4, (unsigned)hh[8] | ((unsigned)hh[9] << 16),
                      (unsigned)hh[10]| ((unsigned)hh[11] << 16));
    }
}

// ---------------------------------------------------------------------------
// GEMM1: A = relu(bn2(h2b)) bf16-stored, B = W1 f32; split-K=8 partials.
__global__ __launch_bounds__(256) void k_gemm1(const unsigned short* __restrict__ h2b,
                                               const float* __restrict__ ss2,
                                               const float* __restrict__ W1,
                                               float* __restrict__ hidp) {
    __shared__ float As[32][128];
    __shared__ float Bs[32][128];
    __shared__ float sc[FF2], sh[FF2];
    int t = threadIdx.x;
    if (t < FF2) { sc[t] = ss2[t]; sh[t] = ss2[FF2 + t]; }
    __syncthreads();
    int mb = blockIdx.x;
    int ks = blockIdx.y;
    const int KS = KDIM / 8;         // 1536
    int m0 = mb * 128;
    int kbase = ks * KS;
    int r  = t >> 1;
    int kg = t & 1;
    int tr = t >> 4;
    int tc = t & 15;
    float acc[8][8];
    #pragma unroll
    for (int i = 0; i < 8; ++i)
        #pragma unroll
        for (int j = 0; j < 8; ++j) acc[i][j] = 0.f;

    for (int kt = 0; kt < KS; kt += 32) {
        int c0 = kbase + kt + 16 * kg;
        const uint2* arow = (const uint2*)(h2b + (size_t)(m0 + r) * KDIM + c0);
        const float* brow = W1 + (size_t)r * KDIM + c0;
        #pragma unroll
        for (int i = 0; i < 4; ++i) {
            uint2 av = arow[i];
            int cc = c0 + 4 * i;
            int j0 = cc % FF2;
            float vals[4] = {bflo(av.x), bfhi(av.x), bflo(av.y), bfhi(av.y)};
            #pragma unroll
            for (int ii = 0; ii < 4; ++ii) {
                int j = j0 + ii; if (j >= FF2) j -= FF2;
                float v = vals[ii] * sc[j] + sh[j];
                As[16 * kg + 4 * i + ii][r] = v > 0.f ? v : 0.f;
            }
            float4 bv = *(const float4*)(brow + 4 * i);
            Bs[16 * kg + 4 * i + 0][r] = bv.x;
            Bs[16 * kg + 4 * i + 1][r] = bv.y;
            Bs[16 * kg + 4 * i + 2][r] = bv.z;
            Bs[16 * kg + 4 * i + 3][r] = bv.w;
        }
        __syncthreads();
        #pragma unroll
        for (int k = 0; k < 32; ++k) {
            float a[8], b[8];
            *(float4*)&a[0] = *(const float4*)&As[k][8 * tr];
            *(float4*)&a[4] = *(const float4*)&As[k][8 * tr + 4];
            *(float4*)&b[0] = *(const float4*)&Bs[k][8 * tc];
            *(float4*)&b[4] = *(const float4*)&Bs[k][8 * tc + 4];
            #pragma unroll
            for (int i = 0; i < 8; ++i)
                #pragma unroll
                for (int j = 0; j < 8; ++j) acc[i][j] += a[i] * b[j];
        }
        __syncthreads();
    }
    float* obase = hidp + (size_t)ks * (BATCHSZ * HIDD);
    #pragma unroll
    for (int i = 0; i < 8; ++i) {
        float* orow = obase + (size_t)(m0 + 8 * tr + i) * HIDD + 8 * tc;
        *(float4*)(orow)     = make_float4(acc[i][0], acc[i][1], acc[i][2], acc[i][3]);
        *(float4*)(orow + 4) = make_float4(acc[i][4], acc[i][5], acc[i][6], acc[i][7]);
    }
}

__global__ __launch_bounds__(256) void k_hred(const float* __restrict__ hidp,
                                              const float* __restrict__ bl1,
                                              float* __restrict__ hid) {
    int i = blockIdx.x * 256 + threadIdx.x;
    float s = bl1[i & (HIDD - 1)];
    #pragma unroll
    for (int p = 0; p < 8; ++p) s += hidp[(size_t)p * (BATCHSZ * HIDD) + i];
    hid[i] = s > 0.f ? s : 0.f;
}

// ---------------------------------------------------------------------------
__global__ __launch_bounds__(256) void k_gemm2(const float* __restrict__ hid,
                                               const float* __restrict__ W2,
                                               const float* __restrict__ bl2,
                                               float* __restrict__ out) {
    __shared__ float As[32][128];
    __shared__ float Bs[32][128];
    int t = threadIdx.x;
    int m0 = blockIdx.x * 128;
    int n0 = blockIdx.y * 128;
    int r  = t >> 1;
    int kg = t & 1;
    int tr = t >> 4;
    int tc = t & 15;
    float acc[8][8];
    #pragma unroll
    for (int i = 0; i < 8; ++i)
        #pragma unroll
        for (int j = 0; j < 8; ++j) acc[i][j] = 0.f;

    for (int kt = 0; kt < HIDD; kt += 32) {
        int c0 = kt + 16 * kg;
        #pragma unroll
        for (int i = 0; i < 4; ++i) {
            float4 av = *(const float4*)(hid + (size_t)(m0 + r) * HIDD + c0 + 4 * i);
            As[16 * kg + 4 * i + 0][r] = av.x;
            As[16 * kg + 4 * i + 1][r] = av.y;
            As[16 * kg + 4 * i + 2][r] = av.z;
            As[16 * kg + 4 * i + 3][r] = av.w;
            float4 bv = *(const float4*)(W2 + (size_t)(n0 + r) * HIDD + c0 + 4 * i);
            Bs[16 * kg + 4 * i + 0][r] = bv.x;
            Bs[16 * kg + 4 * i + 1][r] = bv.y;
            Bs[16 * kg + 4 * i + 2][r] = bv.z;
            Bs[16 * kg + 4 * i + 3][r] = bv.w;
        }
        __syncthreads();
        #pragma unroll
        for (int k = 0; k < 32; ++k) {
            float a[8], b[8];
            *(float4*)&a[0] = *(const float4*)&As[k][8 * tr];
            *(float4*)&a[4] = *(const float4*)&As[k][8 * tr + 4];
            *(float4*)&b[0] = *(const float4*)&Bs[k][8 * tc];
            *(float4*)&b[4] = *(const float4*)&Bs[k][8 * tc + 4];
            #pragma unroll
            for (int i = 0; i < 8; ++i)
                #pragma unroll
                for (int j = 0; j < 8; ++j) acc[i][j] += a[i] * b[j];
        }
        __syncthreads();
    }
    float4 c0v = *(const float4*)(bl2 + n0 + 8 * tc);
    float4 c1v = *(const float4*)(bl2 + n0 + 8 * tc + 4);
    float bvals[8] = {c0v.x, c0v.y, c0v.z, c0v.w, c1v.x, c1v.y, c1v.z, c1v.w};
    #pragma unroll
    for (int i = 0; i < 8; ++i) {
        size_t ro = (size_t)(m0 + 8 * tr + i) * ODIM + n0 + 8 * tc;
        *(float4*)(out + ro)     = make_float4(acc[i][0] + bvals[0], acc[i][1] + bvals[1],
                                               acc[i][2] + bvals[2], acc[i][3] + bvals[3]);
        *(float4*)(out + ro + 4) = make_float4(acc[i][4] + bvals[4], acc[i][5] + bvals[5],
                                               acc[i][6] + bvals[6], acc[i][7] + bvals[7]);
    }
}

// ---------------------------------------------------------------------------
extern "C" void kernel_launch(void* const* d_in, const int* in_sizes, int n_in,
                              void* d_out, int out_size, void* d_ws, size_t ws_size,
                              hipStream_t stream) {
    const float* x      = (const float*)d_in[0];
    const int*   ei     = (const int*)d_in[1];
    const float* Wrel1  = (const float*)d_in[3];
    const float* brel1  = (const float*)d_in[4];
    const float* Wroot1 = (const float*)d_in[5];
    const float* Wrel2  = (const float*)d_in[6];
    const float* brel2  = (const float*)d_in[7];
    const float* Wroot2 = (const float*)d_in[8];
    const float* g1     = (const float*)d_in[9];
    const float* b1     = (const float*)d_in[10];
    const float* g2     = (const float*)d_in[11];
    const float* b2     = (const float*)d_in[12];
    const float* W1     = (const float*)d_in[13];
    const float* bl1    = (const float*)d_in[14];
    const float* W2     = (const float*)d_in[15];
    const float* bl2    = (const float*)d_in[16];
    float* out = (float*)d_out;
    char* ws = (char*)d_ws;

    // Layout (liveness-overlaid), ~346 MB:
    //   Y [0, SZ_YP):       xb(67MB) -> y1p(134MB)
    //   B [SZ_YP, +SZ_BB):  h1b(100MB) -> {h2b 100MB, hidp 16MB, hid 2MB}
    //   E [.., +SZ_E):      fixed-capacity bucket slots (75.5MB)
    //   off [.., +SZ_OFF)
    //   bcur(16KB) + smalls
    const size_t req = SZ_YP + SZ_BB + SZ_E + SZ_OFF + 16384 + 4096;
    if (ws_size < req) {
        float v = (float)(ws_size >> 20);
        k_diag<<<(out_size + 255) / 256, 256, 0, stream>>>(out, out_size, v);
        return;
    }
    char* pY = ws;
    char* pB = ws + SZ_YP;
    unsigned* ebuf = (unsigned*)(ws + SZ_YP + SZ_BB);
    int*  off = (int*)(ws + SZ_YP + SZ_BB + SZ_E);
    char* pK = ws + SZ_YP + SZ_BB + SZ_E + SZ_OFF;
    int*  bcur = (int*)pK;                      // 4096 ints; after bpart = bucket ends
    char* smalls = pK + 16384;
    double* st1  = (double*)smalls;
    double* st2  = st1 + 2 * FF1;
    float*  ss1  = (float*)(st2 + 2 * FF2);
    float*  ss2  = ss1 + 2 * FF1;
    int*    flag = (int*)(ss2 + 2 * FF2);

    uint4*    xb   = (uint4*)pY;
    uint4*    y1p  = (uint4*)pY;
    unsigned* h1b  = (unsigned*)pB;
    unsigned* h2b  = (unsigned*)pB;
    float*    hidp = (float*)(pB + SZ_HB);
    float*    hid  = (float*)(pB + SZ_HB + 8 * SZ_HID);

    hipMemsetAsync(smalls, 0, 1024, stream);
    k_detect<<<1, 256, 0, stream>>>(ei, flag);
    k_binit <<<16, 256, 0, stream>>>(bcur);
    k_padx  <<<NNODES / 4 / 256, 256, 0, stream>>>(x, xb);
    k_bpart <<<128, 512, 0, stream>>>(ei, flag, bcur, ebuf);
    k_bsort <<<NBKT, 256, 0, stream>>>(bcur, ebuf, off);
    k_conv1 <<<NBKT, 256, 0, stream>>>(off, bcur, ebuf, xb, Wrel1, brel1, Wroot1, h1b);
    k_statsb<<<256, 256, 0, stream>>>(h1b, st1);
    k_finalize<<<1, 64, 0, stream>>>(st1, g1, b1, ss1);
    k_y1    <<<NNODES / 256, 256, 0, stream>>>(h1b, ss1, y1p);
    k_conv2 <<<NBKT, 256, 0, stream>>>(off, bcur, ebuf, y1p, Wrel2, brel2, Wroot2, h2b);
    k_statsb<<<256, 256, 0, stream>>>(h2b, st2);
    k_finalize<<<1, 64, 0, stream>>>(st2, g2, b2, ss2);
    k_gemm1<<<dim3(BATCHSZ / 128, 8), 256, 0, stream>>>((const unsigned short*)h2b, ss2, W1, hidp);
    k_hred <<<BATCHSZ * HIDD / 256, 256, 0, stream>>>(hidp, bl1, hid);
    k_gemm2<<<dim3(BATCHSZ / 128, ODIM / 128), 256, 0, stream>>>(hid, W2, bl2, out);
}

// Round 10
// 1911.496 us; speedup vs baseline: 1.0086x; 1.0086x over previous
//
#include <hip/hip_runtime.h>
#include <hip/hip_bf16.h>

#define NBUS    1024
#define BATCHSZ 4096
#define NNODES  (NBUS*BATCHSZ)      // 4194304 = 2^22
#define NEDGES  (4*NNODES)          // 16777216
#define FIN     7
#define FF1     12
#define FF2     12
#define HIDD    128
#define KDIM    (NBUS*FF2)          // 12288
#define ODIM    (NBUS*2)            // 2048
#define NBKT    4096                // fine buckets of 1024 dst nodes
#define CAP     4608                // fine bucket capacity (mean 4096 + 8 sigma)
#define NCB     64                  // coarse buckets of 65536 dst nodes
#define CAPA    265216              // coarse capacity (mean 262144 + 6 sigma)

#define SZ_YP   ((size_t)NNODES * 16 * 2)               // 134,217,728 (xb -> y1p)
#define SZ_HB   ((size_t)NNODES * FF1 * 2)              // 100,663,296 (h1b -> h2b)
#define SZ_HID  ((size_t)BATCHSZ * HIDD * sizeof(float))//   2,097,152
#define SZ_BB   (SZ_HB + 9 * SZ_HID)                    // 119,537,664
#define SZ_E    ((size_t)NBKT * CAP * sizeof(unsigned)) //  75,497,472
#define SZ_OFF  ((size_t)NNODES * sizeof(int))          //  16,777,216
// ebufA (64*CAPA*8 = 135,790,592) overlays [pB .. pB+SZ_BB+SZ_OFF) = 136,314,880

typedef unsigned u32x2v  __attribute__((ext_vector_type(2)));

__device__ __forceinline__ float bflo(unsigned p){ return __uint_as_float(p << 16); }
__device__ __forceinline__ float bfhi(unsigned p){ return __uint_as_float(p & 0xffff0000u); }
__device__ __forceinline__ unsigned short f2bf(float f) {
    unsigned u = __float_as_uint(f);
    return (unsigned short)((u + 0x7fffu + ((u >> 16) & 1u)) >> 16);
}
__device__ __forceinline__ void nts_u2(unsigned* p, unsigned a, unsigned b) {
    u32x2v w; w.x = a; w.y = b;
    __builtin_nontemporal_store(w, (u32x2v*)p);
}
__device__ __forceinline__ uint2 ntl_u2(const unsigned* p) {
    u32x2v v = __builtin_nontemporal_load((const u32x2v*)p);
    uint2 r; r.x = v.x; r.y = v.y; return r;
}

// ---------------------------------------------------------------------------
__global__ void k_diag(float* __restrict__ out, int n, float v) {
    size_t i = (size_t)blockIdx.x * blockDim.x + threadIdx.x;
    if (i < (size_t)n) out[i] = v;
}

__global__ void k_detect(const int* __restrict__ w, int* __restrict__ flag) {
    __shared__ int any;
    if (threadIdx.x == 0) any = 0;
    __syncthreads();
    int acc = 0;
    #pragma unroll
    for (int u = 0; u < 4; ++u) acc |= w[1 + 2 * (threadIdx.x * 4 + u)];
    if (acc) atomicOr(&any, 1);
    __syncthreads();
    if (threadIdx.x == 0) *flag = (any == 0) ? 2 : 1;
}

__global__ void k_binit(int* __restrict__ bcur, int* __restrict__ bcurA) {
    int u = blockIdx.x * 256 + threadIdx.x;
    if (u < NBKT) bcur[u] = u * CAP;
    if (u < NCB) bcurA[u] = u * CAPA;
}

// ---------------------------------------------------------------------------
// pass A: partition edges into 64 coarse buckets (dst >> 16) as (src,dst) u32x2.
// Only 64 active write streams per block -> partial lines stay L2-resident.
__global__ __launch_bounds__(512) void k_partA(const int* __restrict__ ei,
                                               const int* __restrict__ flag,
                                               int* __restrict__ bcurA,
                                               unsigned* __restrict__ ebufA) {
    __shared__ int hist[NCB], lbase[NCB];
    int t = threadIdx.x;
    if (t < NCB) hist[t] = 0;
    __syncthreads();
    int mult = *flag;
    size_t base = (size_t)blockIdx.x * 65536;          // 256 blocks
    #pragma unroll 4
    for (int u = 0; u < 128; ++u) {
        size_t e = base + (size_t)u * 512 + t;
        int d = __builtin_nontemporal_load(ei + ((size_t)NEDGES + e) * mult);
        atomicAdd(&hist[d >> 16], 1);
    }
    __syncthreads();
    if (t < NCB) {
        int c = hist[t];
        lbase[t] = c ? atomicAdd(&bcurA[t], c) : 0;
        hist[t] = 0;
    }
    __syncthreads();
    #pragma unroll 4
    for (int u = 0; u < 128; ++u) {
        size_t e = base + (size_t)u * 512 + t;
        int s = __builtin_nontemporal_load(ei + e * mult);
        int d = __builtin_nontemporal_load(ei + ((size_t)NEDGES + e) * mult);
        int bk = d >> 16;
        int pos = lbase[bk] + atomicAdd(&hist[bk], 1);
        if (pos < (bk + 1) * CAPA)
            nts_u2(ebufA + (size_t)pos * 2, (unsigned)s, (unsigned)d);
    }
}

// ---------------------------------------------------------------------------
// pass B: 4 blocks per coarse bucket; partition into its 64 fine buckets,
// packing (src<<10 | dstLocal) into fixed-CAP fine slots.
__global__ __launch_bounds__(512) void k_partB(const unsigned* __restrict__ ebufA,
                                               const int* __restrict__ bendA,
                                               int* __restrict__ bcur,
                                               unsigned* __restrict__ ebuf) {
    __shared__ int hist[NCB], lbase[NCB];
    int t = threadIdx.x;
    int cb = blockIdx.x >> 2;
    int qq = blockIdx.x & 3;
    int abeg = cb * CAPA;
    int n = bendA[cb] - abeg; if (n > CAPA) n = CAPA;
    int beg = abeg + (int)(((long long)n * qq) >> 2);
    int end = abeg + (int)(((long long)n * (qq + 1)) >> 2);
    if (t < NCB) hist[t] = 0;
    __syncthreads();
    for (int k = beg + t; k < end; k += 512) {
        uint2 e = ntl_u2(ebufA + (size_t)k * 2);
        atomicAdd(&hist[(e.y >> 10) & 63u], 1);
    }
    __syncthreads();
    if (t < NCB) {
        int c = hist[t];
        lbase[t] = c ? atomicAdd(&bcur[cb * 64 + t], c) : 0;
        hist[t] = 0;
    }
    __syncthreads();
    for (int k = beg + t; k < end; k += 512) {
        uint2 e = ntl_u2(ebufA + (size_t)k * 2);
        int lb = (e.y >> 10) & 63u;
        int fb = cb * 64 + lb;
        int pos = lbase[lb] + atomicAdd(&hist[lb], 1);
        if (pos < (fb + 1) * CAP)
            ebuf[pos] = (e.x << 10) | (e.y & 1023u);
    }
}

// ---------------------------------------------------------------------------
// per-bucket counting sort by dstLocal; ebuf becomes src-only sorted by dst.
__global__ __launch_bounds__(256) void k_bsort(const int* __restrict__ bend,
                                               unsigned* __restrict__ ebuf,
                                               int* __restrict__ off) {
    __shared__ unsigned stage[CAP];        // 18KB
    __shared__ int hist[1024];
    __shared__ int wsum[4];
    int t = threadIdx.x;
    int bk = blockIdx.x;
    int ebeg = bk * CAP;
    int n = bend[bk] - ebeg;
    if (n > CAP) n = CAP;
    for (int k = t; k < n; k += 256) stage[k] = __builtin_nontemporal_load(ebuf + ebeg + k);
    for (int u = t; u < 1024; u += 256) hist[u] = 0;
    __syncthreads();
    for (int k = t; k < n; k += 256) atomicAdd(&hist[stage[k] & 1023u], 1);
    __syncthreads();
    int v[4]; int s = 0;
    #pragma unroll
    for (int u = 0; u < 4; ++u) { v[u] = hist[t * 4 + u]; s += v[u]; }
    int lane = t & 63, w = t >> 6;
    int iv = s;
    for (int o = 1; o < 64; o <<= 1) { int uu = __shfl_up(iv, o); if (lane >= o) iv += uu; }
    if (lane == 63) wsum[w] = iv;
    __syncthreads();
    int basep = 0;
    #pragma unroll
    for (int ww = 0; ww < 4; ++ww) if (ww < w) basep += wsum[ww];
    int run = basep + iv - s;
    #pragma unroll
    for (int u = 0; u < 4; ++u) {
        off[(size_t)bk * 1024 + t * 4 + u] = ebeg + run;
        hist[t * 4 + u] = run;
        run += v[u];
    }
    __syncthreads();
    for (int k = t; k < n; k += 256) {
        unsigned p = stage[k];
        int pos = atomicAdd(&hist[p & 1023u], 1);
        ebuf[ebeg + pos] = p >> 10;
    }
}

// ---------------------------------------------------------------------------
__global__ __launch_bounds__(256) void k_padx(const float* __restrict__ x,
                                              uint4* __restrict__ xb) {
    size_t q = (size_t)blockIdx.x * blockDim.x + threadIdx.x;
    if (q >= NNODES / 4) return;
    const float4* xr = (const float4*)(x + q * 28);
    float v[28];
    #pragma unroll
    for (int u = 0; u < 7; ++u) {
        float4 f = xr[u];
        v[4*u] = f.x; v[4*u+1] = f.y; v[4*u+2] = f.z; v[4*u+3] = f.w;
    }
    #pragma unroll
    for (int n = 0; n < 4; ++n) {
        unsigned short h[8];
        #pragma unroll
        for (int j = 0; j < 7; ++j) h[j] = f2bf(v[7*n + j]);
        h[7] = 0;
        uint4 o;
        o.x = (unsigned)h[0] | ((unsigned)h[1] << 16);
        o.y = (unsigned)h[2] | ((unsigned)h[3] << 16);
        o.z = (unsigned)h[4] | ((unsigned)h[5] << 16);
        o.w = (unsigned)h[6] | ((unsigned)h[7] << 16);
        xb[q * 4 + n] = o;
    }
}

// ---------------------------------------------------------------------------
// conv1: block per bucket; gather xb (16B rows); root also from xb; h1 bf16 out.
__global__ __launch_bounds__(256, 4) void k_conv1(const int* __restrict__ off,
                                                  const int* __restrict__ bend,
                                                  const unsigned* __restrict__ lst,
                                                  const uint4* __restrict__ xb,
                                                  const float* __restrict__ Wrel,
                                                  const float* __restrict__ brel,
                                                  const float* __restrict__ Wroot,
                                                  unsigned* __restrict__ h1b) {
    __shared__ float sWr[FF1 * FIN], sWo[FF1 * FIN], sb[FF1];
    int t = threadIdx.x;
    if (t < FF1 * FIN) { sWr[t] = Wrel[t]; sWo[t] = Wroot[t]; }
    if (t < FF1) sb[t] = brel[t];
    __syncthreads();
    int bk = blockIdx.x;
    int be = bend[bk];
    #pragma unroll
    for (int n = 0; n < 4; ++n) {
        int li = n * 256 + t;
        size_t i = (size_t)bk * 1024 + li;
        int beg = off[i];
        int end = (li == 1023) ? be : off[i + 1];
        float agg[FIN] = {0.f, 0.f, 0.f, 0.f, 0.f, 0.f, 0.f};
        int k = beg;
        for (; k + 1 < end; k += 2) {
            unsigned s0 = __builtin_nontemporal_load(lst + k);
            unsigned s1 = __builtin_nontemporal_load(lst + k + 1);
            uint4 a0 = xb[s0], a1 = xb[s1];
            agg[0] += bflo(a0.x) + bflo(a1.x);
            agg[1] += bfhi(a0.x) + bfhi(a1.x);
            agg[2] += bflo(a0.y) + bflo(a1.y);
            agg[3] += bfhi(a0.y) + bfhi(a1.y);
            agg[4] += bflo(a0.z) + bflo(a1.z);
            agg[5] += bfhi(a0.z) + bfhi(a1.z);
            agg[6] += bflo(a0.w) + bflo(a1.w);
        }
        if (k < end) {
            uint4 a0 = xb[__builtin_nontemporal_load(lst + k)];
            agg[0] += bflo(a0.x); agg[1] += bfhi(a0.x);
            agg[2] += bflo(a0.y); agg[3] += bfhi(a0.y);
            agg[4] += bflo(a0.z); agg[5] += bfhi(a0.z);
            agg[6] += bflo(a0.w);
        }
        uint4 ow = xb[i];
        float xv[FIN] = {bflo(ow.x), bfhi(ow.x), bflo(ow.y), bfhi(ow.y),
                         bflo(ow.z), bfhi(ow.z), bflo(ow.w)};
        unsigned short hh[FF1];
        #pragma unroll
        for (int j = 0; j < FF1; ++j) {
            float h = sb[j];
            #pragma unroll
            for (int q = 0; q < FIN; ++q) h += sWr[j * FIN + q] * agg[q] + sWo[j * FIN + q] * xv[q];
            hh[j] = f2bf(h);
        }
        unsigned* p = h1b + i * 6;
        nts_u2(p,     (unsigned)hh[0] | ((unsigned)hh[1] << 16),
                      (unsigned)hh[2] | ((unsigned)hh[3] << 16));
        nts_u2(p + 2, (unsigned)hh[4] | ((unsigned)hh[5] << 16),
                      (unsigned)hh[6] | ((unsigned)hh[7] << 16));
        nts_u2(p + 4, (unsigned)hh[8] | ((unsigned)hh[9] << 16),
                      (unsigned)hh[10]| ((unsigned)hh[11] << 16));
    }
}

// ---------------------------------------------------------------------------
// stats over bf16 24B rows (N x 12 packed in 6 dwords)
__global__ __launch_bounds__(256) void k_statsb(const unsigned* __restrict__ hb,
                                                double* __restrict__ stats) {
    __shared__ float red[4][FF1], redq[4][FF1];
    int t = threadIdx.x;
    float ps[FF1], pq[FF1];
    #pragma unroll
    for (int j = 0; j < FF1; ++j) { ps[j] = 0.f; pq[j] = 0.f; }
    for (size_t i = (size_t)blockIdx.x * 256 + t; i < NNODES; i += 256 * 256) {
        const uint2* r = (const uint2*)(hb + i * 6);
        uint2 u0 = r[0], u1 = r[1], u2 = r[2];
        float v[FF1] = {bflo(u0.x), bfhi(u0.x), bflo(u0.y), bfhi(u0.y),
                        bflo(u1.x), bfhi(u1.x), bflo(u1.y), bfhi(u1.y),
                        bflo(u2.x), bfhi(u2.x), bflo(u2.y), bfhi(u2.y)};
        #pragma unroll
        for (int j = 0; j < FF1; ++j) { ps[j] += v[j]; pq[j] += v[j] * v[j]; }
    }
    #pragma unroll
    for (int j = 0; j < FF1; ++j)
        for (int o = 1; o < 64; o <<= 1) { ps[j] += __shfl_xor(ps[j], o); pq[j] += __shfl_xor(pq[j], o); }
    int lane = t & 63, wv = t >> 6;
    if (lane == 0) {
        #pragma unroll
        for (int j = 0; j < FF1; ++j) { red[wv][j] = ps[j]; redq[wv][j] = pq[j]; }
    }
    __syncthreads();
    if (t < FF1) {
        float s = red[0][t] + red[1][t] + red[2][t] + red[3][t];
        float q = redq[0][t] + redq[1][t] + redq[2][t] + redq[3][t];
        atomicAdd(&stats[t], (double)s);
        atomicAdd(&stats[FF1 + t], (double)q);
    }
}

// ---------------------------------------------------------------------------
__global__ void k_finalize(const double* __restrict__ stats, const float* __restrict__ g,
                           const float* __restrict__ b, float* __restrict__ ss) {
    int j = threadIdx.x;
    if (j < FF1) {
        double mean = stats[j] * (1.0 / NNODES);
        double var  = stats[FF1 + j] * (1.0 / NNODES) - mean * mean;
        float sc = (float)((double)g[j] / sqrt(var + 1e-5));
        ss[j] = sc;
        ss[FF1 + j] = b[j] - (float)mean * sc;
    }
}

// ---------------------------------------------------------------------------
// y1p = relu(bn1(h1b)) as 16 bf16 (32B row, 4 pad); one node per thread.
__global__ __launch_bounds__(256) void k_y1(const unsigned* __restrict__ h1b,
                                            const float* __restrict__ ss,
                                            uint4* __restrict__ y1p) {
    __shared__ float sc[FF1], sh[FF1];
    int t = threadIdx.x;
    if (t < FF1) { sc[t] = ss[t]; sh[t] = ss[FF1 + t]; }
    __syncthreads();
    size_t i = (size_t)blockIdx.x * blockDim.x + t;
    if (i >= NNODES) return;
    const uint2* r = (const uint2*)(h1b + i * 6);
    uint2 u0 = r[0], u1 = r[1], u2 = r[2];
    float v[FF1] = {bflo(u0.x), bfhi(u0.x), bflo(u0.y), bfhi(u0.y),
                    bflo(u1.x), bfhi(u1.x), bflo(u1.y), bfhi(u1.y),
                    bflo(u2.x), bfhi(u2.x), bflo(u2.y), bfhi(u2.y)};
    unsigned short hh[FF1];
    #pragma unroll
    for (int j = 0; j < FF1; ++j) {
        float w = v[j] * sc[j] + sh[j];
        hh[j] = f2bf(w > 0.f ? w : 0.f);
    }
    uint4 w1, w2;
    w1.x = (unsigned)hh[0] | ((unsigned)hh[1] << 16);
    w1.y = (unsigned)hh[2] | ((unsigned)hh[3] << 16);
    w1.z = (unsigned)hh[4] | ((unsigned)hh[5] << 16);
    w1.w = (unsigned)hh[6] | ((unsigned)hh[7] << 16);
    w2.x = (unsigned)hh[8] | ((unsigned)hh[9] << 16);
    w2.y = (unsigned)hh[10]| ((unsigned)hh[11] << 16);
    w2.z = 0u; w2.w = 0u;
    y1p[i * 2]     = w1;
    y1p[i * 2 + 1] = w2;
}

// ---------------------------------------------------------------------------
// conv2: block per bucket; gather y1p (32B rows, no straddle); h2 bf16 out.
__global__ __launch_bounds__(256, 4) void k_conv2(const int* __restrict__ off,
                                                  const int* __restrict__ bend,
                                                  const unsigned* __restrict__ lst,
                                                  const uint4* __restrict__ y1p,
                                                  const float* __restrict__ Wrel,
                                                  const float* __restrict__ brel,
                                                  const float* __restrict__ Wroot,
                                                  unsigned* __restrict__ h2b) {
    __shared__ float sWr[FF2 * FF1], sWo[FF2 * FF1], sb[FF2];
    int t = threadIdx.x;
    if (t < FF2 * FF1) { sWr[t] = Wrel[t]; sWo[t] = Wroot[t]; }
    if (t < FF2) sb[t] = brel[t];
    __syncthreads();
    int bk = blockIdx.x;
    int be = bend[bk];
    #pragma unroll
    for (int n = 0; n < 4; ++n) {
        int li = n * 256 + t;
        size_t i = (size_t)bk * 1024 + li;
        int beg = off[i];
        int end = (li == 1023) ? be : off[i + 1];
        float agg[FF1];
        #pragma unroll
        for (int j = 0; j < FF1; ++j) agg[j] = 0.f;
        int k = beg;
        for (; k + 1 < end; k += 2) {
            unsigned s0 = __builtin_nontemporal_load(lst + k);
            unsigned s1 = __builtin_nontemporal_load(lst + k + 1);
            uint4 a0 = y1p[(size_t)s0 * 2], a1 = y1p[(size_t)s0 * 2 + 1];
            uint4 b0 = y1p[(size_t)s1 * 2], b1 = y1p[(size_t)s1 * 2 + 1];
            agg[0] += bflo(a0.x) + bflo(b0.x); agg[1]  += bfhi(a0.x) + bfhi(b0.x);
            agg[2] += bflo(a0.y) + bflo(b0.y); agg[3]  += bfhi(a0.y) + bfhi(b0.y);
            agg[4] += bflo(a0.z) + bflo(b0.z); agg[5]  += bfhi(a0.z) + bfhi(b0.z);
            agg[6] += bflo(a0.w) + bflo(b0.w); agg[7]  += bfhi(a0.w) + bfhi(b0.w);
            agg[8] += bflo(a1.x) + bflo(b1.x); agg[9]  += bfhi(a1.x) + bfhi(b1.x);
            agg[10]+= bflo(a1.y) + bflo(b1.y); agg[11] += bfhi(a1.y) + bfhi(b1.y);
        }
        if (k < end) {
            unsigned s0 = __builtin_nontemporal_load(lst + k);
            uint4 a0 = y1p[(size_t)s0 * 2], a1 = y1p[(size_t)s0 * 2 + 1];
            agg[0] += bflo(a0.x); agg[1]  += bfhi(a0.x);
            agg[2] += bflo(a0.y); agg[3]  += bfhi(a0.y);
            agg[4] += bflo(a0.z); agg[5]  += bfhi(a0.z);
            agg[6] += bflo(a0.w); agg[7]  += bfhi(a0.w);
            agg[8] += bflo(a1.x); agg[9]  += bfhi(a1.x);
            agg[10]+= bflo(a1.y); agg[11] += bfhi(a1.y);
        }
        uint4 o0 = y1p[i * 2], o1 = y1p[i * 2 + 1];
        float y[FF1] = {bflo(o0.x), bfhi(o0.x), bflo(o0.y), bfhi(o0.y),
                        bflo(o0.z), bfhi(o0.z), bflo(o0.w), bfhi(o0.w),
                        bflo(o1.x), bfhi(o1.x), bflo(o1.y), bfhi(o1.y)};
        unsigned short hh[FF2];
        #pragma unroll
        for (int j = 0; j < FF2; ++j) {
            float h = sb[j];
            #pragma unroll
            for (int q = 0; q < FF1; ++q) h += sWr[j * FF1 + q] * agg[q] + sWo[j * FF1 + q] * y[q];
            hh[j] = f2bf(h);
        }
        unsigned* p = h2b + i * 6;
        nts_u2(p,     (unsigned)hh[0] | ((unsigned)hh[1] << 16),
                      (unsigned)hh[2] | ((unsigned)hh[3] << 16));
        nts_u2(p + 2, (unsigned)hh[4] | ((unsigned)hh[5] << 16),
                      (unsigned)hh[6] | ((unsigned)hh[7] << 16));
        nts_u2(p + 4, (unsigned)hh[8] | ((unsigned)hh[9] << 16),
                      (unsigned)hh[10]| ((unsigned)hh[11] << 16));
    }
}

// ---------------------------------------------------------------------------
// GEMM1: A = relu(bn2(h2b)) bf16-stored, B = W1 f32; split-K=8 partials.
__global__ __launch_bounds__(256) void k_gemm1(const unsigned short* __restrict__ h2b,
                                               const float* __restrict__ ss2,
                                               const float* __restrict__ W1,
                                               float* __restrict__ hidp) {
    __shared__ float As[32][128];
    __shared__ float Bs[32][128];
    __shared__ float sc[FF2], sh[FF2];
    int t = threadIdx.x;
    if (t < FF2) { sc[t] = ss2[t]; sh[t] = ss2[FF2 + t]; }
    __syncthreads();
    int mb = blockIdx.x;
    int ks = blockIdx.y;
    const int KS = KDIM / 8;         // 1536
    int m0 = mb * 128;
    int kbase = ks * KS;
    int r  = t >> 1;
    int kg = t & 1;
    int tr = t >> 4;
    int tc = t & 15;
    float acc[8][8];
    #pragma unroll
    for (int i = 0; i < 8; ++i)
        #pragma unroll
        for (int j = 0; j < 8; ++j) acc[i][j] = 0.f;

    for (int kt = 0; kt < KS; kt += 32) {
        int c0 = kbase + kt + 16 * kg;
        const uint2* arow = (const uint2*)(h2b + (size_t)(m0 + r) * KDIM + c0);
        const float* brow = W1 + (size_t)r * KDIM + c0;
        #pragma unroll
        for (int i = 0; i < 4; ++i) {
            uint2 av = arow[i];
            int cc = c0 + 4 * i;
            int j0 = cc % FF2;
            float vals[4] = {bflo(av.x), bfhi(av.x), bflo(av.y), bfhi(av.y)};
            #pragma unroll
            for (int ii = 0; ii < 4; ++ii) {
                int j = j0 + ii; if (j >= FF2) j -= FF2;
                float v = vals[ii] * sc[j] + sh[j];
                As[16 * kg + 4 * i + ii][r] = v > 0.f ? v : 0.f;
            }
            float4 bv = *(const float4*)(brow + 4 * i);
            Bs[16 * kg + 4 * i + 0][r] = bv.x;
            Bs[16 * kg + 4 * i + 1][r] = bv.y;
            Bs[16 * kg + 4 * i + 2][r] = bv.z;
            Bs[16 * kg + 4 * i + 3][r] = bv.w;
        }
        __syncthreads();
        #pragma unroll
        for (int k = 0; k < 32; ++k) {
            float a[8], b[8];
            *(float4*)&a[0] = *(const float4*)&As[k][8 * tr];
            *(float4*)&a[4] = *(const float4*)&As[k][8 * tr + 4];
            *(float4*)&b[0] = *(const float4*)&Bs[k][8 * tc];
            *(float4*)&b[4] = *(const float4*)&Bs[k][8 * tc + 4];
            #pragma unroll
            for (int i = 0; i < 8; ++i)
                #pragma unroll
                for (int j = 0; j < 8; ++j) acc[i][j] += a[i] * b[j];
        }
        __syncthreads();
    }
    float* obase = hidp + (size_t)ks * (BATCHSZ * HIDD);
    #pragma unroll
    for (int i = 0; i < 8; ++i) {
        float* orow = obase + (size_t)(m0 + 8 * tr + i) * HIDD + 8 * tc;
        *(float4*)(orow)     = make_float4(acc[i][0], acc[i][1], acc[i][2], acc[i][3]);
        *(float4*)(orow + 4) = make_float4(acc[i][4], acc[i][5], acc[i][6], acc[i][7]);
    }
}

__global__ __launch_bounds__(256) void k_hred(const float* __restrict__ hidp,
                                              const float* __restrict__ bl1,
                                              float* __restrict__ hid) {
    int i = blockIdx.x * 256 + threadIdx.x;
    float s = bl1[i & (HIDD - 1)];
    #pragma unroll
    for (int p = 0; p < 8; ++p) s += hidp[(size_t)p * (BATCHSZ * HIDD) + i];
    hid[i] = s > 0.f ? s : 0.f;
}

// ---------------------------------------------------------------------------
__global__ __launch_bounds__(256) void k_gemm2(const float* __restrict__ hid,
                                               const float* __restrict__ W2,
                                               const float* __restrict__ bl2,
                                               float* __restrict__ out) {
    __shared__ float As[32][128];
    __shared__ float Bs[32][128];
    int t = threadIdx.x;
    int m0 = blockIdx.x * 128;
    int n0 = blockIdx.y * 128;
    int r  = t >> 1;
    int kg = t & 1;
    int tr = t >> 4;
    int tc = t & 15;
    float acc[8][8];
    #pragma unroll
    for (int i = 0; i < 8; ++i)
        #pragma unroll
        for (int j = 0; j < 8; ++j) acc[i][j] = 0.f;

    for (int kt = 0; kt < HIDD; kt += 32) {
        int c0 = kt + 16 * kg;
        #pragma unroll
        for (int i = 0; i < 4; ++i) {
            float4 av = *(const float4*)(hid + (size_t)(m0 + r) * HIDD + c0 + 4 * i);
            As[16 * kg + 4 * i + 0][r] = av.x;
            As[16 * kg + 4 * i + 1][r] = av.y;
            As[16 * kg + 4 * i + 2][r] = av.z;
            As[16 * kg + 4 * i + 3][r] = av.w;
            float4 bv = *(const float4*)(W2 + (size_t)(n0 + r) * HIDD + c0 + 4 * i);
            Bs[16 * kg + 4 * i + 0][r] = bv.x;
            Bs[16 * kg + 4 * i + 1][r] = bv.y;
            Bs[16 * kg + 4 * i + 2][r] = bv.z;
            Bs[16 * kg + 4 * i + 3][r] = bv.w;
        }
        __syncthreads();
        #pragma unroll
        for (int k = 0; k < 32; ++k) {
            float a[8], b[8];
            *(float4*)&a[0] = *(const float4*)&As[k][8 * tr];
            *(float4*)&a[4] = *(const float4*)&As[k][8 * tr + 4];
            *(float4*)&b[0] = *(const float4*)&Bs[k][8 * tc];
            *(float4*)&b[4] = *(const float4*)&Bs[k][8 * tc + 4];
            #pragma unroll
            for (int i = 0; i < 8; ++i)
                #pragma unroll
                for (int j = 0; j < 8; ++j) acc[i][j] += a[i] * b[j];
        }
        __syncthreads();
    }
    float4 c0v = *(const float4*)(bl2 + n0 + 8 * tc);
    float4 c1v = *(const float4*)(bl2 + n0 + 8 * tc + 4);
    float bvals[8] = {c0v.x, c0v.y, c0v.z, c0v.w, c1v.x, c1v.y, c1v.z, c1v.w};
    #pragma unroll
    for (int i = 0; i < 8; ++i) {
        size_t ro = (size_t)(m0 + 8 * tr + i) * ODIM + n0 + 8 * tc;
        *(float4*)(out + ro)     = make_float4(acc[i][0] + bvals[0], acc[i][1] + bvals[1],
                                               acc[i][2] + bvals[2], acc[i][3] + bvals[3]);
        *(float4*)(out + ro + 4) = make_float4(acc[i][4] + bvals[4], acc[i][5] + bvals[5],
                                               acc[i][6] + bvals[6], acc[i][7] + bvals[7]);
    }
}

// ---------------------------------------------------------------------------
extern "C" void kernel_launch(void* const* d_in, const int* in_sizes, int n_in,
                              void* d_out, int out_size, void* d_ws, size_t ws_size,
                              hipStream_t stream) {
    const float* x      = (const float*)d_in[0];
    const int*   ei     = (const int*)d_in[1];
    const float* Wrel1  = (const float*)d_in[3];
    const float* brel1  = (const float*)d_in[4];
    const float* Wroot1 = (const float*)d_in[5];
    const float* Wrel2  = (const float*)d_in[6];
    const float* brel2  = (const float*)d_in[7];
    const float* Wroot2 = (const float*)d_in[8];
    const float* g1     = (const float*)d_in[9];
    const float* b1     = (const float*)d_in[10];
    const float* g2     = (const float*)d_in[11];
    const float* b2     = (const float*)d_in[12];
    const float* W1     = (const float*)d_in[13];
    const float* bl1    = (const float*)d_in[14];
    const float* W2     = (const float*)d_in[15];
    const float* bl2    = (const float*)d_in[16];
    float* out = (float*)d_out;
    char* ws = (char*)d_ws;

    // Layout (liveness-overlaid), ~346 MB:
    //   pY  [0, SZ_YP):      xb(67MB) -> y1p(134MB)
    //   E   [SZ_YP, +SZ_E):  fine bucket slots (75.5MB)
    //   pB  [.., +SZ_BB):    ebufA spans pB..off-end (135.8MB) -> h1b -> {h2b, hidp, hid}
    //   off [.., +SZ_OFF)
    //   pK: bcur(16KB), bcurA(256B), smalls
    const size_t req = SZ_YP + SZ_E + SZ_BB + SZ_OFF + 32768;
    if (ws_size < req) {
        float v = (float)(ws_size >> 20);
        k_diag<<<(out_size + 255) / 256, 256, 0, stream>>>(out, out_size, v);
        return;
    }
    char* pY = ws;
    unsigned* ebuf = (unsigned*)(ws + SZ_YP);
    char* pB = ws + SZ_YP + SZ_E;
    int*  off = (int*)(ws + SZ_YP + SZ_E + SZ_BB);
    char* pK = ws + SZ_YP + SZ_E + SZ_BB + SZ_OFF;
    int*  bcur  = (int*)pK;                     // 4096 ints; ends after partB
    int*  bcurA = (int*)(pK + 16384);           // 64 ints; ends after partA
    char* smalls = pK + 20480;
    double* st1  = (double*)smalls;
    double* st2  = st1 + 2 * FF1;
    float*  ss1  = (float*)(st2 + 2 * FF2);
    float*  ss2  = ss1 + 2 * FF1;
    int*    flag = (int*)(ss2 + 2 * FF2);

    uint4*    xb    = (uint4*)pY;
    uint4*    y1p   = (uint4*)pY;
    unsigned* ebufA = (unsigned*)pB;            // 135.8MB, overlays pB+off (dead then)
    unsigned* h1b   = (unsigned*)pB;
    unsigned* h2b   = (unsigned*)pB;
    float*    hidp  = (float*)(pB + SZ_HB);
    float*    hid   = (float*)(pB + SZ_HB + 8 * SZ_HID);

    hipMemsetAsync(smalls, 0, 1024, stream);
    k_detect<<<1, 256, 0, stream>>>(ei, flag);
    k_binit <<<16, 256, 0, stream>>>(bcur, bcurA);
    k_padx  <<<NNODES / 4 / 256, 256, 0, stream>>>(x, xb);
    k_partA <<<256, 512, 0, stream>>>(ei, flag, bcurA, ebufA);
    k_partB <<<NCB * 4, 512, 0, stream>>>(ebufA, bcurA, bcur, ebuf);
    k_bsort <<<NBKT, 256, 0, stream>>>(bcur, ebuf, off);
    k_conv1 <<<NBKT, 256, 0, stream>>>(off, bcur, ebuf, xb, Wrel1, brel1, Wroot1, h1b);
    k_statsb<<<256, 256, 0, stream>>>(h1b, st1);
    k_finalize<<<1, 64, 0, stream>>>(st1, g1, b1, ss1);
    k_y1    <<<NNODES / 256, 256, 0, stream>>>(h1b, ss1, y1p);
    k_conv2 <<<NBKT, 256, 0, stream>>>(off, bcur, ebuf, y1p, Wrel2, brel2, Wroot2, h2b);
    k_statsb<<<256, 256, 0, stream>>>(h2b, st2);
    k_finalize<<<1, 64, 0, stream>>>(st2, g2, b2, ss2);
    k_gemm1<<<dim3(BATCHSZ / 128, 8), 256, 0, stream>>>((const unsigned short*)h2b, ss2, W1, hidp);
    k_hred <<<BATCHSZ * HIDD / 256, 256, 0, stream>>>(hidp, bl1, hid);
    k_gemm2<<<dim3(BATCHSZ / 128, ODIM / 128), 256, 0, stream>>>(hid, W2, bl2, out);
}

// Round 11
// 1565.497 us; speedup vs baseline: 1.2315x; 1.2210x over previous
//
#include <hip/hip_runtime.h>
#include <hip/hip_bf16.h>

#define NBUS    1024
#define BATCHSZ 4096
#define NNODES  (NBUS*BATCHSZ)      // 4194304 = 2^22
#define NEDGES  (4*NNODES)          // 16777216
#define FIN     7
#define FF1     12
#define FF2     12
#define HIDD    128
#define KDIM    (NBUS*FF2)          // 12288
#define ODIM    (NBUS*2)            // 2048
#define NBKT    4096                // fine buckets of 1024 dst nodes
#define CAP     4608                // fine bucket capacity (mean 4096 + 8 sigma)
#define NCB     64                  // coarse buckets of 65536 dst nodes
#define CAPA    265216              // coarse capacity (mean 262144 + 6 sigma)

#define SZ_YP   ((size_t)NNODES * 16 * 2)               // 134,217,728 (xb -> y1p)
#define SZ_HB   ((size_t)NNODES * FF1 * 2)              // 100,663,296 (h1b -> h2b)
#define SZ_HID  ((size_t)BATCHSZ * HIDD * sizeof(float))//   2,097,152
#define SZ_BB   (SZ_HB + 9 * SZ_HID)                    // 119,537,664
#define SZ_E    ((size_t)NBKT * CAP * sizeof(unsigned)) //  75,497,472
#define SZ_OFF  ((size_t)NNODES * sizeof(int))          //  16,777,216
// ebufA (64*CAPA*8 = 135,790,592) overlays [pB .. pB+SZ_BB+SZ_OFF) = 136,314,880

typedef unsigned u32x2v  __attribute__((ext_vector_type(2)));

__device__ __forceinline__ float bflo(unsigned p){ return __uint_as_float(p << 16); }
__device__ __forceinline__ float bfhi(unsigned p){ return __uint_as_float(p & 0xffff0000u); }
__device__ __forceinline__ unsigned short f2bf(float f) {
    unsigned u = __float_as_uint(f);
    return (unsigned short)((u + 0x7fffu + ((u >> 16) & 1u)) >> 16);
}
__device__ __forceinline__ void nts_u2(unsigned* p, unsigned a, unsigned b) {
    u32x2v w; w.x = a; w.y = b;
    __builtin_nontemporal_store(w, (u32x2v*)p);
}
__device__ __forceinline__ uint2 ntl_u2(const unsigned* p) {
    u32x2v v = __builtin_nontemporal_load((const u32x2v*)p);
    uint2 r; r.x = v.x; r.y = v.y; return r;
}

// ---------------------------------------------------------------------------
__global__ void k_diag(float* __restrict__ out, int n, float v) {
    size_t i = (size_t)blockIdx.x * blockDim.x + threadIdx.x;
    if (i < (size_t)n) out[i] = v;
}

__global__ void k_detect(const int* __restrict__ w, int* __restrict__ flag) {
    __shared__ int any;
    if (threadIdx.x == 0) any = 0;
    __syncthreads();
    int acc = 0;
    #pragma unroll
    for (int u = 0; u < 4; ++u) acc |= w[1 + 2 * (threadIdx.x * 4 + u)];
    if (acc) atomicOr(&any, 1);
    __syncthreads();
    if (threadIdx.x == 0) *flag = (any == 0) ? 2 : 1;
}

__global__ void k_binit(int* __restrict__ bcur, int* __restrict__ bcurA) {
    int u = blockIdx.x * 256 + threadIdx.x;
    if (u < NBKT) bcur[u] = u * CAP;
    if (u < NCB) bcurA[u] = u * CAPA;
}

// ---------------------------------------------------------------------------
// pass A: partition edges into 64 coarse buckets (dst >> 16) as (src,dst) u32x2.
// PLAIN stores (not nt): L2 accumulates the 64 per-block write streams into
// full lines (~8KB run per bucket per block).
__global__ __launch_bounds__(512) void k_partA(const int* __restrict__ ei,
                                               const int* __restrict__ flag,
                                               int* __restrict__ bcurA,
                                               unsigned* __restrict__ ebufA) {
    __shared__ int hist[NCB], lbase[NCB];
    int t = threadIdx.x;
    if (t < NCB) hist[t] = 0;
    __syncthreads();
    int mult = *flag;
    size_t base = (size_t)blockIdx.x * 32768;          // 512 blocks
    #pragma unroll 4
    for (int u = 0; u < 64; ++u) {
        size_t e = base + (size_t)u * 512 + t;
        int d = __builtin_nontemporal_load(ei + ((size_t)NEDGES + e) * mult);
        atomicAdd(&hist[d >> 16], 1);
    }
    __syncthreads();
    if (t < NCB) {
        int c = hist[t];
        lbase[t] = c ? atomicAdd(&bcurA[t], c) : 0;
        hist[t] = 0;
    }
    __syncthreads();
    #pragma unroll 4
    for (int u = 0; u < 64; ++u) {
        size_t e = base + (size_t)u * 512 + t;
        int s = __builtin_nontemporal_load(ei + e * mult);
        int d = __builtin_nontemporal_load(ei + ((size_t)NEDGES + e) * mult);
        int bk = d >> 16;
        int pos = lbase[bk] + atomicAdd(&hist[bk], 1);
        if (pos < (bk + 1) * CAPA) {
            uint2* p = (uint2*)(ebufA + (size_t)pos * 2);
            *p = make_uint2((unsigned)s, (unsigned)d);
        }
    }
}

// ---------------------------------------------------------------------------
// pass B: 4 blocks per coarse bucket; partition into its 64 fine buckets,
// packing (src<<10 | dstLocal) into fixed-CAP fine slots. Plain stores.
__global__ __launch_bounds__(512) void k_partB(const unsigned* __restrict__ ebufA,
                                               const int* __restrict__ bendA,
                                               int* __restrict__ bcur,
                                               unsigned* __restrict__ ebuf) {
    __shared__ int hist[NCB], lbase[NCB];
    int t = threadIdx.x;
    int cb = blockIdx.x >> 2;
    int qq = blockIdx.x & 3;
    int abeg = cb * CAPA;
    int n = bendA[cb] - abeg; if (n > CAPA) n = CAPA;
    int beg = abeg + (int)(((long long)n * qq) >> 2);
    int end = abeg + (int)(((long long)n * (qq + 1)) >> 2);
    if (t < NCB) hist[t] = 0;
    __syncthreads();
    for (int k = beg + t; k < end; k += 512) {
        uint2 e = ntl_u2(ebufA + (size_t)k * 2);
        atomicAdd(&hist[(e.y >> 10) & 63u], 1);
    }
    __syncthreads();
    if (t < NCB) {
        int c = hist[t];
        lbase[t] = c ? atomicAdd(&bcur[cb * 64 + t], c) : 0;
        hist[t] = 0;
    }
    __syncthreads();
    for (int k = beg + t; k < end; k += 512) {
        uint2 e = ntl_u2(ebufA + (size_t)k * 2);
        int lb = (e.y >> 10) & 63u;
        int fb = cb * 64 + lb;
        int pos = lbase[lb] + atomicAdd(&hist[lb], 1);
        if (pos < (fb + 1) * CAP)
            ebuf[pos] = (e.x << 10) | (e.y & 1023u);
    }
}

// ---------------------------------------------------------------------------
// per-bucket counting sort by dstLocal; ebuf becomes src-only sorted by dst.
__global__ __launch_bounds__(256) void k_bsort(const int* __restrict__ bend,
                                               unsigned* __restrict__ ebuf,
                                               int* __restrict__ off) {
    __shared__ unsigned stage[CAP];        // 18KB
    __shared__ int hist[1024];
    __shared__ int wsum[4];
    int t = threadIdx.x;
    int bk = blockIdx.x;
    int ebeg = bk * CAP;
    int n = bend[bk] - ebeg;
    if (n > CAP) n = CAP;
    for (int k = t; k < n; k += 256) stage[k] = __builtin_nontemporal_load(ebuf + ebeg + k);
    for (int u = t; u < 1024; u += 256) hist[u] = 0;
    __syncthreads();
    for (int k = t; k < n; k += 256) atomicAdd(&hist[stage[k] & 1023u], 1);
    __syncthreads();
    int v[4]; int s = 0;
    #pragma unroll
    for (int u = 0; u < 4; ++u) { v[u] = hist[t * 4 + u]; s += v[u]; }
    int lane = t & 63, w = t >> 6;
    int iv = s;
    for (int o = 1; o < 64; o <<= 1) { int uu = __shfl_up(iv, o); if (lane >= o) iv += uu; }
    if (lane == 63) wsum[w] = iv;
    __syncthreads();
    int basep = 0;
    #pragma unroll
    for (int ww = 0; ww < 4; ++ww) if (ww < w) basep += wsum[ww];
    int run = basep + iv - s;
    #pragma unroll
    for (int u = 0; u < 4; ++u) {
        off[(size_t)bk * 1024 + t * 4 + u] = ebeg + run;
        hist[t * 4 + u] = run;
        run += v[u];
    }
    __syncthreads();
    for (int k = t; k < n; k += 256) {
        unsigned p = stage[k];
        int pos = atomicAdd(&hist[p & 1023u], 1);
        ebuf[ebeg + pos] = p >> 10;
    }
}

// ---------------------------------------------------------------------------
__global__ __launch_bounds__(256) void k_padx(const float* __restrict__ x,
                                              uint4* __restrict__ xb) {
    size_t q = (size_t)blockIdx.x * blockDim.x + threadIdx.x;
    if (q >= NNODES / 4) return;
    const float4* xr = (const float4*)(x + q * 28);
    float v[28];
    #pragma unroll
    for (int u = 0; u < 7; ++u) {
        float4 f = xr[u];
        v[4*u] = f.x; v[4*u+1] = f.y; v[4*u+2] = f.z; v[4*u+3] = f.w;
    }
    #pragma unroll
    for (int n = 0; n < 4; ++n) {
        unsigned short h[8];
        #pragma unroll
        for (int j = 0; j < 7; ++j) h[j] = f2bf(v[7*n + j]);
        h[7] = 0;
        uint4 o;
        o.x = (unsigned)h[0] | ((unsigned)h[1] << 16);
        o.y = (unsigned)h[2] | ((unsigned)h[3] << 16);
        o.z = (unsigned)h[4] | ((unsigned)h[5] << 16);
        o.w = (unsigned)h[6] | ((unsigned)h[7] << 16);
        xb[q * 4 + n] = o;
    }
}

// ---------------------------------------------------------------------------
// conv1: block per bucket; gather xb (16B rows); root also from xb; h1 bf16 out.
__global__ __launch_bounds__(256, 4) void k_conv1(const int* __restrict__ off,
                                                  const int* __restrict__ bend,
                                                  const unsigned* __restrict__ lst,
                                                  const uint4* __restrict__ xb,
                                                  const float* __restrict__ Wrel,
                                                  const float* __restrict__ brel,
                                                  const float* __restrict__ Wroot,
                                                  unsigned* __restrict__ h1b) {
    __shared__ float sWr[FF1 * FIN], sWo[FF1 * FIN], sb[FF1];
    int t = threadIdx.x;
    if (t < FF1 * FIN) { sWr[t] = Wrel[t]; sWo[t] = Wroot[t]; }
    if (t < FF1) sb[t] = brel[t];
    __syncthreads();
    int bk = blockIdx.x;
    int be = bend[bk];
    #pragma unroll
    for (int n = 0; n < 4; ++n) {
        int li = n * 256 + t;
        size_t i = (size_t)bk * 1024 + li;
        int beg = off[i];
        int end = (li == 1023) ? be : off[i + 1];
        float agg[FIN] = {0.f, 0.f, 0.f, 0.f, 0.f, 0.f, 0.f};
        int k = beg;
        for (; k + 1 < end; k += 2) {
            unsigned s0 = __builtin_nontemporal_load(lst + k);
            unsigned s1 = __builtin_nontemporal_load(lst + k + 1);
            uint4 a0 = xb[s0], a1 = xb[s1];
            agg[0] += bflo(a0.x) + bflo(a1.x);
            agg[1] += bfhi(a0.x) + bfhi(a1.x);
            agg[2] += bflo(a0.y) + bflo(a1.y);
            agg[3] += bfhi(a0.y) + bfhi(a1.y);
            agg[4] += bflo(a0.z) + bflo(a1.z);
            agg[5] += bfhi(a0.z) + bfhi(a1.z);
            agg[6] += bflo(a0.w) + bflo(a1.w);
        }
        if (k < end) {
            uint4 a0 = xb[__builtin_nontemporal_load(lst + k)];
            agg[0] += bflo(a0.x); agg[1] += bfhi(a0.x);
            agg[2] += bflo(a0.y); agg[3] += bfhi(a0.y);
            agg[4] += bflo(a0.z); agg[5] += bfhi(a0.z);
            agg[6] += bflo(a0.w);
        }
        uint4 ow = xb[i];
        float xv[FIN] = {bflo(ow.x), bfhi(ow.x), bflo(ow.y), bfhi(ow.y),
                         bflo(ow.z), bfhi(ow.z), bflo(ow.w)};
        unsigned short hh[FF1];
        #pragma unroll
        for (int j = 0; j < FF1; ++j) {
            float h = sb[j];
            #pragma unroll
            for (int q = 0; q < FIN; ++q) h += sWr[j * FIN + q] * agg[q] + sWo[j * FIN + q] * xv[q];
            hh[j] = f2bf(h);
        }
        unsigned* p = h1b + i * 6;
        nts_u2(p,     (unsigned)hh[0] | ((unsigned)hh[1] << 16),
                      (unsigned)hh[2] | ((unsigned)hh[3] << 16));
        nts_u2(p + 2, (unsigned)hh[4] | ((unsigned)hh[5] << 16),
                      (unsigned)hh[6] | ((unsigned)hh[7] << 16));
        nts_u2(p + 4, (unsigned)hh[8] | ((unsigned)hh[9] << 16),
                      (unsigned)hh[10]| ((unsigned)hh[11] << 16));
    }
}

// ---------------------------------------------------------------------------
// stats over bf16 24B rows (N x 12 packed in 6 dwords)
__global__ __launch_bounds__(256) void k_statsb(const unsigned* __restrict__ hb,
                                                double* __restrict__ stats) {
    __shared__ float red[4][FF1], redq[4][FF1];
    int t = threadIdx.x;
    float ps[FF1], pq[FF1];
    #pragma unroll
    for (int j = 0; j < FF1; ++j) { ps[j] = 0.f; pq[j] = 0.f; }
    for (size_t i = (size_t)blockIdx.x * 256 + t; i < NNODES; i += 256 * 256) {
        const uint2* r = (const uint2*)(hb + i * 6);
        uint2 u0 = r[0], u1 = r[1], u2 = r[2];
        float v[FF1] = {bflo(u0.x), bfhi(u0.x), bflo(u0.y), bfhi(u0.y),
                        bflo(u1.x), bfhi(u1.x), bflo(u1.y), bfhi(u1.y),
                        bflo(u2.x), bfhi(u2.x), bflo(u2.y), bfhi(u2.y)};
        #pragma unroll
        for (int j = 0; j < FF1; ++j) { ps[j] += v[j]; pq[j] += v[j] * v[j]; }
    }
    #pragma unroll
    for (int j = 0; j < FF1; ++j)
        for (int o = 1; o < 64; o <<= 1) { ps[j] += __shfl_xor(ps[j], o); pq[j] += __shfl_xor(pq[j], o); }
    int lane = t & 63, wv = t >> 6;
    if (lane == 0) {
        #pragma unroll
        for (int j = 0; j < FF1; ++j) { red[wv][j] = ps[j]; redq[wv][j] = pq[j]; }
    }
    __syncthreads();
    if (t < FF1) {
        float s = red[0][t] + red[1][t] + red[2][t] + red[3][t];
        float q = redq[0][t] + redq[1][t] + redq[2][t] + redq[3][t];
        atomicAdd(&stats[t], (double)s);
        atomicAdd(&stats[FF1 + t], (double)q);
    }
}

// ---------------------------------------------------------------------------
__global__ void k_finalize(const double* __restrict__ stats, const float* __restrict__ g,
                           const float* __restrict__ b, float* __restrict__ ss) {
    int j = threadIdx.x;
    if (j < FF1) {
        double mean = stats[j] * (1.0 / NNODES);
        double var  = stats[FF1 + j] * (1.0 / NNODES) - mean * mean;
        float sc = (float)((double)g[j] / sqrt(var + 1e-5));
        ss[j] = sc;
        ss[FF1 + j] = b[j] - (float)mean * sc;
    }
}

// ---------------------------------------------------------------------------
// y1p = relu(bn1(h1b)) as 16 bf16 (32B row, 4 pad); one node per thread.
__global__ __launch_bounds__(256) void k_y1(const unsigned* __restrict__ h1b,
                                            const float* __restrict__ ss,
                                            uint4* __restrict__ y1p) {
    __shared__ float sc[FF1], sh[FF1];
    int t = threadIdx.x;
    if (t < FF1) { sc[t] = ss[t]; sh[t] = ss[FF1 + t]; }
    __syncthreads();
    size_t i = (size_t)blockIdx.x * blockDim.x + t;
    if (i >= NNODES) return;
    const uint2* r = (const uint2*)(h1b + i * 6);
    uint2 u0 = r[0], u1 = r[1], u2 = r[2];
    float v[FF1] = {bflo(u0.x), bfhi(u0.x), bflo(u0.y), bfhi(u0.y),
                    bflo(u1.x), bfhi(u1.x), bflo(u1.y), bfhi(u1.y),
                    bflo(u2.x), bfhi(u2.x), bflo(u2.y), bfhi(u2.y)};
    unsigned short hh[FF1];
    #pragma unroll
    for (int j = 0; j < FF1; ++j) {
        float w = v[j] * sc[j] + sh[j];
        hh[j] = f2bf(w > 0.f ? w : 0.f);
    }
    uint4 w1, w2;
    w1.x = (unsigned)hh[0] | ((unsigned)hh[1] << 16);
    w1.y = (unsigned)hh[2] | ((unsigned)hh[3] << 16);
    w1.z = (unsigned)hh[4] | ((unsigned)hh[5] << 16);
    w1.w = (unsigned)hh[6] | ((unsigned)hh[7] << 16);
    w2.x = (unsigned)hh[8] | ((unsigned)hh[9] << 16);
    w2.y = (unsigned)hh[10]| ((unsigned)hh[11] << 16);
    w2.z = 0u; w2.w = 0u;
    y1p[i * 2]     = w1;
    y1p[i * 2 + 1] = w2;
}

// ---------------------------------------------------------------------------
// conv2: block per bucket; gather y1p (32B rows, no straddle); h2 bf16 out.
__global__ __launch_bounds__(256, 4) void k_conv2(const int* __restrict__ off,
                                                  const int* __restrict__ bend,
                                                  const unsigned* __restrict__ lst,
                                                  const uint4* __restrict__ y1p,
                                                  const float* __restrict__ Wrel,
                                                  const float* __restrict__ brel,
                                                  const float* __restrict__ Wroot,
                                                  unsigned* __restrict__ h2b) {
    __shared__ float sWr[FF2 * FF1], sWo[FF2 * FF1], sb[FF2];
    int t = threadIdx.x;
    if (t < FF2 * FF1) { sWr[t] = Wrel[t]; sWo[t] = Wroot[t]; }
    if (t < FF2) sb[t] = brel[t];
    __syncthreads();
    int bk = blockIdx.x;
    int be = bend[bk];
    #pragma unroll
    for (int n = 0; n < 4; ++n) {
        int li = n * 256 + t;
        size_t i = (size_t)bk * 1024 + li;
        int beg = off[i];
        int end = (li == 1023) ? be : off[i + 1];
        float agg[FF1];
        #pragma unroll
        for (int j = 0; j < FF1; ++j) agg[j] = 0.f;
        int k = beg;
        for (; k + 1 < end; k += 2) {
            unsigned s0 = __builtin_nontemporal_load(lst + k);
            unsigned s1 = __builtin_nontemporal_load(lst + k + 1);
            uint4 a0 = y1p[(size_t)s0 * 2], a1 = y1p[(size_t)s0 * 2 + 1];
            uint4 b0 = y1p[(size_t)s1 * 2], b1 = y1p[(size_t)s1 * 2 + 1];
            agg[0] += bflo(a0.x) + bflo(b0.x); agg[1]  += bfhi(a0.x) + bfhi(b0.x);
            agg[2] += bflo(a0.y) + bflo(b0.y); agg[3]  += bfhi(a0.y) + bfhi(b0.y);
            agg[4] += bflo(a0.z) + bflo(b0.z); agg[5]  += bfhi(a0.z) + bfhi(b0.z);
            agg[6] += bflo(a0.w) + bflo(b0.w); agg[7]  += bfhi(a0.w) + bfhi(b0.w);
            agg[8] += bflo(a1.x) + bflo(b1.x); agg[9]  += bfhi(a1.x) + bfhi(b1.x);
            agg[10]+= bflo(a1.y) + bflo(b1.y); agg[11] += bfhi(a1.y) + bfhi(b1.y);
        }
        if (k < end) {
            unsigned s0 = __builtin_nontemporal_load(lst + k);
            uint4 a0 = y1p[(size_t)s0 * 2], a1 = y1p[(size_t)s0 * 2 + 1];
            agg[0] += bflo(a0.x); agg[1]  += bfhi(a0.x);
            agg[2] += bflo(a0.y); agg[3]  += bfhi(a0.y);
            agg[4] += bflo(a0.z); agg[5]  += bfhi(a0.z);
            agg[6] += bflo(a0.w); agg[7]  += bfhi(a0.w);
            agg[8] += bflo(a1.x); agg[9]  += bfhi(a1.x);
            agg[10]+= bflo(a1.y); agg[11] += bfhi(a1.y);
        }
        uint4 o0 = y1p[i * 2], o1 = y1p[i * 2 + 1];
        float y[FF1] = {bflo(o0.x), bfhi(o0.x), bflo(o0.y), bfhi(o0.y),
                        bflo(o0.z), bfhi(o0.z), bflo(o0.w), bfhi(o0.w),
                        bflo(o1.x), bfhi(o1.x), bflo(o1.y), bfhi(o1.y)};
        unsigned short hh[FF2];
        #pragma unroll
        for (int j = 0; j < FF2; ++j) {
            float h = sb[j];
            #pragma unroll
            for (int q = 0; q < FF1; ++q) h += sWr[j * FF1 + q] * agg[q] + sWo[j * FF1 + q] * y[q];
            hh[j] = f2bf(h);
        }
        unsigned* p = h2b + i * 6;
        nts_u2(p,     (unsigned)hh[0] | ((unsigned)hh[1] << 16),
                      (unsigned)hh[2] | ((unsigned)hh[3] << 16));
        nts_u2(p + 2, (unsigned)hh[4] | ((unsigned)hh[5] << 16),
                      (unsigned)hh[6] | ((unsigned)hh[7] << 16));
        nts_u2(p + 4, (unsigned)hh[8] | ((unsigned)hh[9] << 16),
                      (unsigned)hh[10]| ((unsigned)hh[11] << 16));
    }
}

// ---------------------------------------------------------------------------
// GEMM1: A = relu(bn2(h2b)) bf16-stored, B = W1 f32; split-K=8 partials.
__global__ __launch_bounds__(256) void k_gemm1(const unsigned short* __restrict__ h2b,
                                               const float* __restrict__ ss2,
                                               const float* __restrict__ W1,
                                               float* __restrict__ hidp) {
    __shared__ float As[32][128];
    __shared__ float Bs[32][128];
    __shared__ float sc[FF2], sh[FF2];
    int t = threadIdx.x;
    if (t < FF2) { sc[t] = ss2[t]; sh[t] = ss2[FF2 + t]; }
    __syncthreads();
    int mb = blockIdx.x;
    int ks = blockIdx.y;
    const int KS = KDIM / 8;         // 1536
    int m0 = mb * 128;
    int kbase = ks * KS;
    int r  = t >> 1;
    int kg = t & 1;
    int tr = t >> 4;
    int tc = t & 15;
    float acc[8][8];
    #pragma unroll
    for (int i = 0; i < 8; ++i)
        #pragma unroll
        for (int j = 0; j < 8; ++j) acc[i][j] = 0.f;

    for (int kt = 0; kt < KS; kt += 32) {
        int c0 = kbase + kt + 16 * kg;
        const uint2* arow = (const uint2*)(h2b + (size_t)(m0 + r) * KDIM + c0);
        const float* brow = W1 + (size_t)r * KDIM + c0;
        #pragma unroll
        for (int i = 0; i < 4; ++i) {
            uint2 av = arow[i];
            int cc = c0 + 4 * i;
            int j0 = cc % FF2;
            float vals[4] = {bflo(av.x), bfhi(av.x), bflo(av.y), bfhi(av.y)};
            #pragma unroll
            for (int ii = 0; ii < 4; ++ii) {
                int j = j0 + ii; if (j >= FF2) j -= FF2;
                float v = vals[ii] * sc[j] + sh[j];
                As[16 * kg + 4 * i + ii][r] = v > 0.f ? v : 0.f;
            }
            float4 bv = *(const float4*)(brow + 4 * i);
            Bs[16 * kg + 4 * i + 0][r] = bv.x;
            Bs[16 * kg + 4 * i + 1][r] = bv.y;
            Bs[16 * kg + 4 * i + 2][r] = bv.z;
            Bs[16 * kg + 4 * i + 3][r] = bv.w;
        }
        __syncthreads();
        #pragma unroll
        for (int k = 0; k < 32; ++k) {
            float a[8], b[8];
            *(float4*)&a[0] = *(const float4*)&As[k][8 * tr];
            *(float4*)&a[4] = *(const float4*)&As[k][8 * tr + 4];
            *(float4*)&b[0] = *(const float4*)&Bs[k][8 * tc];
            *(float4*)&b[4] = *(const float4*)&Bs[k][8 * tc + 4];
            #pragma unroll
            for (int i = 0; i < 8; ++i)
                #pragma unroll
                for (int j = 0; j < 8; ++j) acc[i][j] += a[i] * b[j];
        }
        __syncthreads();
    }
    float* obase = hidp + (size_t)ks * (BATCHSZ * HIDD);
    #pragma unroll
    for (int i = 0; i < 8; ++i) {
        float* orow = obase + (size_t)(m0 + 8 * tr + i) * HIDD + 8 * tc;
        *(float4*)(orow)     = make_float4(acc[i][0], acc[i][1], acc[i][2], acc[i][3]);
        *(float4*)(orow + 4) = make_float4(acc[i][4], acc[i][5], acc[i][6], acc[i][7]);
    }
}

__global__ __launch_bounds__(256) void k_hred(const float* __restrict__ hidp,
                                              const float* __restrict__ bl1,
                                              float* __restrict__ hid) {
    int i = blockIdx.x * 256 + threadIdx.x;
    float s = bl1[i & (HIDD - 1)];
    #pragma unroll
    for (int p = 0; p < 8; ++p) s += hidp[(size_t)p * (BATCHSZ * HIDD) + i];
    hid[i] = s > 0.f ? s : 0.f;
}

// ---------------------------------------------------------------------------
__global__ __launch_bounds__(256) void k_gemm2(const float* __restrict__ hid,
                                               const float* __restrict__ W2,
                                               const float* __restrict__ bl2,
                                               float* __restrict__ out) {
    __shared__ float As[32][128];
    __shared__ float Bs[32][128];
    int t = threadIdx.x;
    int m0 = blockIdx.x * 128;
    int n0 = blockIdx.y * 128;
    int r  = t >> 1;
    int kg = t & 1;
    int tr = t >> 4;
    int tc = t & 15;
    float acc[8][8];
    #pragma unroll
    for (int i = 0; i < 8; ++i)
        #pragma unroll
        for (int j = 0; j < 8; ++j) acc[i][j] = 0.f;

    for (int kt = 0; kt < HIDD; kt += 32) {
        int c0 = kt + 16 * kg;
        #pragma unroll
        for (int i = 0; i < 4; ++i) {
            float4 av = *(const float4*)(hid + (size_t)(m0 + r) * HIDD + c0 + 4 * i);
            As[16 * kg + 4 * i + 0][r] = av.x;
            As[16 * kg + 4 * i + 1][r] = av.y;
            As[16 * kg + 4 * i + 2][r] = av.z;
            As[16 * kg + 4 * i + 3][r] = av.w;
            float4 bv = *(const float4*)(W2 + (size_t)(n0 + r) * HIDD + c0 + 4 * i);
            Bs[16 * kg + 4 * i + 0][r] = bv.x;
            Bs[16 * kg + 4 * i + 1][r] = bv.y;
            Bs[16 * kg + 4 * i + 2][r] = bv.z;
            Bs[16 * kg + 4 * i + 3][r] = bv.w;
        }
        __syncthreads();
        #pragma unroll
        for (int k = 0; k < 32; ++k) {
            float a[8], b[8];
            *(float4*)&a[0] = *(const float4*)&As[k][8 * tr];
            *(float4*)&a[4] = *(const float4*)&As[k][8 * tr + 4];
            *(float4*)&b[0] = *(const float4*)&Bs[k][8 * tc];
            *(float4*)&b[4] = *(const float4*)&Bs[k][8 * tc + 4];
            #pragma unroll
            for (int i = 0; i < 8; ++i)
                #pragma unroll
                for (int j = 0; j < 8; ++j) acc[i][j] += a[i] * b[j];
        }
        __syncthreads();
    }
    float4 c0v = *(const float4*)(bl2 + n0 + 8 * tc);
    float4 c1v = *(const float4*)(bl2 + n0 + 8 * tc + 4);
    float bvals[8] = {c0v.x, c0v.y, c0v.z, c0v.w, c1v.x, c1v.y, c1v.z, c1v.w};
    #pragma unroll
    for (int i = 0; i < 8; ++i) {
        size_t ro = (size_t)(m0 + 8 * tr + i) * ODIM + n0 + 8 * tc;
        *(float4*)(out + ro)     = make_float4(acc[i][0] + bvals[0], acc[i][1] + bvals[1],
                                               acc[i][2] + bvals[2], acc[i][3] + bvals[3]);
        *(float4*)(out + ro + 4) = make_float4(acc[i][4] + bvals[4], acc[i][5] + bvals[5],
                                               acc[i][6] + bvals[6], acc[i][7] + bvals[7]);
    }
}

// ---------------------------------------------------------------------------
extern "C" void kernel_launch(void* const* d_in, const int* in_sizes, int n_in,
                              void* d_out, int out_size, void* d_ws, size_t ws_size,
                              hipStream_t stream) {
    const float* x      = (const float*)d_in[0];
    const int*   ei     = (const int*)d_in[1];
    const float* Wrel1  = (const float*)d_in[3];
    const float* brel1  = (const float*)d_in[4];
    const float* Wroot1 = (const float*)d_in[5];
    const float* Wrel2  = (const float*)d_in[6];
    const float* brel2  = (const float*)d_in[7];
    const float* Wroot2 = (const float*)d_in[8];
    const float* g1     = (const float*)d_in[9];
    const float* b1     = (const float*)d_in[10];
    const float* g2     = (const float*)d_in[11];
    const float* b2     = (const float*)d_in[12];
    const float* W1     = (const float*)d_in[13];
    const float* bl1    = (const float*)d_in[14];
    const float* W2     = (const float*)d_in[15];
    const float* bl2    = (const float*)d_in[16];
    float* out = (float*)d_out;
    char* ws = (char*)d_ws;

    // Layout (liveness-overlaid), ~346 MB:
    //   pY  [0, SZ_YP):      xb(67MB) -> y1p(134MB)
    //   E   [SZ_YP, +SZ_E):  fine bucket slots (75.5MB)
    //   pB  [.., +SZ_BB):    ebufA spans pB..off-end (135.8MB) -> h1b -> {h2b, hidp, hid}
    //   off [.., +SZ_OFF)
    //   pK: bcur(16KB), bcurA(256B), smalls
    const size_t req = SZ_YP + SZ_E + SZ_BB + SZ_OFF + 32768;
    if (ws_size < req) {
        float v = (float)(ws_size >> 20);
        k_diag<<<(out_size + 255) / 256, 256, 0, stream>>>(out, out_size, v);
        return;
    }
    char* pY = ws;
    unsigned* ebuf = (unsigned*)(ws + SZ_YP);
    char* pB = ws + SZ_YP + SZ_E;
    int*  off = (int*)(ws + SZ_YP + SZ_E + SZ_BB);
    char* pK = ws + SZ_YP + SZ_E + SZ_BB + SZ_OFF;
    int*  bcur  = (int*)pK;                     // 4096 ints; ends after partB
    int*  bcurA = (int*)(pK + 16384);           // 64 ints; ends after partA
    char* smalls = pK + 20480;
    double* st1  = (double*)smalls;
    double* st2  = st1 + 2 * FF1;
    float*  ss1  = (float*)(st2 + 2 * FF2);
    float*  ss2  = ss1 + 2 * FF1;
    int*    flag = (int*)(ss2 + 2 * FF2);

    uint4*    xb    = (uint4*)pY;
    uint4*    y1p   = (uint4*)pY;
    unsigned* ebufA = (unsigned*)pB;            // 135.8MB, overlays pB+off (dead then)
    unsigned* h1b   = (unsigned*)pB;
    unsigned* h2b   = (unsigned*)pB;
    float*    hidp  = (float*)(pB + SZ_HB);
    float*    hid   = (float*)(pB + SZ_HB + 8 * SZ_HID);

    hipMemsetAsync(smalls, 0, 1024, stream);
    k_detect<<<1, 256, 0, stream>>>(ei, flag);
    k_binit <<<16, 256, 0, stream>>>(bcur, bcurA);
    k_padx  <<<NNODES / 4 / 256, 256, 0, stream>>>(x, xb);
    k_partA <<<512, 512, 0, stream>>>(ei, flag, bcurA, ebufA);
    k_partB <<<NCB * 4, 512, 0, stream>>>(ebufA, bcurA, bcur, ebuf);
    k_bsort <<<NBKT, 256, 0, stream>>>(bcur, ebuf, off);
    k_conv1 <<<NBKT, 256, 0, stream>>>(off, bcur, ebuf, xb, Wrel1, brel1, Wroot1, h1b);
    k_statsb<<<256, 256, 0, stream>>>(h1b, st1);
    k_finalize<<<1, 64, 0, stream>>>(st1, g1, b1, ss1);
    k_y1    <<<NNODES / 256, 256, 0, stream>>>(h1b, ss1, y1p);
    k_conv2 <<<NBKT, 256, 0, stream>>>(off, bcur, ebuf, y1p, Wrel2, brel2, Wroot2, h2b);
    k_statsb<<<256, 256, 0, stream>>>(h2b, st2);
    k_finalize<<<1, 64, 0, stream>>>(st2, g2, b2, ss2);
    k_gemm1<<<dim3(BATCHSZ / 128, 8), 256, 0, stream>>>((const unsigned short*)h2b, ss2, W1, hidp);
    k_hred <<<BATCHSZ * HIDD / 256, 256, 0, stream>>>(hidp, bl1, hid);
    k_gemm2<<<dim3(BATCHSZ / 128, ODIM / 128), 256, 0, stream>>>(hid, W2, bl2, out);
}

// Round 12
// 1555.183 us; speedup vs baseline: 1.2397x; 1.0066x over previous
//
#include <hip/hip_runtime.h>
#include <hip/hip_bf16.h>

#define NBUS    1024
#define BATCHSZ 4096
#define NNODES  (NBUS*BATCHSZ)      // 4194304 = 2^22
#define NEDGES  (4*NNODES)          // 16777216
#define FIN     7
#define FF1     12
#define FF2     12
#define HIDD    128
#define KDIM    (NBUS*FF2)          // 12288
#define ODIM    (NBUS*2)            // 2048
#define NBKT    4096                // fine buckets of 1024 dst nodes
#define CAP     4608                // fine bucket capacity (mean 4096 + 8 sigma)
#define NCB     64                  // coarse buckets of 65536 dst nodes
#define CAPA    265216              // coarse capacity (mean 262144 + 6 sigma)

#define SZ_P    ((size_t)NNODES * 32)                   // 134,217,728 (xb | h1p | h2b+hidp+hid)
#define SZ_HB   ((size_t)NNODES * FF2 * 2)              // 100,663,296 (h2b)
#define SZ_HID  ((size_t)BATCHSZ * HIDD * sizeof(float))//   2,097,152
#define SZ_E    ((size_t)NBKT * CAP * sizeof(unsigned)) //  75,497,472
#define SZ_OFF  ((size_t)NNODES * sizeof(int))          //  16,777,216
// ebufA (64*CAPA*8 = 135,790,592) overlays [pB .. pB+SZ_P+SZ_OFF) = 150,994,944

typedef unsigned u32x2v  __attribute__((ext_vector_type(2)));
typedef unsigned u32x4v  __attribute__((ext_vector_type(4)));

__device__ __forceinline__ float bflo(unsigned p){ return __uint_as_float(p << 16); }
__device__ __forceinline__ float bfhi(unsigned p){ return __uint_as_float(p & 0xffff0000u); }
__device__ __forceinline__ unsigned short f2bf(float f) {
    unsigned u = __float_as_uint(f);
    return (unsigned short)((u + 0x7fffu + ((u >> 16) & 1u)) >> 16);
}
__device__ __forceinline__ void nts_u2(unsigned* p, unsigned a, unsigned b) {
    u32x2v w; w.x = a; w.y = b;
    __builtin_nontemporal_store(w, (u32x2v*)p);
}
__device__ __forceinline__ void nts_u4(uint4* p, uint4 v) {
    u32x4v w; w.x = v.x; w.y = v.y; w.z = v.z; w.w = v.w;
    __builtin_nontemporal_store(w, (u32x4v*)p);
}
__device__ __forceinline__ uint2 ntl_u2(const unsigned* p) {
    u32x2v v = __builtin_nontemporal_load((const u32x2v*)p);
    uint2 r; r.x = v.x; r.y = v.y; return r;
}

// accumulate one xb row (8 bf16 in uint4) into agg[7]
__device__ __forceinline__ void acc7(float* agg, uint4 a) {
    agg[0] += bflo(a.x); agg[1] += bfhi(a.x);
    agg[2] += bflo(a.y); agg[3] += bfhi(a.y);
    agg[4] += bflo(a.z); agg[5] += bfhi(a.z);
    agg[6] += bflo(a.w);
}
// accumulate relu(bn1(h1p row)) into agg[12]
__device__ __forceinline__ void accY(float* agg, const float* sc, const float* sh,
                                     uint4 r0, uint4 r1) {
    float v[FF1] = {bflo(r0.x), bfhi(r0.x), bflo(r0.y), bfhi(r0.y),
                    bflo(r0.z), bfhi(r0.z), bflo(r0.w), bfhi(r0.w),
                    bflo(r1.x), bfhi(r1.x), bflo(r1.y), bfhi(r1.y)};
    #pragma unroll
    for (int j = 0; j < FF1; ++j) {
        float y = v[j] * sc[j] + sh[j];
        agg[j] += (y > 0.f ? y : 0.f);
    }
}

// ---------------------------------------------------------------------------
__global__ void k_diag(float* __restrict__ out, int n, float v) {
    size_t i = (size_t)blockIdx.x * blockDim.x + threadIdx.x;
    if (i < (size_t)n) out[i] = v;
}

__global__ void k_detect(const int* __restrict__ w, int* __restrict__ flag) {
    __shared__ int any;
    if (threadIdx.x == 0) any = 0;
    __syncthreads();
    int acc = 0;
    #pragma unroll
    for (int u = 0; u < 4; ++u) acc |= w[1 + 2 * (threadIdx.x * 4 + u)];
    if (acc) atomicOr(&any, 1);
    __syncthreads();
    if (threadIdx.x == 0) *flag = (any == 0) ? 2 : 1;
}

__global__ void k_binit(int* __restrict__ bcur, int* __restrict__ bcurA) {
    int u = blockIdx.x * 256 + threadIdx.x;
    if (u < NBKT) bcur[u] = u * CAP;
    if (u < NCB) bcurA[u] = u * CAPA;
}

// ---------------------------------------------------------------------------
// pass A: 64 coarse buckets (dst >> 16) as (src,dst); PLAIN stores (L2 merges).
__global__ __launch_bounds__(512) void k_partA(const int* __restrict__ ei,
                                               const int* __restrict__ flag,
                                               int* __restrict__ bcurA,
                                               unsigned* __restrict__ ebufA) {
    __shared__ int hist[NCB], lbase[NCB];
    int t = threadIdx.x;
    if (t < NCB) hist[t] = 0;
    __syncthreads();
    int mult = *flag;
    size_t base = (size_t)blockIdx.x * 32768;          // 512 blocks
    #pragma unroll 4
    for (int u = 0; u < 64; ++u) {
        size_t e = base + (size_t)u * 512 + t;
        int d = __builtin_nontemporal_load(ei + ((size_t)NEDGES + e) * mult);
        atomicAdd(&hist[d >> 16], 1);
    }
    __syncthreads();
    if (t < NCB) {
        int c = hist[t];
        lbase[t] = c ? atomicAdd(&bcurA[t], c) : 0;
        hist[t] = 0;
    }
    __syncthreads();
    #pragma unroll 4
    for (int u = 0; u < 64; ++u) {
        size_t e = base + (size_t)u * 512 + t;
        int s = __builtin_nontemporal_load(ei + e * mult);
        int d = __builtin_nontemporal_load(ei + ((size_t)NEDGES + e) * mult);
        int bk = d >> 16;
        int pos = lbase[bk] + atomicAdd(&hist[bk], 1);
        if (pos < (bk + 1) * CAPA) {
            uint2* p = (uint2*)(ebufA + (size_t)pos * 2);
            *p = make_uint2((unsigned)s, (unsigned)d);
        }
    }
}

// ---------------------------------------------------------------------------
// pass B: 4 blocks per coarse bucket -> 64 fine buckets, packed. Plain stores.
__global__ __launch_bounds__(512) void k_partB(const unsigned* __restrict__ ebufA,
                                               const int* __restrict__ bendA,
                                               int* __restrict__ bcur,
                                               unsigned* __restrict__ ebuf) {
    __shared__ int hist[NCB], lbase[NCB];
    int t = threadIdx.x;
    int cb = blockIdx.x >> 2;
    int qq = blockIdx.x & 3;
    int abeg = cb * CAPA;
    int n = bendA[cb] - abeg; if (n > CAPA) n = CAPA;
    int beg = abeg + (int)(((long long)n * qq) >> 2);
    int end = abeg + (int)(((long long)n * (qq + 1)) >> 2);
    if (t < NCB) hist[t] = 0;
    __syncthreads();
    for (int k = beg + t; k < end; k += 512) {
        uint2 e = ntl_u2(ebufA + (size_t)k * 2);
        atomicAdd(&hist[(e.y >> 10) & 63u], 1);
    }
    __syncthreads();
    if (t < NCB) {
        int c = hist[t];
        lbase[t] = c ? atomicAdd(&bcur[cb * 64 + t], c) : 0;
        hist[t] = 0;
    }
    __syncthreads();
    for (int k = beg + t; k < end; k += 512) {
        uint2 e = ntl_u2(ebufA + (size_t)k * 2);
        int lb = (e.y >> 10) & 63u;
        int fb = cb * 64 + lb;
        int pos = lbase[lb] + atomicAdd(&hist[lb], 1);
        if (pos < (fb + 1) * CAP)
            ebuf[pos] = (e.x << 10) | (e.y & 1023u);
    }
}

// ---------------------------------------------------------------------------
// per-bucket counting sort by dstLocal; ebuf becomes src-only sorted by dst.
__global__ __launch_bounds__(256) void k_bsort(const int* __restrict__ bend,
                                               unsigned* __restrict__ ebuf,
                                               int* __restrict__ off) {
    __shared__ unsigned stage[CAP];        // 18KB
    __shared__ int hist[1024];
    __shared__ int wsum[4];
    int t = threadIdx.x;
    int bk = blockIdx.x;
    int ebeg = bk * CAP;
    int n = bend[bk] - ebeg;
    if (n > CAP) n = CAP;
    for (int k = t; k < n; k += 256) stage[k] = __builtin_nontemporal_load(ebuf + ebeg + k);
    for (int u = t; u < 1024; u += 256) hist[u] = 0;
    __syncthreads();
    for (int k = t; k < n; k += 256) atomicAdd(&hist[stage[k] & 1023u], 1);
    __syncthreads();
    int v[4]; int s = 0;
    #pragma unroll
    for (int u = 0; u < 4; ++u) { v[u] = hist[t * 4 + u]; s += v[u]; }
    int lane = t & 63, w = t >> 6;
    int iv = s;
    for (int o = 1; o < 64; o <<= 1) { int uu = __shfl_up(iv, o); if (lane >= o) iv += uu; }
    if (lane == 63) wsum[w] = iv;
    __syncthreads();
    int basep = 0;
    #pragma unroll
    for (int ww = 0; ww < 4; ++ww) if (ww < w) basep += wsum[ww];
    int run = basep + iv - s;
    #pragma unroll
    for (int u = 0; u < 4; ++u) {
        off[(size_t)bk * 1024 + t * 4 + u] = ebeg + run;
        hist[t * 4 + u] = run;
        run += v[u];
    }
    __syncthreads();
    for (int k = t; k < n; k += 256) {
        unsigned p = stage[k];
        int pos = atomicAdd(&hist[p & 1023u], 1);
        ebuf[ebeg + pos] = p >> 10;
    }
}

// ---------------------------------------------------------------------------
__global__ __launch_bounds__(256) void k_padx(const float* __restrict__ x,
                                              uint4* __restrict__ xb) {
    size_t q = (size_t)blockIdx.x * blockDim.x + threadIdx.x;
    if (q >= NNODES / 4) return;
    const float4* xr = (const float4*)(x + q * 28);
    float v[28];
    #pragma unroll
    for (int u = 0; u < 7; ++u) {
        float4 f = xr[u];
        v[4*u] = f.x; v[4*u+1] = f.y; v[4*u+2] = f.z; v[4*u+3] = f.w;
    }
    #pragma unroll
    for (int n = 0; n < 4; ++n) {
        unsigned short h[8];
        #pragma unroll
        for (int j = 0; j < 7; ++j) h[j] = f2bf(v[7*n + j]);
        h[7] = 0;
        uint4 o;
        o.x = (unsigned)h[0] | ((unsigned)h[1] << 16);
        o.y = (unsigned)h[2] | ((unsigned)h[3] << 16);
        o.z = (unsigned)h[4] | ((unsigned)h[5] << 16);
        o.w = (unsigned)h[6] | ((unsigned)h[7] << 16);
        xb[q * 4 + n] = o;
    }
}

// ---------------------------------------------------------------------------
// conv1: block per bucket; unroll-4 gather of xb (16B rows); h1p 32B bf16 out.
__global__ __launch_bounds__(256, 4) void k_conv1(const int* __restrict__ off,
                                                  const int* __restrict__ bend,
                                                  const unsigned* __restrict__ lst,
                                                  const uint4* __restrict__ xb,
                                                  const float* __restrict__ Wrel,
                                                  const float* __restrict__ brel,
                                                  const float* __restrict__ Wroot,
                                                  uint4* __restrict__ h1p) {
    __shared__ float sWr[FF1 * FIN], sWo[FF1 * FIN], sb[FF1];
    int t = threadIdx.x;
    if (t < FF1 * FIN) { sWr[t] = Wrel[t]; sWo[t] = Wroot[t]; }
    if (t < FF1) sb[t] = brel[t];
    __syncthreads();
    int bk = blockIdx.x;
    int be = bend[bk];
    #pragma unroll
    for (int n = 0; n < 4; ++n) {
        int li = n * 256 + t;
        size_t i = (size_t)bk * 1024 + li;
        int beg = off[i];
        int end = (li == 1023) ? be : off[i + 1];
        float agg[FIN] = {0.f, 0.f, 0.f, 0.f, 0.f, 0.f, 0.f};
        int k = beg;
        for (; k + 3 < end; k += 4) {
            unsigned s0 = __builtin_nontemporal_load(lst + k);
            unsigned s1 = __builtin_nontemporal_load(lst + k + 1);
            unsigned s2 = __builtin_nontemporal_load(lst + k + 2);
            unsigned s3 = __builtin_nontemporal_load(lst + k + 3);
            uint4 a0 = xb[s0], a1 = xb[s1], a2 = xb[s2], a3 = xb[s3];
            acc7(agg, a0); acc7(agg, a1); acc7(agg, a2); acc7(agg, a3);
        }
        for (; k < end; ++k)
            acc7(agg, xb[__builtin_nontemporal_load(lst + k)]);
        uint4 ow = xb[i];
        float xv[FIN] = {bflo(ow.x), bfhi(ow.x), bflo(ow.y), bfhi(ow.y),
                         bflo(ow.z), bfhi(ow.z), bflo(ow.w)};
        unsigned short hh[FF1];
        #pragma unroll
        for (int j = 0; j < FF1; ++j) {
            float h = sb[j];
            #pragma unroll
            for (int q = 0; q < FIN; ++q) h += sWr[j * FIN + q] * agg[q] + sWo[j * FIN + q] * xv[q];
            hh[j] = f2bf(h);
        }
        uint4 w1, w2;
        w1.x = (unsigned)hh[0] | ((unsigned)hh[1] << 16);
        w1.y = (unsigned)hh[2] | ((unsigned)hh[3] << 16);
        w1.z = (unsigned)hh[4] | ((unsigned)hh[5] << 16);
        w1.w = (unsigned)hh[6] | ((unsigned)hh[7] << 16);
        w2.x = (unsigned)hh[8] | ((unsigned)hh[9] << 16);
        w2.y = (unsigned)hh[10]| ((unsigned)hh[11] << 16);
        w2.z = 0u; w2.w = 0u;
        nts_u4(h1p + i * 2, w1);
        nts_u4(h1p + i * 2 + 1, w2);
    }
}

// ---------------------------------------------------------------------------
// stats over bf16 rows (first 12 bf16 of each row; STRIDE dwords per row)
template<int STRIDE>
__global__ __launch_bounds__(256) void k_statsb(const unsigned* __restrict__ hb,
                                                double* __restrict__ stats) {
    __shared__ float red[4][FF1], redq[4][FF1];
    int t = threadIdx.x;
    float ps[FF1], pq[FF1];
    #pragma unroll
    for (int j = 0; j < FF1; ++j) { ps[j] = 0.f; pq[j] = 0.f; }
    for (size_t i = (size_t)blockIdx.x * 256 + t; i < NNODES; i += 256 * 256) {
        const uint2* r = (const uint2*)(hb + i * STRIDE);
        uint2 u0 = r[0], u1 = r[1], u2 = r[2];
        float v[FF1] = {bflo(u0.x), bfhi(u0.x), bflo(u0.y), bfhi(u0.y),
                        bflo(u1.x), bfhi(u1.x), bflo(u1.y), bfhi(u1.y),
                        bflo(u2.x), bfhi(u2.x), bflo(u2.y), bfhi(u2.y)};
        #pragma unroll
        for (int j = 0; j < FF1; ++j) { ps[j] += v[j]; pq[j] += v[j] * v[j]; }
    }
    #pragma unroll
    for (int j = 0; j < FF1; ++j)
        for (int o = 1; o < 64; o <<= 1) { ps[j] += __shfl_xor(ps[j], o); pq[j] += __shfl_xor(pq[j], o); }
    int lane = t & 63, wv = t >> 6;
    if (lane == 0) {
        #pragma unroll
        for (int j = 0; j < FF1; ++j) { red[wv][j] = ps[j]; redq[wv][j] = pq[j]; }
    }
    __syncthreads();
    if (t < FF1) {
        float s = red[0][t] + red[1][t] + red[2][t] + red[3][t];
        float q = redq[0][t] + redq[1][t] + redq[2][t] + redq[3][t];
        atomicAdd(&stats[t], (double)s);
        atomicAdd(&stats[FF1 + t], (double)q);
    }
}

// ---------------------------------------------------------------------------
__global__ void k_finalize(const double* __restrict__ stats, const float* __restrict__ g,
                           const float* __restrict__ b, float* __restrict__ ss) {
    int j = threadIdx.x;
    if (j < FF1) {
        double mean = stats[j] * (1.0 / NNODES);
        double var  = stats[FF1 + j] * (1.0 / NNODES) - mean * mean;
        float sc = (float)((double)g[j] / sqrt(var + 1e-5));
        ss[j] = sc;
        ss[FF1 + j] = b[j] - (float)mean * sc;
    }
}

// ---------------------------------------------------------------------------
// conv2: block per bucket; unroll-4 gather of h1p (32B rows); bn1+relu inline;
// h2 bf16 (24B rows) nt out.
__global__ __launch_bounds__(256, 4) void k_conv2(const int* __restrict__ off,
                                                  const int* __restrict__ bend,
                                                  const unsigned* __restrict__ lst,
                                                  const uint4* __restrict__ h1p,
                                                  const float* __restrict__ ss,
                                                  const float* __restrict__ Wrel,
                                                  const float* __restrict__ brel,
                                                  const float* __restrict__ Wroot,
                                                  unsigned* __restrict__ h2b) {
    __shared__ float sWr[FF2 * FF1], sWo[FF2 * FF1], sb[FF2], sc[FF1], sh[FF1];
    int t = threadIdx.x;
    if (t < FF2 * FF1) { sWr[t] = Wrel[t]; sWo[t] = Wroot[t]; }
    if (t < FF2) { sb[t] = brel[t]; sc[t] = ss[t]; sh[t] = ss[FF1 + t]; }
    __syncthreads();
    int bk = blockIdx.x;
    int be = bend[bk];
    #pragma unroll
    for (int n = 0; n < 4; ++n) {
        int li = n * 256 + t;
        size_t i = (size_t)bk * 1024 + li;
        int beg = off[i];
        int end = (li == 1023) ? be : off[i + 1];
        float agg[FF1];
        #pragma unroll
        for (int j = 0; j < FF1; ++j) agg[j] = 0.f;
        int k = beg;
        for (; k + 3 < end; k += 4) {
            unsigned s0 = __builtin_nontemporal_load(lst + k);
            unsigned s1 = __builtin_nontemporal_load(lst + k + 1);
            unsigned s2 = __builtin_nontemporal_load(lst + k + 2);
            unsigned s3 = __builtin_nontemporal_load(lst + k + 3);
            uint4 a0 = h1p[(size_t)s0 * 2], a1 = h1p[(size_t)s0 * 2 + 1];
            uint4 b0 = h1p[(size_t)s1 * 2], b1 = h1p[(size_t)s1 * 2 + 1];
            uint4 c0 = h1p[(size_t)s2 * 2], c1 = h1p[(size_t)s2 * 2 + 1];
            uint4 d0 = h1p[(size_t)s3 * 2], d1 = h1p[(size_t)s3 * 2 + 1];
            accY(agg, sc, sh, a0, a1);
            accY(agg, sc, sh, b0, b1);
            accY(agg, sc, sh, c0, c1);
            accY(agg, sc, sh, d0, d1);
        }
        for (; k < end; ++k) {
            unsigned s0 = __builtin_nontemporal_load(lst + k);
            accY(agg, sc, sh, h1p[(size_t)s0 * 2], h1p[(size_t)s0 * 2 + 1]);
        }
        uint4 o0 = h1p[i * 2], o1 = h1p[i * 2 + 1];
        float vо[FF1] = {bflo(o0.x), bfhi(o0.x), bflo(o0.y), bfhi(o0.y),
                         bflo(o0.z), bfhi(o0.z), bflo(o0.w), bfhi(o0.w),
                         bflo(o1.x), bfhi(o1.x), bflo(o1.y), bfhi(o1.y)};
        float y[FF1];
        #pragma unroll
        for (int j = 0; j < FF1; ++j) {
            float w = vо[j] * sc[j] + sh[j];
            y[j] = w > 0.f ? w : 0.f;
        }
        unsigned short hh[FF2];
        #pragma unroll
        for (int j = 0; j < FF2; ++j) {
            float h = sb[j];
            #pragma unroll
            for (int q = 0; q < FF1; ++q) h += sWr[j * FF1 + q] * agg[q] + sWo[j * FF1 + q] * y[q];
            hh[j] = f2bf(h);
        }
        unsigned* p = h2b + i * 6;
        nts_u2(p,     (unsigned)hh[0] | ((unsigned)hh[1] << 16),
                      (unsigned)hh[2] | ((unsigned)hh[3] << 16));
        nts_u2(p + 2, (unsigned)hh[4] | ((unsigned)hh[5] << 16),
                      (unsigned)hh[6] | ((unsigned)hh[7] << 16));
        nts_u2(p + 4, (unsigned)hh[8] | ((unsigned)hh[9] << 16),
                      (unsigned)hh[10]| ((unsigned)hh[11] << 16));
    }
}

// ---------------------------------------------------------------------------
// GEMM1: A = relu(bn2(h2b)) bf16-stored, B = W1 f32; split-K=8 partials.
__global__ __launch_bounds__(256) void k_gemm1(const unsigned short* __restrict__ h2b,
                                               const float* __restrict__ ss2,
                                               const float* __restrict__ W1,
                                               float* __restrict__ hidp) {
    __shared__ float As[32][128];
    __shared__ float Bs[32][128];
    __shared__ float sc[FF2], sh[FF2];
    int t = threadIdx.x;
    if (t < FF2) { sc[t] = ss2[t]; sh[t] = ss2[FF2 + t]; }
    __syncthreads();
    int mb = blockIdx.x;
    int ks = blockIdx.y;
    const int KS = KDIM / 8;         // 1536
    int m0 = mb * 128;
    int kbase = ks * KS;
    int r  = t >> 1;
    int kg = t & 1;
    int tr = t >> 4;
    int tc = t & 15;
    float acc[8][8];
    #pragma unroll
    for (int i = 0; i < 8; ++i)
        #pragma unroll
        for (int j = 0; j < 8; ++j) acc[i][j] = 0.f;

    for (int kt = 0; kt < KS; kt += 32) {
        int c0 = kbase + kt + 16 * kg;
        const uint2* arow = (const uint2*)(h2b + (size_t)(m0 + r) * KDIM + c0);
        const float* brow = W1 + (size_t)r * KDIM + c0;
        #pragma unroll
        for (int i = 0; i < 4; ++i) {
            uint2 av = arow[i];
            int cc = c0 + 4 * i;
            int j0 = cc % FF2;
            float vals[4] = {bflo(av.x), bfhi(av.x), bflo(av.y), bfhi(av.y)};
            #pragma unroll
            for (int ii = 0; ii < 4; ++ii) {
                int j = j0 + ii; if (j >= FF2) j -= FF2;
                float v = vals[ii] * sc[j] + sh[j];
                As[16 * kg + 4 * i + ii][r] = v > 0.f ? v : 0.f;
            }
            float4 bv = *(const float4*)(brow + 4 * i);
            Bs[16 * kg + 4 * i + 0][r] = bv.x;
            Bs[16 * kg + 4 * i + 1][r] = bv.y;
            Bs[16 * kg + 4 * i + 2][r] = bv.z;
            Bs[16 * kg + 4 * i + 3][r] = bv.w;
        }
        __syncthreads();
        #pragma unroll
        for (int k = 0; k < 32; ++k) {
            float a[8], b[8];
            *(float4*)&a[0] = *(const float4*)&As[k][8 * tr];
            *(float4*)&a[4] = *(const float4*)&As[k][8 * tr + 4];
            *(float4*)&b[0] = *(const float4*)&Bs[k][8 * tc];
            *(float4*)&b[4] = *(const float4*)&Bs[k][8 * tc + 4];
            #pragma unroll
            for (int i = 0; i < 8; ++i)
                #pragma unroll
                for (int j = 0; j < 8; ++j) acc[i][j] += a[i] * b[j];
        }
        __syncthreads();
    }
    float* obase = hidp + (size_t)ks * (BATCHSZ * HIDD);
    #pragma unroll
    for (int i = 0; i < 8; ++i) {
        float* orow = obase + (size_t)(m0 + 8 * tr + i) * HIDD + 8 * tc;
        *(float4*)(orow)     = make_float4(acc[i][0], acc[i][1], acc[i][2], acc[i][3]);
        *(float4*)(orow + 4) = make_float4(acc[i][4], acc[i][5], acc[i][6], acc[i][7]);
    }
}

__global__ __launch_bounds__(256) void k_hred(const float* __restrict__ hidp,
                                              const float* __restrict__ bl1,
                                              float* __restrict__ hid) {
    int i = blockIdx.x * 256 + threadIdx.x;
    float s = bl1[i & (HIDD - 1)];
    #pragma unroll
    for (int p = 0; p < 8; ++p) s += hidp[(size_t)p * (BATCHSZ * HIDD) + i];
    hid[i] = s > 0.f ? s : 0.f;
}

// ---------------------------------------------------------------------------
__global__ __launch_bounds__(256) void k_gemm2(const float* __restrict__ hid,
                                               const float* __restrict__ W2,
                                               const float* __restrict__ bl2,
                                               float* __restrict__ out) {
    __shared__ float As[32][128];
    __shared__ float Bs[32][128];
    int t = threadIdx.x;
    int m0 = blockIdx.x * 128;
    int n0 = blockIdx.y * 128;
    int r  = t >> 1;
    int kg = t & 1;
    int tr = t >> 4;
    int tc = t & 15;
    float acc[8][8];
    #pragma unroll
    for (int i = 0; i < 8; ++i)
        #pragma unroll
        for (int j = 0; j < 8; ++j) acc[i][j] = 0.f;

    for (int kt = 0; kt < HIDD; kt += 32) {
        int c0 = kt + 16 * kg;
        #pragma unroll
        for (int i = 0; i < 4; ++i) {
            float4 av = *(const float4*)(hid + (size_t)(m0 + r) * HIDD + c0 + 4 * i);
            As[16 * kg + 4 * i + 0][r] = av.x;
            As[16 * kg + 4 * i + 1][r] = av.y;
            As[16 * kg + 4 * i + 2][r] = av.z;
            As[16 * kg + 4 * i + 3][r] = av.w;
            float4 bv = *(const float4*)(W2 + (size_t)(n0 + r) * HIDD + c0 + 4 * i);
            Bs[16 * kg + 4 * i + 0][r] = bv.x;
            Bs[16 * kg + 4 * i + 1][r] = bv.y;
            Bs[16 * kg + 4 * i + 2][r] = bv.z;
            Bs[16 * kg + 4 * i + 3][r] = bv.w;
        }
        __syncthreads();
        #pragma unroll
        for (int k = 0; k < 32; ++k) {
            float a[8], b[8];
            *(float4*)&a[0] = *(const float4*)&As[k][8 * tr];
            *(float4*)&a[4] = *(const float4*)&As[k][8 * tr + 4];
            *(float4*)&b[0] = *(const float4*)&Bs[k][8 * tc];
            *(float4*)&b[4] = *(const float4*)&Bs[k][8 * tc + 4];
            #pragma unroll
            for (int i = 0; i < 8; ++i)
                #pragma unroll
                for (int j = 0; j < 8; ++j) acc[i][j] += a[i] * b[j];
        }
        __syncthreads();
    }
    float4 c0v = *(const float4*)(bl2 + n0 + 8 * tc);
    float4 c1v = *(const float4*)(bl2 + n0 + 8 * tc + 4);
    float bvals[8] = {c0v.x, c0v.y, c0v.z, c0v.w, c1v.x, c1v.y, c1v.z, c1v.w};
    #pragma unroll
    for (int i = 0; i < 8; ++i) {
        size_t ro = (size_t)(m0 + 8 * tr + i) * ODIM + n0 + 8 * tc;
        *(float4*)(out + ro)     = make_float4(acc[i][0] + bvals[0], acc[i][1] + bvals[1],
                                               acc[i][2] + bvals[2], acc[i][3] + bvals[3]);
        *(float4*)(out + ro + 4) = make_float4(acc[i][4] + bvals[4], acc[i][5] + bvals[5],
                                               acc[i][6] + bvals[6], acc[i][7] + bvals[7]);
    }
}

// ---------------------------------------------------------------------------
extern "C" void kernel_launch(void* const* d_in, const int* in_sizes, int n_in,
                              void* d_out, int out_size, void* d_ws, size_t ws_size,
                              hipStream_t stream) {
    const float* x      = (const float*)d_in[0];
    const int*   ei     = (const int*)d_in[1];
    const float* Wrel1  = (const float*)d_in[3];
    const float* brel1  = (const float*)d_in[4];
    const float* Wroot1 = (const float*)d_in[5];
    const float* Wrel2  = (const float*)d_in[6];
    const float* brel2  = (const float*)d_in[7];
    const float* Wroot2 = (const float*)d_in[8];
    const float* g1     = (const float*)d_in[9];
    const float* b1     = (const float*)d_in[10];
    const float* g2     = (const float*)d_in[11];
    const float* b2     = (const float*)d_in[12];
    const float* W1     = (const float*)d_in[13];
    const float* bl1    = (const float*)d_in[14];
    const float* W2     = (const float*)d_in[15];
    const float* bl2    = (const float*)d_in[16];
    float* out = (float*)d_out;
    char* ws = (char*)d_ws;

    // Layout (liveness-overlaid), ~361 MB:
    //   pY  [0, SZ_P):       xb(67MB) -> [after conv1] h2b(100MB)+hidp(16MB)+hid(2MB)
    //   E   [SZ_P, +SZ_E):   fine bucket slots (75.5MB)
    //   pB  [.., +SZ_P):     ebufA(135.8MB, spills into off) -> h1p(134MB)
    //   off [.., +SZ_OFF)    written by bsort after ebufA dead
    //   pK: bcur(16KB), bcurA(256B), smalls
    const size_t req = SZ_P + SZ_E + SZ_P + SZ_OFF + 32768;
    if (ws_size < req) {
        float v = (float)(ws_size >> 20);
        k_diag<<<(out_size + 255) / 256, 256, 0, stream>>>(out, out_size, v);
        return;
    }
    char* pY = ws;
    unsigned* ebuf = (unsigned*)(ws + SZ_P);
    char* pB = ws + SZ_P + SZ_E;
    int*  off = (int*)(ws + SZ_P + SZ_E + SZ_P);
    char* pK = ws + SZ_P + SZ_E + SZ_P + SZ_OFF;
    int*  bcur  = (int*)pK;                     // 4096 ints; ends after partB
    int*  bcurA = (int*)(pK + 16384);           // 64 ints; ends after partA
    char* smalls = pK + 20480;
    double* st1  = (double*)smalls;
    double* st2  = st1 + 2 * FF1;
    float*  ss1  = (float*)(st2 + 2 * FF2);
    float*  ss2  = ss1 + 2 * FF1;
    int*    flag = (int*)(ss2 + 2 * FF2);

    uint4*    xb    = (uint4*)pY;
    unsigned* h2b   = (unsigned*)pY;
    float*    hidp  = (float*)(pY + SZ_HB);
    float*    hid   = (float*)(pY + SZ_HB + 8 * SZ_HID);
    unsigned* ebufA = (unsigned*)pB;            // 135.8MB, overlays pB+off (dead then)
    uint4*    h1p   = (uint4*)pB;

    hipMemsetAsync(smalls, 0, 1024, stream);
    k_detect<<<1, 256, 0, stream>>>(ei, flag);
    k_binit <<<16, 256, 0, stream>>>(bcur, bcurA);
    k_padx  <<<NNODES / 4 / 256, 256, 0, stream>>>(x, xb);
    k_partA <<<512, 512, 0, stream>>>(ei, flag, bcurA, ebufA);
    k_partB <<<NCB * 4, 512, 0, stream>>>(ebufA, bcurA, bcur, ebuf);
    k_bsort <<<NBKT, 256, 0, stream>>>(bcur, ebuf, off);
    k_conv1 <<<NBKT, 256, 0, stream>>>(off, bcur, ebuf, xb, Wrel1, brel1, Wroot1, h1p);
    k_statsb<8><<<256, 256, 0, stream>>>((const unsigned*)h1p, st1);
    k_finalize<<<1, 64, 0, stream>>>(st1, g1, b1, ss1);
    k_conv2 <<<NBKT, 256, 0, stream>>>(off, bcur, ebuf, h1p, ss1, Wrel2, brel2, Wroot2, h2b);
    k_statsb<6><<<256, 256, 0, stream>>>(h2b, st2);
    k_finalize<<<1, 64, 0, stream>>>(st2, g2, b2, ss2);
    k_gemm1<<<dim3(BATCHSZ / 128, 8), 256, 0, stream>>>((const unsigned short*)h2b, ss2, W1, hidp);
    k_hred <<<BATCHSZ * HIDD / 256, 256, 0, stream>>>(hidp, bl1, hid);
    k_gemm2<<<dim3(BATCHSZ / 128, ODIM / 128), 256, 0, stream>>>(hid, W2, bl2, out);
}

// Round 13
// 1520.604 us; speedup vs baseline: 1.2679x; 1.0227x over previous
//
#include <hip/hip_runtime.h>
#include <hip/hip_bf16.h>

#define NBUS    1024
#define BATCHSZ 4096
#define NNODES  (NBUS*BATCHSZ)      // 4194304 = 2^22
#define NEDGES  (4*NNODES)          // 16777216
#define FIN     7
#define FF1     12
#define FF2     12
#define HIDD    128
#define KDIM    (NBUS*FF2)          // 12288
#define ODIM    (NBUS*2)            // 2048
#define NBKT    4096                // fine buckets of 1024 dst nodes
#define CAP     4608                // fine bucket capacity (mean 4096 + 8 sigma)
#define ITPT    18                  // CAP / 256
#define NCB     64                  // coarse buckets of 65536 dst nodes
#define CAPA    265216              // coarse capacity (mean 262144 + 6 sigma)

#define SZ_P    ((size_t)NNODES * 32)                   // 134,217,728 (xb -> h2b+hidp+hid)
#define SZ_HB   ((size_t)NNODES * FF2 * 2)              // 100,663,296 (h2b)
#define SZ_HID  ((size_t)BATCHSZ * HIDD * sizeof(float))//   2,097,152
#define SZ_E    ((size_t)NBKT * CAP * sizeof(unsigned)) //  75,497,472
#define SZ_PB   ((size_t)NCB * CAPA * 8)                // 135,790,592 (ebufA -> h1p)

typedef unsigned u32x2v  __attribute__((ext_vector_type(2)));
typedef unsigned u32x4v  __attribute__((ext_vector_type(4)));

__device__ __forceinline__ float bflo(unsigned p){ return __uint_as_float(p << 16); }
__device__ __forceinline__ float bfhi(unsigned p){ return __uint_as_float(p & 0xffff0000u); }
__device__ __forceinline__ unsigned short f2bf(float f) {
    unsigned u = __float_as_uint(f);
    return (unsigned short)((u + 0x7fffu + ((u >> 16) & 1u)) >> 16);
}
__device__ __forceinline__ void nts_u2(unsigned* p, unsigned a, unsigned b) {
    u32x2v w; w.x = a; w.y = b;
    __builtin_nontemporal_store(w, (u32x2v*)p);
}
__device__ __forceinline__ void nts_u4(uint4* p, uint4 v) {
    u32x4v w; w.x = v.x; w.y = v.y; w.z = v.z; w.w = v.w;
    __builtin_nontemporal_store(w, (u32x4v*)p);
}
__device__ __forceinline__ uint2 ntl_u2(const unsigned* p) {
    u32x2v v = __builtin_nontemporal_load((const u32x2v*)p);
    uint2 r; r.x = v.x; r.y = v.y; return r;
}

__device__ __forceinline__ void acc7(float* agg, uint4 a) {
    agg[0] += bflo(a.x); agg[1] += bfhi(a.x);
    agg[2] += bflo(a.y); agg[3] += bfhi(a.y);
    agg[4] += bflo(a.z); agg[5] += bfhi(a.z);
    agg[6] += bflo(a.w);
}
__device__ __forceinline__ void accY(float* agg, const float* sc, const float* sh,
                                     uint4 r0, uint4 r1) {
    float v[FF1] = {bflo(r0.x), bfhi(r0.x), bflo(r0.y), bfhi(r0.y),
                    bflo(r0.z), bfhi(r0.z), bflo(r0.w), bfhi(r0.w),
                    bflo(r1.x), bfhi(r1.x), bflo(r1.y), bfhi(r1.y)};
    #pragma unroll
    for (int j = 0; j < FF1; ++j) {
        float y = v[j] * sc[j] + sh[j];
        agg[j] += (y > 0.f ? y : 0.f);
    }
}

// ---------------------------------------------------------------------------
__global__ void k_diag(float* __restrict__ out, int n, float v) {
    size_t i = (size_t)blockIdx.x * blockDim.x + threadIdx.x;
    if (i < (size_t)n) out[i] = v;
}

// init cursors + int64/int32 detection (block 0)
__global__ void k_init(const int* __restrict__ w, int* __restrict__ flag,
                       int* __restrict__ bcur, int* __restrict__ bcurA) {
    int u = blockIdx.x * 256 + threadIdx.x;
    if (u < NBKT) bcur[u] = u * CAP;
    if (u < NCB) bcurA[u] = u * CAPA;
    if (blockIdx.x == 0) {
        __shared__ int any;
        if (threadIdx.x == 0) any = 0;
        __syncthreads();
        int acc = 0;
        #pragma unroll
        for (int q = 0; q < 4; ++q) acc |= w[1 + 2 * (threadIdx.x * 4 + q)];
        if (acc) atomicOr(&any, 1);
        __syncthreads();
        if (threadIdx.x == 0) *flag = (any == 0) ? 2 : 1;
    }
}

// ---------------------------------------------------------------------------
// pass A: 64 coarse buckets (dst >> 16) as (src,dst); plain stores (L2 merges).
__global__ __launch_bounds__(512) void k_partA(const int* __restrict__ ei,
                                               const int* __restrict__ flag,
                                               int* __restrict__ bcurA,
                                               unsigned* __restrict__ ebufA) {
    __shared__ int hist[NCB], lbase[NCB];
    int t = threadIdx.x;
    if (t < NCB) hist[t] = 0;
    __syncthreads();
    int mult = *flag;
    size_t base = (size_t)blockIdx.x * 32768;          // 512 blocks
    #pragma unroll 4
    for (int u = 0; u < 64; ++u) {
        size_t e = base + (size_t)u * 512 + t;
        int d = __builtin_nontemporal_load(ei + ((size_t)NEDGES + e) * mult);
        atomicAdd(&hist[d >> 16], 1);
    }
    __syncthreads();
    if (t < NCB) {
        int c = hist[t];
        lbase[t] = c ? atomicAdd(&bcurA[t], c) : 0;
        hist[t] = 0;
    }
    __syncthreads();
    #pragma unroll 4
    for (int u = 0; u < 64; ++u) {
        size_t e = base + (size_t)u * 512 + t;
        int s = __builtin_nontemporal_load(ei + e * mult);
        int d = __builtin_nontemporal_load(ei + ((size_t)NEDGES + e) * mult);
        int bk = d >> 16;
        int pos = lbase[bk] + atomicAdd(&hist[bk], 1);
        if (pos < (bk + 1) * CAPA) {
            uint2* p = (uint2*)(ebufA + (size_t)pos * 2);
            *p = make_uint2((unsigned)s, (unsigned)d);
        }
    }
}

// ---------------------------------------------------------------------------
// pass B: 4 blocks per coarse bucket -> 64 fine buckets, packed. Plain stores.
__global__ __launch_bounds__(512) void k_partB(const unsigned* __restrict__ ebufA,
                                               const int* __restrict__ bendA,
                                               int* __restrict__ bcur,
                                               unsigned* __restrict__ ebuf) {
    __shared__ int hist[NCB], lbase[NCB];
    int t = threadIdx.x;
    int cb = blockIdx.x >> 2;
    int qq = blockIdx.x & 3;
    int abeg = cb * CAPA;
    int n = bendA[cb] - abeg; if (n > CAPA) n = CAPA;
    int beg = abeg + (int)(((long long)n * qq) >> 2);
    int end = abeg + (int)(((long long)n * (qq + 1)) >> 2);
    if (t < NCB) hist[t] = 0;
    __syncthreads();
    for (int k = beg + t; k < end; k += 512) {
        uint2 e = ntl_u2(ebufA + (size_t)k * 2);
        atomicAdd(&hist[(e.y >> 10) & 63u], 1);
    }
    __syncthreads();
    if (t < NCB) {
        int c = hist[t];
        lbase[t] = c ? atomicAdd(&bcur[cb * 64 + t], c) : 0;
        hist[t] = 0;
    }
    __syncthreads();
    for (int k = beg + t; k < end; k += 512) {
        uint2 e = ntl_u2(ebufA + (size_t)k * 2);
        int lb = (e.y >> 10) & 63u;
        int fb = cb * 64 + lb;
        int pos = lbase[lb] + atomicAdd(&hist[lb], 1);
        if (pos < (fb + 1) * CAP)
            ebuf[pos] = (e.x << 10) | (e.y & 1023u);
    }
}

// ---------------------------------------------------------------------------
__global__ __launch_bounds__(256) void k_padx(const float* __restrict__ x,
                                              uint4* __restrict__ xb) {
    size_t q = (size_t)blockIdx.x * blockDim.x + threadIdx.x;
    if (q >= NNODES / 4) return;
    const float4* xr = (const float4*)(x + q * 28);
    float v[28];
    #pragma unroll
    for (int u = 0; u < 7; ++u) {
        float4 f = xr[u];
        v[4*u] = f.x; v[4*u+1] = f.y; v[4*u+2] = f.z; v[4*u+3] = f.w;
    }
    #pragma unroll
    for (int n = 0; n < 4; ++n) {
        unsigned short h[8];
        #pragma unroll
        for (int j = 0; j < 7; ++j) h[j] = f2bf(v[7*n + j]);
        h[7] = 0;
        uint4 o;
        o.x = (unsigned)h[0] | ((unsigned)h[1] << 16);
        o.y = (unsigned)h[2] | ((unsigned)h[3] << 16);
        o.z = (unsigned)h[4] | ((unsigned)h[5] << 16);
        o.w = (unsigned)h[6] | ((unsigned)h[7] << 16);
        xb[q * 4 + n] = o;
    }
}

// ---------------------------------------------------------------------------
// conv1: per fine bucket: load unsorted bucket -> regs, in-LDS counting sort by
// dstLocal, gather xb from LDS-resident src list, BN1 stats fused, h1p bf16 out.
__global__ __launch_bounds__(256) void k_conv1(const int* __restrict__ bend,
                                               const unsigned* __restrict__ ebuf,
                                               const uint4* __restrict__ xb,
                                               const float* __restrict__ Wrel,
                                               const float* __restrict__ brel,
                                               const float* __restrict__ Wroot,
                                               uint4* __restrict__ h1p,
                                               double* __restrict__ stats) {
    __shared__ unsigned stage[CAP];     // 18KB (sorted srcs)
    __shared__ int hist[1024];          // counts -> cursors
    __shared__ int offL[1024];          // segment starts
    __shared__ int wsum[4];
    __shared__ float sWr[FF1 * FIN], sWo[FF1 * FIN], sb[FF1];
    __shared__ float red[4][FF1], redq[4][FF1];
    int t = threadIdx.x;
    if (t < FF1 * FIN) { sWr[t] = Wrel[t]; sWo[t] = Wroot[t]; }
    if (t < FF1) sb[t] = brel[t];
    int bk = blockIdx.x;
    int ebeg = bk * CAP;
    int n = bend[bk] - ebeg; if (n > CAP) n = CAP; if (n < 0) n = 0;
    unsigned it[ITPT];
    #pragma unroll
    for (int u = 0; u < ITPT; ++u) {
        int k = u * 256 + t;
        it[u] = (k < n) ? __builtin_nontemporal_load(ebuf + ebeg + k) : 0u;
    }
    for (int u = t; u < 1024; u += 256) hist[u] = 0;
    __syncthreads();
    #pragma unroll
    for (int u = 0; u < ITPT; ++u) {
        int k = u * 256 + t;
        if (k < n) atomicAdd(&hist[it[u] & 1023u], 1);
    }
    __syncthreads();
    int v[4]; int s = 0;
    #pragma unroll
    for (int u = 0; u < 4; ++u) { v[u] = hist[t * 4 + u]; s += v[u]; }
    int lane = t & 63, w = t >> 6;
    int iv = s;
    for (int o = 1; o < 64; o <<= 1) { int uu = __shfl_up(iv, o); if (lane >= o) iv += uu; }
    if (lane == 63) wsum[w] = iv;
    __syncthreads();
    int basep = 0;
    #pragma unroll
    for (int ww = 0; ww < 4; ++ww) if (ww < w) basep += wsum[ww];
    int run = basep + iv - s;
    #pragma unroll
    for (int u = 0; u < 4; ++u) {
        offL[t * 4 + u] = run;
        hist[t * 4 + u] = run;
        run += v[u];
    }
    __syncthreads();
    #pragma unroll
    for (int u = 0; u < ITPT; ++u) {
        int k = u * 256 + t;
        if (k < n) {
            int pos = atomicAdd(&hist[it[u] & 1023u], 1);
            stage[pos] = it[u] >> 10;
        }
    }
    __syncthreads();
    // gather + compute + stats
    float ps[FF1], pq[FF1];
    #pragma unroll
    for (int j = 0; j < FF1; ++j) { ps[j] = 0.f; pq[j] = 0.f; }
    #pragma unroll
    for (int nn = 0; nn < 4; ++nn) {
        int li = nn * 256 + t;
        size_t i = (size_t)bk * 1024 + li;
        int beg = offL[li];
        int end = (li == 1023) ? n : offL[li + 1];
        float agg[FIN] = {0.f, 0.f, 0.f, 0.f, 0.f, 0.f, 0.f};
        int k = beg;
        for (; k + 3 < end; k += 4) {
            unsigned s0 = stage[k], s1 = stage[k+1], s2 = stage[k+2], s3 = stage[k+3];
            uint4 a0 = xb[s0], a1 = xb[s1], a2 = xb[s2], a3 = xb[s3];
            acc7(agg, a0); acc7(agg, a1); acc7(agg, a2); acc7(agg, a3);
        }
        for (; k < end; ++k) acc7(agg, xb[stage[k]]);
        uint4 ow = xb[i];
        float xv[FIN] = {bflo(ow.x), bfhi(ow.x), bflo(ow.y), bfhi(ow.y),
                         bflo(ow.z), bfhi(ow.z), bflo(ow.w)};
        unsigned short hh[FF1];
        #pragma unroll
        for (int j = 0; j < FF1; ++j) {
            float h = sb[j];
            #pragma unroll
            for (int q = 0; q < FIN; ++q) h += sWr[j * FIN + q] * agg[q] + sWo[j * FIN + q] * xv[q];
            ps[j] += h; pq[j] += h * h;
            hh[j] = f2bf(h);
        }
        uint4 w1, w2;
        w1.x = (unsigned)hh[0] | ((unsigned)hh[1] << 16);
        w1.y = (unsigned)hh[2] | ((unsigned)hh[3] << 16);
        w1.z = (unsigned)hh[4] | ((unsigned)hh[5] << 16);
        w1.w = (unsigned)hh[6] | ((unsigned)hh[7] << 16);
        w2.x = (unsigned)hh[8] | ((unsigned)hh[9] << 16);
        w2.y = (unsigned)hh[10]| ((unsigned)hh[11] << 16);
        w2.z = 0u; w2.w = 0u;
        nts_u4(h1p + i * 2, w1);
        nts_u4(h1p + i * 2 + 1, w2);
    }
    #pragma unroll
    for (int j = 0; j < FF1; ++j)
        for (int o = 1; o < 64; o <<= 1) { ps[j] += __shfl_xor(ps[j], o); pq[j] += __shfl_xor(pq[j], o); }
    if (lane == 0) {
        #pragma unroll
        for (int j = 0; j < FF1; ++j) { red[w][j] = ps[j]; redq[w][j] = pq[j]; }
    }
    __syncthreads();
    if (t < FF1) {
        float ss = red[0][t] + red[1][t] + red[2][t] + red[3][t];
        float qq = redq[0][t] + redq[1][t] + redq[2][t] + redq[3][t];
        atomicAdd(&stats[t], (double)ss);
        atomicAdd(&stats[FF1 + t], (double)qq);
    }
}

// ---------------------------------------------------------------------------
__global__ void k_finalize(const double* __restrict__ stats, const float* __restrict__ g,
                           const float* __restrict__ b, float* __restrict__ ss) {
    int j = threadIdx.x;
    if (j < FF1) {
        double mean = stats[j] * (1.0 / NNODES);
        double var  = stats[FF1 + j] * (1.0 / NNODES) - mean * mean;
        float sc = (float)((double)g[j] / sqrt(var + 1e-5));
        ss[j] = sc;
        ss[FF1 + j] = b[j] - (float)mean * sc;
    }
}

// ---------------------------------------------------------------------------
// conv2: same in-LDS sort; gather h1p (32B rows), bn1+relu inline; BN2 stats
// fused; h2 bf16 (24B rows) nt out.
__global__ __launch_bounds__(256) void k_conv2(const int* __restrict__ bend,
                                               const unsigned* __restrict__ ebuf,
                                               const uint4* __restrict__ h1p,
                                               const float* __restrict__ ss,
                                               const float* __restrict__ Wrel,
                                               const float* __restrict__ brel,
                                               const float* __restrict__ Wroot,
                                               unsigned* __restrict__ h2b,
                                               double* __restrict__ stats) {
    __shared__ unsigned stage[CAP];
    __shared__ int hist[1024];
    __shared__ int offL[1024];
    __shared__ int wsum[4];
    __shared__ float sWr[FF2 * FF1], sWo[FF2 * FF1], sb[FF2], sc[FF1], sh[FF1];
    __shared__ float red[4][FF2], redq[4][FF2];
    int t = threadIdx.x;
    if (t < FF2 * FF1) { sWr[t] = Wrel[t]; sWo[t] = Wroot[t]; }
    if (t < FF2) { sb[t] = brel[t]; sc[t] = ss[t]; sh[t] = ss[FF1 + t]; }
    int bk = blockIdx.x;
    int ebeg = bk * CAP;
    int n = bend[bk] - ebeg; if (n > CAP) n = CAP; if (n < 0) n = 0;
    unsigned it[ITPT];
    #pragma unroll
    for (int u = 0; u < ITPT; ++u) {
        int k = u * 256 + t;
        it[u] = (k < n) ? __builtin_nontemporal_load(ebuf + ebeg + k) : 0u;
    }
    for (int u = t; u < 1024; u += 256) hist[u] = 0;
    __syncthreads();
    #pragma unroll
    for (int u = 0; u < ITPT; ++u) {
        int k = u * 256 + t;
        if (k < n) atomicAdd(&hist[it[u] & 1023u], 1);
    }
    __syncthreads();
    int v[4]; int s = 0;
    #pragma unroll
    for (int u = 0; u < 4; ++u) { v[u] = hist[t * 4 + u]; s += v[u]; }
    int lane = t & 63, w = t >> 6;
    int iv = s;
    for (int o = 1; o < 64; o <<= 1) { int uu = __shfl_up(iv, o); if (lane >= o) iv += uu; }
    if (lane == 63) wsum[w] = iv;
    __syncthreads();
    int basep = 0;
    #pragma unroll
    for (int ww = 0; ww < 4; ++ww) if (ww < w) basep += wsum[ww];
    int run = basep + iv - s;
    #pragma unroll
    for (int u = 0; u < 4; ++u) {
        offL[t * 4 + u] = run;
        hist[t * 4 + u] = run;
        run += v[u];
    }
    __syncthreads();
    #pragma unroll
    for (int u = 0; u < ITPT; ++u) {
        int k = u * 256 + t;
        if (k < n) {
            int pos = atomicAdd(&hist[it[u] & 1023u], 1);
            stage[pos] = it[u] >> 10;
        }
    }
    __syncthreads();
    float ps[FF2], pq[FF2];
    #pragma unroll
    for (int j = 0; j < FF2; ++j) { ps[j] = 0.f; pq[j] = 0.f; }
    #pragma unroll
    for (int nn = 0; nn < 4; ++nn) {
        int li = nn * 256 + t;
        size_t i = (size_t)bk * 1024 + li;
        int beg = offL[li];
        int end = (li == 1023) ? n : offL[li + 1];
        float agg[FF1];
        #pragma unroll
        for (int j = 0; j < FF1; ++j) agg[j] = 0.f;
        int k = beg;
        for (; k + 3 < end; k += 4) {
            unsigned s0 = stage[k], s1 = stage[k+1], s2 = stage[k+2], s3 = stage[k+3];
            uint4 a0 = h1p[(size_t)s0 * 2], a1 = h1p[(size_t)s0 * 2 + 1];
            uint4 b0 = h1p[(size_t)s1 * 2], b1 = h1p[(size_t)s1 * 2 + 1];
            uint4 c0 = h1p[(size_t)s2 * 2], c1 = h1p[(size_t)s2 * 2 + 1];
            uint4 d0 = h1p[(size_t)s3 * 2], d1 = h1p[(size_t)s3 * 2 + 1];
            accY(agg, sc, sh, a0, a1);
            accY(agg, sc, sh, b0, b1);
            accY(agg, sc, sh, c0, c1);
            accY(agg, sc, sh, d0, d1);
        }
        for (; k < end; ++k) {
            unsigned s0 = stage[k];
            accY(agg, sc, sh, h1p[(size_t)s0 * 2], h1p[(size_t)s0 * 2 + 1]);
        }
        uint4 o0 = h1p[i * 2], o1 = h1p[i * 2 + 1];
        float vo[FF1] = {bflo(o0.x), bfhi(o0.x), bflo(o0.y), bfhi(o0.y),
                         bflo(o0.z), bfhi(o0.z), bflo(o0.w), bfhi(o0.w),
                         bflo(o1.x), bfhi(o1.x), bflo(o1.y), bfhi(o1.y)};
        float y[FF1];
        #pragma unroll
        for (int j = 0; j < FF1; ++j) {
            float wv = vo[j] * sc[j] + sh[j];
            y[j] = wv > 0.f ? wv : 0.f;
        }
        unsigned short hh[FF2];
        #pragma unroll
        for (int j = 0; j < FF2; ++j) {
            float h = sb[j];
            #pragma unroll
            for (int q = 0; q < FF1; ++q) h += sWr[j * FF1 + q] * agg[q] + sWo[j * FF1 + q] * y[q];
            ps[j] += h; pq[j] += h * h;
            hh[j] = f2bf(h);
        }
        unsigned* p = h2b + i * 6;
        nts_u2(p,     (unsigned)hh[0] | ((unsigned)hh[1] << 16),
                      (unsigned)hh[2] | ((unsigned)hh[3] << 16));
        nts_u2(p + 2, (unsigned)hh[4] | ((unsigned)hh[5] << 16),
                      (unsigned)hh[6] | ((unsigned)hh[7] << 16));
        nts_u2(p + 4, (unsigned)hh[8] | ((unsigned)hh[9] << 16),
                      (unsigned)hh[10]| ((unsigned)hh[11] << 16));
    }
    #pragma unroll
    for (int j = 0; j < FF2; ++j)
        for (int o = 1; o < 64; o <<= 1) { ps[j] += __shfl_xor(ps[j], o); pq[j] += __shfl_xor(pq[j], o); }
    if (lane == 0) {
        #pragma unroll
        for (int j = 0; j < FF2; ++j) { red[w][j] = ps[j]; redq[w][j] = pq[j]; }
    }
    __syncthreads();
    if (t < FF2) {
        float s2 = red[0][t] + red[1][t] + red[2][t] + red[3][t];
        float q2 = redq[0][t] + redq[1][t] + redq[2][t] + redq[3][t];
        atomicAdd(&stats[t], (double)s2);
        atomicAdd(&stats[FF2 + t], (double)q2);
    }
}

// ---------------------------------------------------------------------------
// GEMM1: A = relu(bn2(h2b)) bf16-stored, B = W1 f32; split-K=8 partials.
__global__ __launch_bounds__(256) void k_gemm1(const unsigned short* __restrict__ h2b,
                                               const float* __restrict__ ss2,
                                               const float* __restrict__ W1,
                                               float* __restrict__ hidp) {
    __shared__ float As[32][128];
    __shared__ float Bs[32][128];
    __shared__ float sc[FF2], sh[FF2];
    int t = threadIdx.x;
    if (t < FF2) { sc[t] = ss2[t]; sh[t] = ss2[FF2 + t]; }
    __syncthreads();
    int mb = blockIdx.x;
    int ks = blockIdx.y;
    const int KS = KDIM / 8;         // 1536
    int m0 = mb * 128;
    int kbase = ks * KS;
    int r  = t >> 1;
    int kg = t & 1;
    int tr = t >> 4;
    int tc = t & 15;
    float acc[8][8];
    #pragma unroll
    for (int i = 0; i < 8; ++i)
        #pragma unroll
        for (int j = 0; j < 8; ++j) acc[i][j] = 0.f;

    for (int kt = 0; kt < KS; kt += 32) {
        int c0 = kbase + kt + 16 * kg;
        const uint2* arow = (const uint2*)(h2b + (size_t)(m0 + r) * KDIM + c0);
        const float* brow = W1 + (size_t)r * KDIM + c0;
        #pragma unroll
        for (int i = 0; i < 4; ++i) {
            uint2 av = arow[i];
            int cc = c0 + 4 * i;
            int j0 = cc % FF2;
            float vals[4] = {bflo(av.x), bfhi(av.x), bflo(av.y), bfhi(av.y)};
            #pragma unroll
            for (int ii = 0; ii < 4; ++ii) {
                int j = j0 + ii; if (j >= FF2) j -= FF2;
                float v = vals[ii] * sc[j] + sh[j];
                As[16 * kg + 4 * i + ii][r] = v > 0.f ? v : 0.f;
            }
            float4 bv = *(const float4*)(brow + 4 * i);
            Bs[16 * kg + 4 * i + 0][r] = bv.x;
            Bs[16 * kg + 4 * i + 1][r] = bv.y;
            Bs[16 * kg + 4 * i + 2][r] = bv.z;
            Bs[16 * kg + 4 * i + 3][r] = bv.w;
        }
        __syncthreads();
        #pragma unroll
        for (int k = 0; k < 32; ++k) {
            float a[8], b[8];
            *(float4*)&a[0] = *(const float4*)&As[k][8 * tr];
            *(float4*)&a[4] = *(const float4*)&As[k][8 * tr + 4];
            *(float4*)&b[0] = *(const float4*)&Bs[k][8 * tc];
            *(float4*)&b[4] = *(const float4*)&Bs[k][8 * tc + 4];
            #pragma unroll
            for (int i = 0; i < 8; ++i)
                #pragma unroll
                for (int j = 0; j < 8; ++j) acc[i][j] += a[i] * b[j];
        }
        __syncthreads();
    }
    float* obase = hidp + (size_t)ks * (BATCHSZ * HIDD);
    #pragma unroll
    for (int i = 0; i < 8; ++i) {
        float* orow = obase + (size_t)(m0 + 8 * tr + i) * HIDD + 8 * tc;
        *(float4*)(orow)     = make_float4(acc[i][0], acc[i][1], acc[i][2], acc[i][3]);
        *(float4*)(orow + 4) = make_float4(acc[i][4], acc[i][5], acc[i][6], acc[i][7]);
    }
}

__global__ __launch_bounds__(256) void k_hred(const float* __restrict__ hidp,
                                              const float* __restrict__ bl1,
                                              float* __restrict__ hid) {
    int i = blockIdx.x * 256 + threadIdx.x;
    float s = bl1[i & (HIDD - 1)];
    #pragma unroll
    for (int p = 0; p < 8; ++p) s += hidp[(size_t)p * (BATCHSZ * HIDD) + i];
    hid[i] = s > 0.f ? s : 0.f;
}

// ---------------------------------------------------------------------------
__global__ __launch_bounds__(256) void k_gemm2(const float* __restrict__ hid,
                                               const float* __restrict__ W2,
                                               const float* __restrict__ bl2,
                                               float* __restrict__ out) {
    __shared__ float As[32][128];
    __shared__ float Bs[32][128];
    int t = threadIdx.x;
    int m0 = blockIdx.x * 128;
    int n0 = blockIdx.y * 128;
    int r  = t >> 1;
    int kg = t & 1;
    int tr = t >> 4;
    int tc = t & 15;
    float acc[8][8];
    #pragma unroll
    for (int i = 0; i < 8; ++i)
        #pragma unroll
        for (int j = 0; j < 8; ++j) acc[i][j] = 0.f;

    for (int kt = 0; kt < HIDD; kt += 32) {
        int c0 = kt + 16 * kg;
        #pragma unroll
        for (int i = 0; i < 4; ++i) {
            float4 av = *(const float4*)(hid + (size_t)(m0 + r) * HIDD + c0 + 4 * i);
            As[16 * kg + 4 * i + 0][r] = av.x;
            As[16 * kg + 4 * i + 1][r] = av.y;
            As[16 * kg + 4 * i + 2][r] = av.z;
            As[16 * kg + 4 * i + 3][r] = av.w;
            float4 bv = *(const float4*)(W2 + (size_t)(n0 + r) * HIDD + c0 + 4 * i);
            Bs[16 * kg + 4 * i + 0][r] = bv.x;
            Bs[16 * kg + 4 * i + 1][r] = bv.y;
            Bs[16 * kg + 4 * i + 2][r] = bv.z;
            Bs[16 * kg + 4 * i + 3][r] = bv.w;
        }
        __syncthreads();
        #pragma unroll
        for (int k = 0; k < 32; ++k) {
            float a[8], b[8];
            *(float4*)&a[0] = *(const float4*)&As[k][8 * tr];
            *(float4*)&a[4] = *(const float4*)&As[k][8 * tr + 4];
            *(float4*)&b[0] = *(const float4*)&Bs[k][8 * tc];
            *(float4*)&b[4] = *(const float4*)&Bs[k][8 * tc + 4];
            #pragma unroll
            for (int i = 0; i < 8; ++i)
                #pragma unroll
                for (int j = 0; j < 8; ++j) acc[i][j] += a[i] * b[j];
        }
        __syncthreads();
    }
    float4 c0v = *(const float4*)(bl2 + n0 + 8 * tc);
    float4 c1v = *(const float4*)(bl2 + n0 + 8 * tc + 4);
    float bvals[8] = {c0v.x, c0v.y, c0v.z, c0v.w, c1v.x, c1v.y, c1v.z, c1v.w};
    #pragma unroll
    for (int i = 0; i < 8; ++i) {
        size_t ro = (size_t)(m0 + 8 * tr + i) * ODIM + n0 + 8 * tc;
        *(float4*)(out + ro)     = make_float4(acc[i][0] + bvals[0], acc[i][1] + bvals[1],
                                               acc[i][2] + bvals[2], acc[i][3] + bvals[3]);
        *(float4*)(out + ro + 4) = make_float4(acc[i][4] + bvals[4], acc[i][5] + bvals[5],
                                               acc[i][6] + bvals[6], acc[i][7] + bvals[7]);
    }
}

// ---------------------------------------------------------------------------
extern "C" void kernel_launch(void* const* d_in, const int* in_sizes, int n_in,
                              void* d_out, int out_size, void* d_ws, size_t ws_size,
                              hipStream_t stream) {
    const float* x      = (const float*)d_in[0];
    const int*   ei     = (const int*)d_in[1];
    const float* Wrel1  = (const float*)d_in[3];
    const float* brel1  = (const float*)d_in[4];
    const float* Wroot1 = (const float*)d_in[5];
    const float* Wrel2  = (const float*)d_in[6];
    const float* brel2  = (const float*)d_in[7];
    const float* Wroot2 = (const float*)d_in[8];
    const float* g1     = (const float*)d_in[9];
    const float* b1     = (const float*)d_in[10];
    const float* g2     = (const float*)d_in[11];
    const float* b2     = (const float*)d_in[12];
    const float* W1     = (const float*)d_in[13];
    const float* bl1    = (const float*)d_in[14];
    const float* W2     = (const float*)d_in[15];
    const float* bl2    = (const float*)d_in[16];
    float* out = (float*)d_out;
    char* ws = (char*)d_ws;

    // Layout (liveness-overlaid), ~346 MB:
    //   pY  [0, SZ_P):       xb(67MB) -> [after conv1] h2b(100MB)+hidp(16MB)+hid(2MB)
    //   E   [SZ_P, +SZ_E):   fine bucket slots (75.5MB), unsorted packed edges
    //   pB  [.., +SZ_PB):    ebufA(135.8MB) -> h1p(134MB)
    //   pK: bcur(16KB), bcurA(256B), smalls
    const size_t req = SZ_P + SZ_E + SZ_PB + 32768;
    if (ws_size < req) {
        float v = (float)(ws_size >> 20);
        k_diag<<<(out_size + 255) / 256, 256, 0, stream>>>(out, out_size, v);
        return;
    }
    char* pY = ws;
    unsigned* ebuf = (unsigned*)(ws + SZ_P);
    char* pB = ws + SZ_P + SZ_E;
    char* pK = ws + SZ_P + SZ_E + SZ_PB;
    int*  bcur  = (int*)pK;                     // 4096 ints; ends after partB
    int*  bcurA = (int*)(pK + 16384);           // 64 ints; ends after partA
    char* smalls = pK + 20480;
    double* st1  = (double*)smalls;
    double* st2  = st1 + 2 * FF1;
    float*  ss1  = (float*)(st2 + 2 * FF2);
    float*  ss2  = ss1 + 2 * FF1;
    int*    flag = (int*)(ss2 + 2 * FF2);

    uint4*    xb    = (uint4*)pY;
    unsigned* h2b   = (unsigned*)pY;
    float*    hidp  = (float*)(pY + SZ_HB);
    float*    hid   = (float*)(pY + SZ_HB + 8 * SZ_HID);
    unsigned* ebufA = (unsigned*)pB;
    uint4*    h1p   = (uint4*)pB;

    hipMemsetAsync(smalls, 0, 1024, stream);
    k_init  <<<16, 256, 0, stream>>>(ei, flag, bcur, bcurA);
    k_padx  <<<NNODES / 4 / 256, 256, 0, stream>>>(x, xb);
    k_partA <<<512, 512, 0, stream>>>(ei, flag, bcurA, ebufA);
    k_partB <<<NCB * 4, 512, 0, stream>>>(ebufA, bcurA, bcur, ebuf);
    k_conv1 <<<NBKT, 256, 0, stream>>>(bcur, ebuf, xb, Wrel1, brel1, Wroot1, h1p, st1);
    k_finalize<<<1, 64, 0, stream>>>(st1, g1, b1, ss1);
    k_conv2 <<<NBKT, 256, 0, stream>>>(bcur, ebuf, h1p, ss1, Wrel2, brel2, Wroot2, h2b, st2);
    k_finalize<<<1, 64, 0, stream>>>(st2, g2, b2, ss2);
    k_gemm1<<<dim3(BATCHSZ / 128, 8), 256, 0, stream>>>((const unsigned short*)h2b, ss2, W1, hidp);
    k_hred <<<BATCHSZ * HIDD / 256, 256, 0, stream>>>(hidp, bl1, hid);
    k_gemm2<<<dim3(BATCHSZ / 128, ODIM / 128), 256, 0, stream>>>(hid, W2, bl2, out);
}

// Round 14
// 1414.735 us; speedup vs baseline: 1.3627x; 1.0748x over previous
//
#include <hip/hip_runtime.h>
#include <hip/hip_bf16.h>

#define NBUS    1024
#define BATCHSZ 4096
#define NNODES  (NBUS*BATCHSZ)      // 4194304 = 2^22
#define NEDGES  (4*NNODES)          // 16777216
#define FIN     7
#define FF1     12
#define FF2     12
#define HIDD    128
#define KDIM    (NBUS*FF2)          // 12288
#define ODIM    (NBUS*2)            // 2048
#define NBKT    4096                // fine buckets of 1024 dst nodes
#define CAP     4608                // fine bucket capacity (mean 4096 + 8 sigma)
#define ITPT    18                  // CAP / 256
#define NCB     64                  // coarse buckets of 65536 dst nodes
#define CAPA    265216              // coarse capacity (mean 262144 + 6 sigma)

#define SZ_P    ((size_t)NNODES * 32)                   // 134,217,728 (xb -> h2b+hidp+hid)
#define SZ_HB   ((size_t)NNODES * FF2 * 2)              // 100,663,296 (h2b)
#define SZ_HID  ((size_t)BATCHSZ * HIDD * sizeof(float))//   2,097,152
#define SZ_E    ((size_t)NBKT * CAP * sizeof(unsigned)) //  75,497,472
#define SZ_PB   ((size_t)NCB * CAPA * 8)                // 135,790,592 (ebufA -> h1p)

typedef unsigned u32x2v  __attribute__((ext_vector_type(2)));
typedef unsigned u32x4v  __attribute__((ext_vector_type(4)));

__device__ __forceinline__ float bflo(unsigned p){ return __uint_as_float(p << 16); }
__device__ __forceinline__ float bfhi(unsigned p){ return __uint_as_float(p & 0xffff0000u); }
__device__ __forceinline__ unsigned short f2bf(float f) {
    unsigned u = __float_as_uint(f);
    return (unsigned short)((u + 0x7fffu + ((u >> 16) & 1u)) >> 16);
}
__device__ __forceinline__ void nts_u2(unsigned* p, unsigned a, unsigned b) {
    u32x2v w; w.x = a; w.y = b;
    __builtin_nontemporal_store(w, (u32x2v*)p);
}
__device__ __forceinline__ void nts_u4(uint4* p, uint4 v) {
    u32x4v w; w.x = v.x; w.y = v.y; w.z = v.z; w.w = v.w;
    __builtin_nontemporal_store(w, (u32x4v*)p);
}
__device__ __forceinline__ uint2 ntl_u2(const unsigned* p) {
    u32x2v v = __builtin_nontemporal_load((const u32x2v*)p);
    uint2 r; r.x = v.x; r.y = v.y; return r;
}
__device__ __forceinline__ float4 ntl_f4(const float* p) {
    typedef float f32x4v __attribute__((ext_vector_type(4)));
    f32x4v v = __builtin_nontemporal_load((const f32x4v*)p);
    return make_float4(v.x, v.y, v.z, v.w);
}

__device__ __forceinline__ void acc7(float* agg, uint4 a) {
    agg[0] += bflo(a.x); agg[1] += bfhi(a.x);
    agg[2] += bflo(a.y); agg[3] += bfhi(a.y);
    agg[4] += bflo(a.z); agg[5] += bfhi(a.z);
    agg[6] += bflo(a.w);
}
__device__ __forceinline__ void accY(float* agg, const float* sc, const float* sh,
                                     uint4 r0, uint4 r1) {
    float v[FF1] = {bflo(r0.x), bfhi(r0.x), bflo(r0.y), bfhi(r0.y),
                    bflo(r0.z), bfhi(r0.z), bflo(r0.w), bfhi(r0.w),
                    bflo(r1.x), bfhi(r1.x), bflo(r1.y), bfhi(r1.y)};
    #pragma unroll
    for (int j = 0; j < FF1; ++j) {
        float y = v[j] * sc[j] + sh[j];
        agg[j] += (y > 0.f ? y : 0.f);
    }
}

// ---------------------------------------------------------------------------
__global__ void k_diag(float* __restrict__ out, int n, float v) {
    size_t i = (size_t)blockIdx.x * blockDim.x + threadIdx.x;
    if (i < (size_t)n) out[i] = v;
}

// init cursors + int64/int32 detection (block 0)
__global__ void k_init(const int* __restrict__ w, int* __restrict__ flag,
                       int* __restrict__ bcur, int* __restrict__ bcurA) {
    int u = blockIdx.x * 256 + threadIdx.x;
    if (u < NBKT) bcur[u] = u * CAP;
    if (u < NCB) bcurA[u] = u * CAPA;
    if (blockIdx.x == 0) {
        __shared__ int any;
        if (threadIdx.x == 0) any = 0;
        __syncthreads();
        int acc = 0;
        #pragma unroll
        for (int q = 0; q < 4; ++q) acc |= w[1 + 2 * (threadIdx.x * 4 + q)];
        if (acc) atomicOr(&any, 1);
        __syncthreads();
        if (threadIdx.x == 0) *flag = (any == 0) ? 2 : 1;
    }
}

// ---------------------------------------------------------------------------
// pass A: 64 coarse buckets (dst >> 16) as (src,dst); plain stores (L2 merges).
__global__ __launch_bounds__(512) void k_partA(const int* __restrict__ ei,
                                               const int* __restrict__ flag,
                                               int* __restrict__ bcurA,
                                               unsigned* __restrict__ ebufA) {
    __shared__ int hist[NCB], lbase[NCB];
    int t = threadIdx.x;
    if (t < NCB) hist[t] = 0;
    __syncthreads();
    int mult = *flag;
    size_t base = (size_t)blockIdx.x * 32768;          // 512 blocks
    #pragma unroll 4
    for (int u = 0; u < 64; ++u) {
        size_t e = base + (size_t)u * 512 + t;
        int d = __builtin_nontemporal_load(ei + ((size_t)NEDGES + e) * mult);
        atomicAdd(&hist[d >> 16], 1);
    }
    __syncthreads();
    if (t < NCB) {
        int c = hist[t];
        lbase[t] = c ? atomicAdd(&bcurA[t], c) : 0;
        hist[t] = 0;
    }
    __syncthreads();
    #pragma unroll 4
    for (int u = 0; u < 64; ++u) {
        size_t e = base + (size_t)u * 512 + t;
        int s = __builtin_nontemporal_load(ei + e * mult);
        int d = __builtin_nontemporal_load(ei + ((size_t)NEDGES + e) * mult);
        int bk = d >> 16;
        int pos = lbase[bk] + atomicAdd(&hist[bk], 1);
        if (pos < (bk + 1) * CAPA) {
            uint2* p = (uint2*)(ebufA + (size_t)pos * 2);
            *p = make_uint2((unsigned)s, (unsigned)d);
        }
    }
}

// ---------------------------------------------------------------------------
// pass B: 4 blocks per coarse bucket -> 64 fine buckets, packed. Plain stores.
__global__ __launch_bounds__(512) void k_partB(const unsigned* __restrict__ ebufA,
                                               const int* __restrict__ bendA,
                                               int* __restrict__ bcur,
                                               unsigned* __restrict__ ebuf) {
    __shared__ int hist[NCB], lbase[NCB];
    int t = threadIdx.x;
    int cb = blockIdx.x >> 2;
    int qq = blockIdx.x & 3;
    int abeg = cb * CAPA;
    int n = bendA[cb] - abeg; if (n > CAPA) n = CAPA;
    int beg = abeg + (int)(((long long)n * qq) >> 2);
    int end = abeg + (int)(((long long)n * (qq + 1)) >> 2);
    if (t < NCB) hist[t] = 0;
    __syncthreads();
    for (int k = beg + t; k < end; k += 512) {
        uint2 e = ntl_u2(ebufA + (size_t)k * 2);
        atomicAdd(&hist[(e.y >> 10) & 63u], 1);
    }
    __syncthreads();
    if (t < NCB) {
        int c = hist[t];
        lbase[t] = c ? atomicAdd(&bcur[cb * 64 + t], c) : 0;
        hist[t] = 0;
    }
    __syncthreads();
    for (int k = beg + t; k < end; k += 512) {
        uint2 e = ntl_u2(ebufA + (size_t)k * 2);
        int lb = (e.y >> 10) & 63u;
        int fb = cb * 64 + lb;
        int pos = lbase[lb] + atomicAdd(&hist[lb], 1);
        if (pos < (fb + 1) * CAP)
            ebuf[pos] = (e.x << 10) | (e.y & 1023u);
    }
}

// ---------------------------------------------------------------------------
__global__ __launch_bounds__(256) void k_padx(const float* __restrict__ x,
                                              uint4* __restrict__ xb) {
    size_t q = (size_t)blockIdx.x * blockDim.x + threadIdx.x;
    if (q >= NNODES / 4) return;
    const float4* xr = (const float4*)(x + q * 28);
    float v[28];
    #pragma unroll
    for (int u = 0; u < 7; ++u) {
        float4 f = xr[u];
        v[4*u] = f.x; v[4*u+1] = f.y; v[4*u+2] = f.z; v[4*u+3] = f.w;
    }
    #pragma unroll
    for (int n = 0; n < 4; ++n) {
        unsigned short h[8];
        #pragma unroll
        for (int j = 0; j < 7; ++j) h[j] = f2bf(v[7*n + j]);
        h[7] = 0;
        uint4 o;
        o.x = (unsigned)h[0] | ((unsigned)h[1] << 16);
        o.y = (unsigned)h[2] | ((unsigned)h[3] << 16);
        o.z = (unsigned)h[4] | ((unsigned)h[5] << 16);
        o.w = (unsigned)h[6] | ((unsigned)h[7] << 16);
        xb[q * 4 + n] = o;
    }
}

// ---------------------------------------------------------------------------
// conv1: in-LDS counting sort of the bucket (two-pass ebuf read, no reg
// staging), then register gather of xb; h1p bf16 32B rows out. No fused stats.
__global__ __launch_bounds__(256, 4) void k_conv1(const int* __restrict__ bend,
                                                  const unsigned* __restrict__ ebuf,
                                                  const uint4* __restrict__ xb,
                                                  const float* __restrict__ Wrel,
                                                  const float* __restrict__ brel,
                                                  const float* __restrict__ Wroot,
                                                  uint4* __restrict__ h1p) {
    __shared__ unsigned stage[CAP];     // 18KB (sorted srcs)
    __shared__ int hist[1024];
    __shared__ int offL[1024];
    __shared__ int wsum[4];
    __shared__ float sWr[FF1 * FIN], sWo[FF1 * FIN], sb[FF1];
    int t = threadIdx.x;
    if (t < FF1 * FIN) { sWr[t] = Wrel[t]; sWo[t] = Wroot[t]; }
    if (t < FF1) sb[t] = brel[t];
    int bk = blockIdx.x;
    int ebeg = bk * CAP;
    int n = bend[bk] - ebeg; if (n > CAP) n = CAP; if (n < 0) n = 0;
    for (int u = t; u < 1024; u += 256) hist[u] = 0;
    __syncthreads();
    for (int k = t; k < n; k += 256)
        atomicAdd(&hist[ebuf[ebeg + k] & 1023u], 1);
    __syncthreads();
    int v[4]; int s = 0;
    #pragma unroll
    for (int u = 0; u < 4; ++u) { v[u] = hist[t * 4 + u]; s += v[u]; }
    int lane = t & 63, w = t >> 6;
    int iv = s;
    for (int o = 1; o < 64; o <<= 1) { int uu = __shfl_up(iv, o); if (lane >= o) iv += uu; }
    if (lane == 63) wsum[w] = iv;
    __syncthreads();
    int basep = 0;
    #pragma unroll
    for (int ww = 0; ww < 4; ++ww) if (ww < w) basep += wsum[ww];
    int run = basep + iv - s;
    #pragma unroll
    for (int u = 0; u < 4; ++u) {
        offL[t * 4 + u] = run;
        hist[t * 4 + u] = run;
        run += v[u];
    }
    __syncthreads();
    for (int k = t; k < n; k += 256) {
        unsigned p = ebuf[ebeg + k];
        int pos = atomicAdd(&hist[p & 1023u], 1);
        stage[pos] = p >> 10;
    }
    __syncthreads();
    #pragma unroll
    for (int nn = 0; nn < 4; ++nn) {
        int li = nn * 256 + t;
        size_t i = (size_t)bk * 1024 + li;
        int beg = offL[li];
        int end = (li == 1023) ? n : offL[li + 1];
        float agg[FIN] = {0.f, 0.f, 0.f, 0.f, 0.f, 0.f, 0.f};
        int k = beg;
        for (; k + 3 < end; k += 4) {
            unsigned s0 = stage[k], s1 = stage[k+1], s2 = stage[k+2], s3 = stage[k+3];
            uint4 a0 = xb[s0], a1 = xb[s1], a2 = xb[s2], a3 = xb[s3];
            acc7(agg, a0); acc7(agg, a1); acc7(agg, a2); acc7(agg, a3);
        }
        for (; k < end; ++k) acc7(agg, xb[stage[k]]);
        uint4 ow = xb[i];
        float xv[FIN] = {bflo(ow.x), bfhi(ow.x), bflo(ow.y), bfhi(ow.y),
                         bflo(ow.z), bfhi(ow.z), bflo(ow.w)};
        unsigned short hh[FF1];
        #pragma unroll
        for (int j = 0; j < FF1; ++j) {
            float h = sb[j];
            #pragma unroll
            for (int q = 0; q < FIN; ++q) h += sWr[j * FIN + q] * agg[q] + sWo[j * FIN + q] * xv[q];
            hh[j] = f2bf(h);
        }
        uint4 w1, w2;
        w1.x = (unsigned)hh[0] | ((unsigned)hh[1] << 16);
        w1.y = (unsigned)hh[2] | ((unsigned)hh[3] << 16);
        w1.z = (unsigned)hh[4] | ((unsigned)hh[5] << 16);
        w1.w = (unsigned)hh[6] | ((unsigned)hh[7] << 16);
        w2.x = (unsigned)hh[8] | ((unsigned)hh[9] << 16);
        w2.y = (unsigned)hh[10]| ((unsigned)hh[11] << 16);
        w2.z = 0u; w2.w = 0u;
        nts_u4(h1p + i * 2, w1);
        nts_u4(h1p + i * 2 + 1, w2);
    }
}

// ---------------------------------------------------------------------------
// stats over bf16 rows (first 12 bf16 of each row; STRIDE dwords per row)
template<int STRIDE>
__global__ __launch_bounds__(256) void k_statsb(const unsigned* __restrict__ hb,
                                                double* __restrict__ stats) {
    __shared__ float red[4][FF1], redq[4][FF1];
    int t = threadIdx.x;
    float ps[FF1], pq[FF1];
    #pragma unroll
    for (int j = 0; j < FF1; ++j) { ps[j] = 0.f; pq[j] = 0.f; }
    for (size_t i = (size_t)blockIdx.x * 256 + t; i < NNODES; i += 256 * 256) {
        const uint2* r = (const uint2*)(hb + i * STRIDE);
        uint2 u0 = r[0], u1 = r[1], u2 = r[2];
        float v[FF1] = {bflo(u0.x), bfhi(u0.x), bflo(u0.y), bfhi(u0.y),
                        bflo(u1.x), bfhi(u1.x), bflo(u1.y), bfhi(u1.y),
                        bflo(u2.x), bfhi(u2.x), bflo(u2.y), bfhi(u2.y)};
        #pragma unroll
        for (int j = 0; j < FF1; ++j) { ps[j] += v[j]; pq[j] += v[j] * v[j]; }
    }
    #pragma unroll
    for (int j = 0; j < FF1; ++j)
        for (int o = 1; o < 64; o <<= 1) { ps[j] += __shfl_xor(ps[j], o); pq[j] += __shfl_xor(pq[j], o); }
    int lane = t & 63, wv = t >> 6;
    if (lane == 0) {
        #pragma unroll
        for (int j = 0; j < FF1; ++j) { red[wv][j] = ps[j]; redq[wv][j] = pq[j]; }
    }
    __syncthreads();
    if (t < FF1) {
        float s = red[0][t] + red[1][t] + red[2][t] + red[3][t];
        float q = redq[0][t] + redq[1][t] + redq[2][t] + redq[3][t];
        atomicAdd(&stats[t], (double)s);
        atomicAdd(&stats[FF1 + t], (double)q);
    }
}

// ---------------------------------------------------------------------------
__global__ void k_finalize(const double* __restrict__ stats, const float* __restrict__ g,
                           const float* __restrict__ b, float* __restrict__ ss) {
    int j = threadIdx.x;
    if (j < FF1) {
        double mean = stats[j] * (1.0 / NNODES);
        double var  = stats[FF1 + j] * (1.0 / NNODES) - mean * mean;
        float sc = (float)((double)g[j] / sqrt(var + 1e-5));
        ss[j] = sc;
        ss[FF1 + j] = b[j] - (float)mean * sc;
    }
}

// ---------------------------------------------------------------------------
// conv2: in-LDS sort (two-pass ebuf read); gather h1p (32B rows), bn1+relu
// inline; h2 bf16 (24B rows) nt out. No fused stats.
__global__ __launch_bounds__(256, 4) void k_conv2(const int* __restrict__ bend,
                                                  const unsigned* __restrict__ ebuf,
                                                  const uint4* __restrict__ h1p,
                                                  const float* __restrict__ ss,
                                                  const float* __restrict__ Wrel,
                                                  const float* __restrict__ brel,
                                                  const float* __restrict__ Wroot,
                                                  unsigned* __restrict__ h2b) {
    __shared__ unsigned stage[CAP];
    __shared__ int hist[1024];
    __shared__ int offL[1024];
    __shared__ int wsum[4];
    __shared__ float sWr[FF2 * FF1], sWo[FF2 * FF1], sb[FF2], sc[FF1], sh[FF1];
    int t = threadIdx.x;
    if (t < FF2 * FF1) { sWr[t] = Wrel[t]; sWo[t] = Wroot[t]; }
    if (t < FF2) { sb[t] = brel[t]; sc[t] = ss[t]; sh[t] = ss[FF1 + t]; }
    int bk = blockIdx.x;
    int ebeg = bk * CAP;
    int n = bend[bk] - ebeg; if (n > CAP) n = CAP; if (n < 0) n = 0;
    for (int u = t; u < 1024; u += 256) hist[u] = 0;
    __syncthreads();
    for (int k = t; k < n; k += 256)
        atomicAdd(&hist[ebuf[ebeg + k] & 1023u], 1);
    __syncthreads();
    int v[4]; int s = 0;
    #pragma unroll
    for (int u = 0; u < 4; ++u) { v[u] = hist[t * 4 + u]; s += v[u]; }
    int lane = t & 63, w = t >> 6;
    int iv = s;
    for (int o = 1; o < 64; o <<= 1) { int uu = __shfl_up(iv, o); if (lane >= o) iv += uu; }
    if (lane == 63) wsum[w] = iv;
    __syncthreads();
    int basep = 0;
    #pragma unroll
    for (int ww = 0; ww < 4; ++ww) if (ww < w) basep += wsum[ww];
    int run = basep + iv - s;
    #pragma unroll
    for (int u = 0; u < 4; ++u) {
        offL[t * 4 + u] = run;
        hist[t * 4 + u] = run;
        run += v[u];
    }
    __syncthreads();
    for (int k = t; k < n; k += 256) {
        unsigned p = ebuf[ebeg + k];
        int pos = atomicAdd(&hist[p & 1023u], 1);
        stage[pos] = p >> 10;
    }
    __syncthreads();
    #pragma unroll
    for (int nn = 0; nn < 4; ++nn) {
        int li = nn * 256 + t;
        size_t i = (size_t)bk * 1024 + li;
        int beg = offL[li];
        int end = (li == 1023) ? n : offL[li + 1];
        float agg[FF1];
        #pragma unroll
        for (int j = 0; j < FF1; ++j) agg[j] = 0.f;
        int k = beg;
        for (; k + 3 < end; k += 4) {
            unsigned s0 = stage[k], s1 = stage[k+1], s2 = stage[k+2], s3 = stage[k+3];
            uint4 a0 = h1p[(size_t)s0 * 2], a1 = h1p[(size_t)s0 * 2 + 1];
            uint4 b0 = h1p[(size_t)s1 * 2], b1 = h1p[(size_t)s1 * 2 + 1];
            uint4 c0 = h1p[(size_t)s2 * 2], c1 = h1p[(size_t)s2 * 2 + 1];
            uint4 d0 = h1p[(size_t)s3 * 2], d1 = h1p[(size_t)s3 * 2 + 1];
            accY(agg, sc, sh, a0, a1);
            accY(agg, sc, sh, b0, b1);
            accY(agg, sc, sh, c0, c1);
            accY(agg, sc, sh, d0, d1);
        }
        for (; k < end; ++k) {
            unsigned s0 = stage[k];
            accY(agg, sc, sh, h1p[(size_t)s0 * 2], h1p[(size_t)s0 * 2 + 1]);
        }
        uint4 o0 = h1p[i * 2], o1 = h1p[i * 2 + 1];
        float vo[FF1] = {bflo(o0.x), bfhi(o0.x), bflo(o0.y), bfhi(o0.y),
                         bflo(o0.z), bfhi(o0.z), bflo(o0.w), bfhi(o0.w),
                         bflo(o1.x), bfhi(o1.x), bflo(o1.y), bfhi(o1.y)};
        float y[FF1];
        #pragma unroll
        for (int j = 0; j < FF1; ++j) {
            float wv = vo[j] * sc[j] + sh[j];
            y[j] = wv > 0.f ? wv : 0.f;
        }
        unsigned short hh[FF2];
        #pragma unroll
        for (int j = 0; j < FF2; ++j) {
            float h = sb[j];
            #pragma unroll
            for (int q = 0; q < FF1; ++q) h += sWr[j * FF1 + q] * agg[q] + sWo[j * FF1 + q] * y[q];
            hh[j] = f2bf(h);
        }
        unsigned* p = h2b + i * 6;
        nts_u2(p,     (unsigned)hh[0] | ((unsigned)hh[1] << 16),
                      (unsigned)hh[2] | ((unsigned)hh[3] << 16));
        nts_u2(p + 2, (unsigned)hh[4] | ((unsigned)hh[5] << 16),
                      (unsigned)hh[6] | ((unsigned)hh[7] << 16));
        nts_u2(p + 4, (unsigned)hh[8] | ((unsigned)hh[9] << 16),
                      (unsigned)hh[10]| ((unsigned)hh[11] << 16));
    }
}

// ---------------------------------------------------------------------------
// GEMM1: A = relu(bn2(h2b)) bf16-stored, B = W1 f32; split-K=8 partials.
__global__ __launch_bounds__(256) void k_gemm1(const unsigned short* __restrict__ h2b,
                                               const float* __restrict__ ss2,
                                               const float* __restrict__ W1,
                                               float* __restrict__ hidp) {
    __shared__ float As[32][128];
    __shared__ float Bs[32][128];
    __shared__ float sc[FF2], sh[FF2];
    int t = threadIdx.x;
    if (t < FF2) { sc[t] = ss2[t]; sh[t] = ss2[FF2 + t]; }
    __syncthreads();
    int mb = blockIdx.x;
    int ks = blockIdx.y;
    const int KS = KDIM / 8;         // 1536
    int m0 = mb * 128;
    int kbase = ks * KS;
    int r  = t >> 1;
    int kg = t & 1;
    int tr = t >> 4;
    int tc = t & 15;
    float acc[8][8];
    #pragma unroll
    for (int i = 0; i < 8; ++i)
        #pragma unroll
        for (int j = 0; j < 8; ++j) acc[i][j] = 0.f;

    for (int kt = 0; kt < KS; kt += 32) {
        int c0 = kbase + kt + 16 * kg;
        const uint2* arow = (const uint2*)(h2b + (size_t)(m0 + r) * KDIM + c0);
        const float* brow = W1 + (size_t)r * KDIM + c0;
        #pragma unroll
        for (int i = 0; i < 4; ++i) {
            uint2 av = arow[i];
            int cc = c0 + 4 * i;
            int j0 = cc % FF2;
            float vals[4] = {bflo(av.x), bfhi(av.x), bflo(av.y), bfhi(av.y)};
            #pragma unroll
            for (int ii = 0; ii < 4; ++ii) {
                int j = j0 + ii; if (j >= FF2) j -= FF2;
                float v = vals[ii] * sc[j] + sh[j];
                As[16 * kg + 4 * i + ii][r] = v > 0.f ? v : 0.f;
            }
            float4 bv = *(const float4*)(brow + 4 * i);
            Bs[16 * kg + 4 * i + 0][r] = bv.x;
            Bs[16 * kg + 4 * i + 1][r] = bv.y;
            Bs[16 * kg + 4 * i + 2][r] = bv.z;
            Bs[16 * kg + 4 * i + 3][r] = bv.w;
        }
        __syncthreads();
        #pragma unroll
        for (int k = 0; k < 32; ++k) {
            float a[8], b[8];
            *(float4*)&a[0] = *(const float4*)&As[k][8 * tr];
            *(float4*)&a[4] = *(const float4*)&As[k][8 * tr + 4];
            *(float4*)&b[0] = *(const float4*)&Bs[k][8 * tc];
            *(float4*)&b[4] = *(const float4*)&Bs[k][8 * tc + 4];
            #pragma unroll
            for (int i = 0; i < 8; ++i)
                #pragma unroll
                for (int j = 0; j < 8; ++j) acc[i][j] += a[i] * b[j];
        }
        __syncthreads();
    }
    float* obase = hidp + (size_t)ks * (BATCHSZ * HIDD);
    #pragma unroll
    for (int i = 0; i < 8; ++i) {
        float* orow = obase + (size_t)(m0 + 8 * tr + i) * HIDD + 8 * tc;
        *(float4*)(orow)     = make_float4(acc[i][0], acc[i][1], acc[i][2], acc[i][3]);
        *(float4*)(orow + 4) = make_float4(acc[i][4], acc[i][5], acc[i][6], acc[i][7]);
    }
}

__global__ __launch_bounds__(256) void k_hred(const float* __restrict__ hidp,
                                              const float* __restrict__ bl1,
                                              float* __restrict__ hid) {
    int i = blockIdx.x * 256 + threadIdx.x;
    float s = bl1[i & (HIDD - 1)];
    #pragma unroll
    for (int p = 0; p < 8; ++p) s += hidp[(size_t)p * (BATCHSZ * HIDD) + i];
    hid[i] = s > 0.f ? s : 0.f;
}

// ---------------------------------------------------------------------------
__global__ __launch_bounds__(256) void k_gemm2(const float* __restrict__ hid,
                                               const float* __restrict__ W2,
                                               const float* __restrict__ bl2,
                                               float* __restrict__ out) {
    __shared__ float As[32][128];
    __shared__ float Bs[32][128];
    int t = threadIdx.x;
    int m0 = blockIdx.x * 128;
    int n0 = blockIdx.y * 128;
    int r  = t >> 1;
    int kg = t & 1;
    int tr = t >> 4;
    int tc = t & 15;
    float acc[8][8];
    #pragma unroll
    for (int i = 0; i < 8; ++i)
        #pragma unroll
        for (int j = 0; j < 8; ++j) acc[i][j] = 0.f;

    for (int kt = 0; kt < HIDD; kt += 32) {
        int c0 = kt + 16 * kg;
        #pragma unroll
        for (int i = 0; i < 4; ++i) {
            float4 av = *(const float4*)(hid + (size_t)(m0 + r) * HIDD + c0 + 4 * i);
            As[16 * kg + 4 * i + 0][r] = av.x;
            As[16 * kg + 4 * i + 1][r] = av.y;
            As[16 * kg + 4 * i + 2][r] = av.z;
            As[16 * kg + 4 * i + 3][r] = av.w;
            float4 bv = *(const float4*)(W2 + (size_t)(n0 + r) * HIDD + c0 + 4 * i);
            Bs[16 * kg + 4 * i + 0][r] = bv.x;
            Bs[16 * kg + 4 * i + 1][r] = bv.y;
            Bs[16 * kg + 4 * i + 2][r] = bv.z;
            Bs[16 * kg + 4 * i + 3][r] = bv.w;
        }
        __syncthreads();
        #pragma unroll
        for (int k = 0; k < 32; ++k) {
            float a[8], b[8];
            *(float4*)&a[0] = *(const float4*)&As[k][8 * tr];
            *(float4*)&a[4] = *(const float4*)&As[k][8 * tr + 4];
            *(float4*)&b[0] = *(const float4*)&Bs[k][8 * tc];
            *(float4*)&b[4] = *(const float4*)&Bs[k][8 * tc + 4];
            #pragma unroll
            for (int i = 0; i < 8; ++i)
                #pragma unroll
                for (int j = 0; j < 8; ++j) acc[i][j] += a[i] * b[j];
        }
        __syncthreads();
    }
    float4 c0v = *(const float4*)(bl2 + n0 + 8 * tc);
    float4 c1v = *(const float4*)(bl2 + n0 + 8 * tc + 4);
    float bvals[8] = {c0v.x, c0v.y, c0v.z, c0v.w, c1v.x, c1v.y, c1v.z, c1v.w};
    #pragma unroll
    for (int i = 0; i < 8; ++i) {
        size_t ro = (size_t)(m0 + 8 * tr + i) * ODIM + n0 + 8 * tc;
        *(float4*)(out + ro)     = make_float4(acc[i][0] + bvals[0], acc[i][1] + bvals[1],
                                               acc[i][2] + bvals[2], acc[i][3] + bvals[3]);
        *(float4*)(out + ro + 4) = make_float4(acc[i][4] + bvals[4], acc[i][5] + bvals[5],
                                               acc[i][6] + bvals[6], acc[i][7] + bvals[7]);
    }
}

// ---------------------------------------------------------------------------
extern "C" void kernel_launch(void* const* d_in, const int* in_sizes, int n_in,
                              void* d_out, int out_size, void* d_ws, size_t ws_size,
                              hipStream_t stream) {
    const float* x      = (const float*)d_in[0];
    const int*   ei     = (const int*)d_in[1];
    const float* Wrel1  = (const float*)d_in[3];
    const float* brel1  = (const float*)d_in[4];
    const float* Wroot1 = (const float*)d_in[5];
    const float* Wrel2  = (const float*)d_in[6];
    const float* brel2  = (const float*)d_in[7];
    const float* Wroot2 = (const float*)d_in[8];
    const float* g1     = (const float*)d_in[9];
    const float* b1     = (const float*)d_in[10];
    const float* g2     = (const float*)d_in[11];
    const float* b2     = (const float*)d_in[12];
    const float* W1     = (const float*)d_in[13];
    const float* bl1    = (const float*)d_in[14];
    const float* W2     = (const float*)d_in[15];
    const float* bl2    = (const float*)d_in[16];
    float* out = (float*)d_out;
    char* ws = (char*)d_ws;

    // Layout (liveness-overlaid), ~346 MB:
    //   pY  [0, SZ_P):       xb(67MB) -> [after conv1] h2b(100MB)+hidp(16MB)+hid(2MB)
    //   E   [SZ_P, +SZ_E):   fine bucket slots (75.5MB), unsorted packed edges
    //   pB  [.., +SZ_PB):    ebufA(135.8MB) -> h1p(134MB)
    //   pK: bcur(16KB), bcurA(256B), smalls
    const size_t req = SZ_P + SZ_E + SZ_PB + 32768;
    if (ws_size < req) {
        float v = (float)(ws_size >> 20);
        k_diag<<<(out_size + 255) / 256, 256, 0, stream>>>(out, out_size, v);
        return;
    }
    char* pY = ws;
    unsigned* ebuf = (unsigned*)(ws + SZ_P);
    char* pB = ws + SZ_P + SZ_E;
    char* pK = ws + SZ_P + SZ_E + SZ_PB;
    int*  bcur  = (int*)pK;                     // 4096 ints; ends after partB
    int*  bcurA = (int*)(pK + 16384);           // 64 ints; ends after partA
    char* smalls = pK + 20480;
    double* st1  = (double*)smalls;
    double* st2  = st1 + 2 * FF1;
    float*  ss1  = (float*)(st2 + 2 * FF2);
    float*  ss2  = ss1 + 2 * FF1;
    int*    flag = (int*)(ss2 + 2 * FF2);

    uint4*    xb    = (uint4*)pY;
    unsigned* h2b   = (unsigned*)pY;
    float*    hidp  = (float*)(pY + SZ_HB);
    float*    hid   = (float*)(pY + SZ_HB + 8 * SZ_HID);
    unsigned* ebufA = (unsigned*)pB;
    uint4*    h1p   = (uint4*)pB;

    hipMemsetAsync(smalls, 0, 1024, stream);
    k_init  <<<16, 256, 0, stream>>>(ei, flag, bcur, bcurA);
    k_padx  <<<NNODES / 4 / 256, 256, 0, stream>>>(x, xb);
    k_partA <<<512, 512, 0, stream>>>(ei, flag, bcurA, ebufA);
    k_partB <<<NCB * 4, 512, 0, stream>>>(ebufA, bcurA, bcur, ebuf);
    k_conv1 <<<NBKT, 256, 0, stream>>>(bcur, ebuf, xb, Wrel1, brel1, Wroot1, h1p);
    k_statsb<8><<<256, 256, 0, stream>>>((const unsigned*)h1p, st1);
    k_finalize<<<1, 64, 0, stream>>>(st1, g1, b1, ss1);
    k_conv2 <<<NBKT, 256, 0, stream>>>(bcur, ebuf, h1p, ss1, Wrel2, brel2, Wroot2, h2b);
    k_statsb<6><<<256, 256, 0, stream>>>(h2b, st2);
    k_finalize<<<1, 64, 0, stream>>>(st2, g2, b2, ss2);
    k_gemm1<<<dim3(BATCHSZ / 128, 8), 256, 0, stream>>>((const unsigned short*)h2b, ss2, W1, hidp);
    k_hred <<<BATCHSZ * HIDD / 256, 256, 0, stream>>>(hidp, bl1, hid);
    k_gemm2<<<dim3(BATCHSZ / 128, ODIM / 128), 256, 0, stream>>>(hid, W2, bl2, out);
}

// Round 15
// 1383.518 us; speedup vs baseline: 1.3935x; 1.0226x over previous
//
#include <hip/hip_runtime.h>
#include <hip/hip_bf16.h>

#define NBUS    1024
#define BATCHSZ 4096
#define NNODES  (NBUS*BATCHSZ)      // 4194304 = 2^22
#define NEDGES  (4*NNODES)          // 16777216
#define FIN     7
#define FF1     12
#define FF2     12
#define HIDD    128
#define KDIM    (NBUS*FF2)          // 12288
#define ODIM    (NBUS*2)            // 2048
#define NBKT    4096                // fine buckets of 1024 dst nodes
#define CAP     4608                // fine bucket capacity
#define NCB     64                  // coarse buckets of 65536 dst nodes
#define CAPA    265216              // coarse capacity (mean + 6 sigma)

#define SZ_P    ((size_t)NNODES * 32)                   // 134,217,728
#define SZ_HB   ((size_t)NNODES * FF2 * 2)              // 100,663,296
#define SZ_HID  ((size_t)BATCHSZ * HIDD * sizeof(float))//   2,097,152
#define SZ_E    ((size_t)NBKT * CAP * sizeof(unsigned)) //  75,497,472
#define SZ_PB   ((size_t)NCB * CAPA * 8)                // 135,790,592
#define SZ_W1B  ((size_t)HIDD * KDIM * 2)               //   3,145,728

typedef unsigned u32x2v  __attribute__((ext_vector_type(2)));
typedef unsigned u32x4v  __attribute__((ext_vector_type(4)));
typedef __attribute__((ext_vector_type(8))) short bf16x8;
typedef __attribute__((ext_vector_type(4))) float f32x4;

__device__ __forceinline__ float bflo(unsigned p){ return __uint_as_float(p << 16); }
__device__ __forceinline__ float bfhi(unsigned p){ return __uint_as_float(p & 0xffff0000u); }
__device__ __forceinline__ unsigned short f2bf(float f) {
    unsigned u = __float_as_uint(f);
    return (unsigned short)((u + 0x7fffu + ((u >> 16) & 1u)) >> 16);
}
__device__ __forceinline__ void nts_u2(unsigned* p, unsigned a, unsigned b) {
    u32x2v w; w.x = a; w.y = b;
    __builtin_nontemporal_store(w, (u32x2v*)p);
}
__device__ __forceinline__ void nts_u4(uint4* p, uint4 v) {
    u32x4v w; w.x = v.x; w.y = v.y; w.z = v.z; w.w = v.w;
    __builtin_nontemporal_store(w, (u32x4v*)p);
}
__device__ __forceinline__ uint2 ntl_u2(const unsigned* p) {
    u32x2v v = __builtin_nontemporal_load((const u32x2v*)p);
    uint2 r; r.x = v.x; r.y = v.y; return r;
}

__device__ __forceinline__ void acc7(float* agg, uint4 a) {
    agg[0] += bflo(a.x); agg[1] += bfhi(a.x);
    agg[2] += bflo(a.y); agg[3] += bfhi(a.y);
    agg[4] += bflo(a.z); agg[5] += bfhi(a.z);
    agg[6] += bflo(a.w);
}
__device__ __forceinline__ void accY(float* agg, const float* sc, const float* sh,
                                     uint4 r0, uint4 r1) {
    float v[FF1] = {bflo(r0.x), bfhi(r0.x), bflo(r0.y), bfhi(r0.y),
                    bflo(r0.z), bfhi(r0.z), bflo(r0.w), bfhi(r0.w),
                    bflo(r1.x), bfhi(r1.x), bflo(r1.y), bfhi(r1.y)};
    #pragma unroll
    for (int j = 0; j < FF1; ++j) {
        float y = v[j] * sc[j] + sh[j];
        agg[j] += (y > 0.f ? y : 0.f);
    }
}

// ---------------------------------------------------------------------------
__global__ void k_diag(float* __restrict__ out, int n, float v) {
    size_t i = (size_t)blockIdx.x * blockDim.x + threadIdx.x;
    if (i < (size_t)n) out[i] = v;
}

__global__ void k_init(const int* __restrict__ w, int* __restrict__ flag,
                       int* __restrict__ bcur, int* __restrict__ bcurA) {
    int u = blockIdx.x * 256 + threadIdx.x;
    if (u < NBKT) bcur[u] = u * CAP;
    if (u < NCB) bcurA[u] = u * CAPA;
    if (blockIdx.x == 0) {
        __shared__ int any;
        if (threadIdx.x == 0) any = 0;
        __syncthreads();
        int acc = 0;
        #pragma unroll
        for (int q = 0; q < 4; ++q) acc |= w[1 + 2 * (threadIdx.x * 4 + q)];
        if (acc) atomicOr(&any, 1);
        __syncthreads();
        if (threadIdx.x == 0) *flag = (any == 0) ? 2 : 1;
    }
}

// ---------------------------------------------------------------------------
// pass A: 64 coarse buckets (dst >> 16) as (src,dst); per-wave LDS histograms.
__global__ __launch_bounds__(512) void k_partA(const int* __restrict__ ei,
                                               const int* __restrict__ flag,
                                               int* __restrict__ bcurA,
                                               unsigned* __restrict__ ebufA) {
    __shared__ int hist[8][NCB];
    __shared__ int lbase[8][NCB];
    int t = threadIdx.x;
    int w8 = t >> 6;
    for (int u = t; u < 8 * NCB; u += 512) ((int*)hist)[u] = 0;
    __syncthreads();
    int mult = *flag;
    size_t base = (size_t)blockIdx.x * 32768;          // 512 blocks
    #pragma unroll 4
    for (int u = 0; u < 64; ++u) {
        size_t e = base + (size_t)u * 512 + t;
        int d = __builtin_nontemporal_load(ei + ((size_t)NEDGES + e) * mult);
        atomicAdd(&hist[w8][d >> 16], 1);
    }
    __syncthreads();
    if (t < NCB) {
        int c[8]; int ctot = 0;
        #pragma unroll
        for (int ww = 0; ww < 8; ++ww) { c[ww] = hist[ww][t]; ctot += c[ww]; }
        int bg = ctot ? atomicAdd(&bcurA[t], ctot) : 0;
        #pragma unroll
        for (int ww = 0; ww < 8; ++ww) { lbase[ww][t] = bg; bg += c[ww]; hist[ww][t] = 0; }
    }
    __syncthreads();
    #pragma unroll 4
    for (int u = 0; u < 64; ++u) {
        size_t e = base + (size_t)u * 512 + t;
        int s = __builtin_nontemporal_load(ei + e * mult);
        int d = __builtin_nontemporal_load(ei + ((size_t)NEDGES + e) * mult);
        int bk = d >> 16;
        int pos = lbase[w8][bk] + atomicAdd(&hist[w8][bk], 1);
        if (pos < (bk + 1) * CAPA) {
            uint2* p = (uint2*)(ebufA + (size_t)pos * 2);
            *p = make_uint2((unsigned)s, (unsigned)d);
        }
    }
}

// ---------------------------------------------------------------------------
// pass B: 4 blocks per coarse bucket -> 64 fine buckets; per-wave histograms.
__global__ __launch_bounds__(512) void k_partB(const unsigned* __restrict__ ebufA,
                                               const int* __restrict__ bendA,
                                               int* __restrict__ bcur,
                                               unsigned* __restrict__ ebuf) {
    __shared__ int hist[8][NCB];
    __shared__ int lbase[8][NCB];
    int t = threadIdx.x;
    int w8 = t >> 6;
    int cb = blockIdx.x >> 2;
    int qq = blockIdx.x & 3;
    int abeg = cb * CAPA;
    int n = bendA[cb] - abeg; if (n > CAPA) n = CAPA;
    int beg = abeg + (int)(((long long)n * qq) >> 2);
    int end = abeg + (int)(((long long)n * (qq + 1)) >> 2);
    for (int u = t; u < 8 * NCB; u += 512) ((int*)hist)[u] = 0;
    __syncthreads();
    for (int k = beg + t; k < end; k += 512) {
        uint2 e = ntl_u2(ebufA + (size_t)k * 2);
        atomicAdd(&hist[w8][(e.y >> 10) & 63u], 1);
    }
    __syncthreads();
    if (t < NCB) {
        int c[8]; int ctot = 0;
        #pragma unroll
        for (int ww = 0; ww < 8; ++ww) { c[ww] = hist[ww][t]; ctot += c[ww]; }
        int bg = ctot ? atomicAdd(&bcur[cb * 64 + t], ctot) : 0;
        #pragma unroll
        for (int ww = 0; ww < 8; ++ww) { lbase[ww][t] = bg; bg += c[ww]; hist[ww][t] = 0; }
    }
    __syncthreads();
    for (int k = beg + t; k < end; k += 512) {
        uint2 e = ntl_u2(ebufA + (size_t)k * 2);
        int lb = (e.y >> 10) & 63u;
        int fb = cb * 64 + lb;
        int pos = lbase[w8][lb] + atomicAdd(&hist[w8][lb], 1);
        if (pos < (fb + 1) * CAP)
            ebuf[pos] = (e.x << 10) | (e.y & 1023u);
    }
}

// ---------------------------------------------------------------------------
__global__ __launch_bounds__(256) void k_padx(const float* __restrict__ x,
                                              uint4* __restrict__ xb) {
    size_t q = (size_t)blockIdx.x * blockDim.x + threadIdx.x;
    if (q >= NNODES / 4) return;
    const float4* xr = (const float4*)(x + q * 28);
    float v[28];
    #pragma unroll
    for (int u = 0; u < 7; ++u) {
        float4 f = xr[u];
        v[4*u] = f.x; v[4*u+1] = f.y; v[4*u+2] = f.z; v[4*u+3] = f.w;
    }
    #pragma unroll
    for (int n = 0; n < 4; ++n) {
        unsigned short h[8];
        #pragma unroll
        for (int j = 0; j < 7; ++j) h[j] = f2bf(v[7*n + j]);
        h[7] = 0;
        uint4 o;
        o.x = (unsigned)h[0] | ((unsigned)h[1] << 16);
        o.y = (unsigned)h[2] | ((unsigned)h[3] << 16);
        o.z = (unsigned)h[4] | ((unsigned)h[5] << 16);
        o.w = (unsigned)h[6] | ((unsigned)h[7] << 16);
        xb[q * 4 + n] = o;
    }
}

// W1 (f32 [128][12288]) -> bf16
__global__ __launch_bounds__(256) void k_w1b(const float* __restrict__ W1,
                                             uint4* __restrict__ w1b) {
    size_t q = (size_t)blockIdx.x * blockDim.x + threadIdx.x;   // 8 elems each
    if (q >= (size_t)HIDD * KDIM / 8) return;
    const float4* r = (const float4*)(W1 + q * 8);
    float4 a = r[0], b = r[1];
    uint4 o;
    o.x = (unsigned)f2bf(a.x) | ((unsigned)f2bf(a.y) << 16);
    o.y = (unsigned)f2bf(a.z) | ((unsigned)f2bf(a.w) << 16);
    o.z = (unsigned)f2bf(b.x) | ((unsigned)f2bf(b.y) << 16);
    o.w = (unsigned)f2bf(b.z) | ((unsigned)f2bf(b.w) << 16);
    w1b[q] = o;
}

// ---------------------------------------------------------------------------
// conv1: in-LDS counting sort, register gather of xb; h1p bf16 32B rows out.
__global__ __launch_bounds__(256, 4) void k_conv1(const int* __restrict__ bend,
                                                  const unsigned* __restrict__ ebuf,
                                                  const uint4* __restrict__ xb,
                                                  const float* __restrict__ Wrel,
                                                  const float* __restrict__ brel,
                                                  const float* __restrict__ Wroot,
                                                  uint4* __restrict__ h1p) {
    __shared__ unsigned stage[CAP];
    __shared__ int hist[1024];
    __shared__ int offL[1024];
    __shared__ int wsum[4];
    __shared__ float sWr[FF1 * FIN], sWo[FF1 * FIN], sb[FF1];
    int t = threadIdx.x;
    if (t < FF1 * FIN) { sWr[t] = Wrel[t]; sWo[t] = Wroot[t]; }
    if (t < FF1) sb[t] = brel[t];
    int bk = blockIdx.x;
    int ebeg = bk * CAP;
    int n = bend[bk] - ebeg; if (n > CAP) n = CAP; if (n < 0) n = 0;
    for (int u = t; u < 1024; u += 256) hist[u] = 0;
    __syncthreads();
    for (int k = t; k < n; k += 256)
        atomicAdd(&hist[ebuf[ebeg + k] & 1023u], 1);
    __syncthreads();
    int v[4]; int s = 0;
    #pragma unroll
    for (int u = 0; u < 4; ++u) { v[u] = hist[t * 4 + u]; s += v[u]; }
    int lane = t & 63, w = t >> 6;
    int iv = s;
    for (int o = 1; o < 64; o <<= 1) { int uu = __shfl_up(iv, o); if (lane >= o) iv += uu; }
    if (lane == 63) wsum[w] = iv;
    __syncthreads();
    int basep = 0;
    #pragma unroll
    for (int ww = 0; ww < 4; ++ww) if (ww < w) basep += wsum[ww];
    int run = basep + iv - s;
    #pragma unroll
    for (int u = 0; u < 4; ++u) {
        offL[t * 4 + u] = run;
        hist[t * 4 + u] = run;
        run += v[u];
    }
    __syncthreads();
    for (int k = t; k < n; k += 256) {
        unsigned p = ebuf[ebeg + k];
        int pos = atomicAdd(&hist[p & 1023u], 1);
        stage[pos] = p >> 10;
    }
    __syncthreads();
    #pragma unroll
    for (int nn = 0; nn < 4; ++nn) {
        int li = nn * 256 + t;
        size_t i = (size_t)bk * 1024 + li;
        int beg = offL[li];
        int end = (li == 1023) ? n : offL[li + 1];
        float agg[FIN] = {0.f, 0.f, 0.f, 0.f, 0.f, 0.f, 0.f};
        int k = beg;
        for (; k + 3 < end; k += 4) {
            unsigned s0 = stage[k], s1 = stage[k+1], s2 = stage[k+2], s3 = stage[k+3];
            uint4 a0 = xb[s0], a1 = xb[s1], a2 = xb[s2], a3 = xb[s3];
            acc7(agg, a0); acc7(agg, a1); acc7(agg, a2); acc7(agg, a3);
        }
        for (; k < end; ++k) acc7(agg, xb[stage[k]]);
        uint4 ow = xb[i];
        float xv[FIN] = {bflo(ow.x), bfhi(ow.x), bflo(ow.y), bfhi(ow.y),
                         bflo(ow.z), bfhi(ow.z), bflo(ow.w)};
        unsigned short hh[FF1];
        #pragma unroll
        for (int j = 0; j < FF1; ++j) {
            float h = sb[j];
            #pragma unroll
            for (int q = 0; q < FIN; ++q) h += sWr[j * FIN + q] * agg[q] + sWo[j * FIN + q] * xv[q];
            hh[j] = f2bf(h);
        }
        uint4 w1, w2;
        w1.x = (unsigned)hh[0] | ((unsigned)hh[1] << 16);
        w1.y = (unsigned)hh[2] | ((unsigned)hh[3] << 16);
        w1.z = (unsigned)hh[4] | ((unsigned)hh[5] << 16);
        w1.w = (unsigned)hh[6] | ((unsigned)hh[7] << 16);
        w2.x = (unsigned)hh[8] | ((unsigned)hh[9] << 16);
        w2.y = (unsigned)hh[10]| ((unsigned)hh[11] << 16);
        w2.z = 0u; w2.w = 0u;
        nts_u4(h1p + i * 2, w1);
        nts_u4(h1p + i * 2 + 1, w2);
    }
}

// ---------------------------------------------------------------------------
template<int STRIDE>
__global__ __launch_bounds__(256) void k_statsb(const unsigned* __restrict__ hb,
                                                double* __restrict__ stats) {
    __shared__ float red[4][FF1], redq[4][FF1];
    int t = threadIdx.x;
    float ps[FF1], pq[FF1];
    #pragma unroll
    for (int j = 0; j < FF1; ++j) { ps[j] = 0.f; pq[j] = 0.f; }
    for (size_t i = (size_t)blockIdx.x * 256 + t; i < NNODES; i += 256 * 256) {
        const uint2* r = (const uint2*)(hb + i * STRIDE);
        uint2 u0 = r[0], u1 = r[1], u2 = r[2];
        float v[FF1] = {bflo(u0.x), bfhi(u0.x), bflo(u0.y), bfhi(u0.y),
                        bflo(u1.x), bfhi(u1.x), bflo(u1.y), bfhi(u1.y),
                        bflo(u2.x), bfhi(u2.x), bflo(u2.y), bfhi(u2.y)};
        #pragma unroll
        for (int j = 0; j < FF1; ++j) { ps[j] += v[j]; pq[j] += v[j] * v[j]; }
    }
    #pragma unroll
    for (int j = 0; j < FF1; ++j)
        for (int o = 1; o < 64; o <<= 1) { ps[j] += __shfl_xor(ps[j], o); pq[j] += __shfl_xor(pq[j], o); }
    int lane = t & 63, wv = t >> 6;
    if (lane == 0) {
        #pragma unroll
        for (int j = 0; j < FF1; ++j) { red[wv][j] = ps[j]; redq[wv][j] = pq[j]; }
    }
    __syncthreads();
    if (t < FF1) {
        float s = red[0][t] + red[1][t] + red[2][t] + red[3][t];
        float q = redq[0][t] + redq[1][t] + redq[2][t] + redq[3][t];
        atomicAdd(&stats[t], (double)s);
        atomicAdd(&stats[FF1 + t], (double)q);
    }
}

// ---------------------------------------------------------------------------
__global__ void k_finalize(const double* __restrict__ stats, const float* __restrict__ g,
                           const float* __restrict__ b, float* __restrict__ ss) {
    int j = threadIdx.x;
    if (j < FF1) {
        double mean = stats[j] * (1.0 / NNODES);
        double var  = stats[FF1 + j] * (1.0 / NNODES) - mean * mean;
        float sc = (float)((double)g[j] / sqrt(var + 1e-5));
        ss[j] = sc;
        ss[FF1 + j] = b[j] - (float)mean * sc;
    }
}

// ---------------------------------------------------------------------------
// conv2: in-LDS sort; gather h1p (32B rows), bn1+relu inline; h2 bf16 nt out.
__global__ __launch_bounds__(256, 4) void k_conv2(const int* __restrict__ bend,
                                                  const unsigned* __restrict__ ebuf,
                                                  const uint4* __restrict__ h1p,
                                                  const float* __restrict__ ss,
                                                  const float* __restrict__ Wrel,
                                                  const float* __restrict__ brel,
                                                  const float* __restrict__ Wroot,
                                                  unsigned* __restrict__ h2b) {
    __shared__ unsigned stage[CAP];
    __shared__ int hist[1024];
    __shared__ int offL[1024];
    __shared__ int wsum[4];
    __shared__ float sWr[FF2 * FF1], sWo[FF2 * FF1], sb[FF2], sc[FF1], sh[FF1];
    int t = threadIdx.x;
    if (t < FF2 * FF1) { sWr[t] = Wrel[t]; sWo[t] = Wroot[t]; }
    if (t < FF2) { sb[t] = brel[t]; sc[t] = ss[t]; sh[t] = ss[FF1 + t]; }
    int bk = blockIdx.x;
    int ebeg = bk * CAP;
    int n = bend[bk] - ebeg; if (n > CAP) n = CAP; if (n < 0) n = 0;
    for (int u = t; u < 1024; u += 256) hist[u] = 0;
    __syncthreads();
    for (int k = t; k < n; k += 256)
        atomicAdd(&hist[ebuf[ebeg + k] & 1023u], 1);
    __syncthreads();
    int v[4]; int s = 0;
    #pragma unroll
    for (int u = 0; u < 4; ++u) { v[u] = hist[t * 4 + u]; s += v[u]; }
    int lane = t & 63, w = t >> 6;
    int iv = s;
    for (int o = 1; o < 64; o <<= 1) { int uu = __shfl_up(iv, o); if (lane >= o) iv += uu; }
    if (lane == 63) wsum[w] = iv;
    __syncthreads();
    int basep = 0;
    #pragma unroll
    for (int ww = 0; ww < 4; ++ww) if (ww < w) basep += wsum[ww];
    int run = basep + iv - s;
    #pragma unroll
    for (int u = 0; u < 4; ++u) {
        offL[t * 4 + u] = run;
        hist[t * 4 + u] = run;
        run += v[u];
    }
    __syncthreads();
    for (int k = t; k < n; k += 256) {
        unsigned p = ebuf[ebeg + k];
        int pos = atomicAdd(&hist[p & 1023u], 1);
        stage[pos] = p >> 10;
    }
    __syncthreads();
    #pragma unroll
    for (int nn = 0; nn < 4; ++nn) {
        int li = nn * 256 + t;
        size_t i = (size_t)bk * 1024 + li;
        int beg = offL[li];
        int end = (li == 1023) ? n : offL[li + 1];
        float agg[FF1];
        #pragma unroll
        for (int j = 0; j < FF1; ++j) agg[j] = 0.f;
        int k = beg;
        for (; k + 3 < end; k += 4) {
            unsigned s0 = stage[k], s1 = stage[k+1], s2 = stage[k+2], s3 = stage[k+3];
            uint4 a0 = h1p[(size_t)s0 * 2], a1 = h1p[(size_t)s0 * 2 + 1];
            uint4 b0 = h1p[(size_t)s1 * 2], b1 = h1p[(size_t)s1 * 2 + 1];
            uint4 c0 = h1p[(size_t)s2 * 2], c1 = h1p[(size_t)s2 * 2 + 1];
            uint4 d0 = h1p[(size_t)s3 * 2], d1 = h1p[(size_t)s3 * 2 + 1];
            accY(agg, sc, sh, a0, a1);
            accY(agg, sc, sh, b0, b1);
            accY(agg, sc, sh, c0, c1);
            accY(agg, sc, sh, d0, d1);
        }
        for (; k < end; ++k) {
            unsigned s0 = stage[k];
            accY(agg, sc, sh, h1p[(size_t)s0 * 2], h1p[(size_t)s0 * 2 + 1]);
        }
        uint4 o0 = h1p[i * 2], o1 = h1p[i * 2 + 1];
        float vo[FF1] = {bflo(o0.x), bfhi(o0.x), bflo(o0.y), bfhi(o0.y),
                         bflo(o0.z), bfhi(o0.z), bflo(o0.w), bfhi(o0.w),
                         bflo(o1.x), bfhi(o1.x), bflo(o1.y), bfhi(o1.y)};
        float y[FF1];
        #pragma unroll
        for (int j = 0; j < FF1; ++j) {
            float wv = vo[j] * sc[j] + sh[j];
            y[j] = wv > 0.f ? wv : 0.f;
        }
        unsigned short hh[FF2];
        #pragma unroll
        for (int j = 0; j < FF2; ++j) {
            float h = sb[j];
            #pragma unroll
            for (int q = 0; q < FF1; ++q) h += sWr[j * FF1 + q] * agg[q] + sWo[j * FF1 + q] * y[q];
            hh[j] = f2bf(h);
        }
        unsigned* p = h2b + i * 6;
        nts_u2(p,     (unsigned)hh[0] | ((unsigned)hh[1] << 16),
                      (unsigned)hh[2] | ((unsigned)hh[3] << 16));
        nts_u2(p + 2, (unsigned)hh[4] | ((unsigned)hh[5] << 16),
                      (unsigned)hh[6] | ((unsigned)hh[7] << 16));
        nts_u2(p + 4, (unsigned)hh[8] | ((unsigned)hh[9] << 16),
                      (unsigned)hh[10]| ((unsigned)hh[11] << 16));
    }
}

// ---------------------------------------------------------------------------
// GEMM1 via MFMA bf16: hidp[ks] = relu(bn2(A)) @ W1b^T over K-chunk ks.
// A = h2b [4096][12288] bf16; W1b [128][12288] bf16; 2x2 waves, 4x4 frags.
__global__ __launch_bounds__(256) void k_gemm1m(const unsigned short* __restrict__ h2b,
                                                const float* __restrict__ ss2,
                                                const unsigned short* __restrict__ w1b,
                                                float* __restrict__ hidp) {
    __shared__ float sc[FF2], sh[FF2];
    int t = threadIdx.x;
    if (t < FF2) { sc[t] = ss2[t]; sh[t] = ss2[FF2 + t]; }
    __syncthreads();
    const int KS = KDIM / 8;          // 1536
    int mb = blockIdx.x;              // 0..31
    int ks = blockIdx.y;              // 0..7
    int wid = t >> 6;
    int lane = t & 63;
    int wm = wid >> 1, wn = wid & 1;  // 2x2 wave grid
    int m0 = mb * 128 + wm * 64;
    int n0 = wn * 64;
    int lrow = lane & 15;
    int kgrp = lane >> 4;             // 0..3
    f32x4 acc[4][4];
    #pragma unroll
    for (int mi = 0; mi < 4; ++mi)
        #pragma unroll
        for (int ni = 0; ni < 4; ++ni) acc[mi][ni] = (f32x4)(0.f);
    int kbase = ks * KS;
    for (int k0 = 0; k0 < KS; k0 += 32) {
        int kk = kbase + k0 + kgrp * 8;
        bf16x8 af[4], bf[4];
        #pragma unroll
        for (int mi = 0; mi < 4; ++mi) {
            const unsigned short* ap = h2b + (size_t)(m0 + mi * 16 + lrow) * KDIM + kk;
            uint4 av = *(const uint4*)ap;
            unsigned hw[8] = {av.x & 0xffffu, av.x >> 16, av.y & 0xffffu, av.y >> 16,
                              av.z & 0xffffu, av.z >> 16, av.w & 0xffffu, av.w >> 16};
            int j = kk % FF2;
            bf16x8 r;
            #pragma unroll
            for (int u = 0; u < 8; ++u) {
                float f = __uint_as_float(hw[u] << 16);
                float y = f * sc[j] + sh[j];
                y = y > 0.f ? y : 0.f;
                r[u] = (short)f2bf(y);
                ++j; if (j >= FF2) j = 0;
            }
            af[mi] = r;
        }
        #pragma unroll
        for (int ni = 0; ni < 4; ++ni)
            bf[ni] = *(const bf16x8*)(w1b + (size_t)(n0 + ni * 16 + lrow) * KDIM + kk);
        #pragma unroll
        for (int mi = 0; mi < 4; ++mi)
            #pragma unroll
            for (int ni = 0; ni < 4; ++ni)
                acc[mi][ni] = __builtin_amdgcn_mfma_f32_16x16x32_bf16(
                    af[mi], bf[ni], acc[mi][ni], 0, 0, 0);
    }
    float* obase = hidp + (size_t)ks * (BATCHSZ * HIDD);
    #pragma unroll
    for (int mi = 0; mi < 4; ++mi) {
        #pragma unroll
        for (int ni = 0; ni < 4; ++ni) {
            #pragma unroll
            for (int reg = 0; reg < 4; ++reg) {
                int row = m0 + mi * 16 + kgrp * 4 + reg;
                int col = n0 + ni * 16 + lrow;
                obase[(size_t)row * HIDD + col] = acc[mi][ni][reg];
            }
        }
    }
}

__global__ __launch_bounds__(256) void k_hred(const float* __restrict__ hidp,
                                              const float* __restrict__ bl1,
                                              float* __restrict__ hid) {
    int i = blockIdx.x * 256 + threadIdx.x;
    float s = bl1[i & (HIDD - 1)];
    #pragma unroll
    for (int p = 0; p < 8; ++p) s += hidp[(size_t)p * (BATCHSZ * HIDD) + i];
    hid[i] = s > 0.f ? s : 0.f;
}

// ---------------------------------------------------------------------------
__global__ __launch_bounds__(256) void k_gemm2(const float* __restrict__ hid,
                                               const float* __restrict__ W2,
                                               const float* __restrict__ bl2,
                                               float* __restrict__ out) {
    __shared__ float As[32][128];
    __shared__ float Bs[32][128];
    int t = threadIdx.x;
    int m0 = blockIdx.x * 128;
    int n0 = blockIdx.y * 128;
    int r  = t >> 1;
    int kg = t & 1;
    int tr = t >> 4;
    int tc = t & 15;
    float acc[8][8];
    #pragma unroll
    for (int i = 0; i < 8; ++i)
        #pragma unroll
        for (int j = 0; j < 8; ++j) acc[i][j] = 0.f;

    for (int kt = 0; kt < HIDD; kt += 32) {
        int c0 = kt + 16 * kg;
        #pragma unroll
        for (int i = 0; i < 4; ++i) {
            float4 av = *(const float4*)(hid + (size_t)(m0 + r) * HIDD + c0 + 4 * i);
            As[16 * kg + 4 * i + 0][r] = av.x;
            As[16 * kg + 4 * i + 1][r] = av.y;
            As[16 * kg + 4 * i + 2][r] = av.z;
            As[16 * kg + 4 * i + 3][r] = av.w;
            float4 bv = *(const float4*)(W2 + (size_t)(n0 + r) * HIDD + c0 + 4 * i);
            Bs[16 * kg + 4 * i + 0][r] = bv.x;
            Bs[16 * kg + 4 * i + 1][r] = bv.y;
            Bs[16 * kg + 4 * i + 2][r] = bv.z;
            Bs[16 * kg + 4 * i + 3][r] = bv.w;
        }
        __syncthreads();
        #pragma unroll
        for (int k = 0; k < 32; ++k) {
            float a[8], b[8];
            *(float4*)&a[0] = *(const float4*)&As[k][8 * tr];
            *(float4*)&a[4] = *(const float4*)&As[k][8 * tr + 4];
            *(float4*)&b[0] = *(const float4*)&Bs[k][8 * tc];
            *(float4*)&b[4] = *(const float4*)&Bs[k][8 * tc + 4];
            #pragma unroll
            for (int i = 0; i < 8; ++i)
                #pragma unroll
                for (int j = 0; j < 8; ++j) acc[i][j] += a[i] * b[j];
        }
        __syncthreads();
    }
    float4 c0v = *(const float4*)(bl2 + n0 + 8 * tc);
    float4 c1v = *(const float4*)(bl2 + n0 + 8 * tc + 4);
    float bvals[8] = {c0v.x, c0v.y, c0v.z, c0v.w, c1v.x, c1v.y, c1v.z, c1v.w};
    #pragma unroll
    for (int i = 0; i < 8; ++i) {
        size_t ro = (size_t)(m0 + 8 * tr + i) * ODIM + n0 + 8 * tc;
        *(float4*)(out + ro)     = make_float4(acc[i][0] + bvals[0], acc[i][1] + bvals[1],
                                               acc[i][2] + bvals[2], acc[i][3] + bvals[3]);
        *(float4*)(out + ro + 4) = make_float4(acc[i][4] + bvals[4], acc[i][5] + bvals[5],
                                               acc[i][6] + bvals[6], acc[i][7] + bvals[7]);
    }
}

// ---------------------------------------------------------------------------
extern "C" void kernel_launch(void* const* d_in, const int* in_sizes, int n_in,
                              void* d_out, int out_size, void* d_ws, size_t ws_size,
                              hipStream_t stream) {
    const float* x      = (const float*)d_in[0];
    const int*   ei     = (const int*)d_in[1];
    const float* Wrel1  = (const float*)d_in[3];
    const float* brel1  = (const float*)d_in[4];
    const float* Wroot1 = (const float*)d_in[5];
    const float* Wrel2  = (const float*)d_in[6];
    const float* brel2  = (const float*)d_in[7];
    const float* Wroot2 = (const float*)d_in[8];
    const float* g1     = (const float*)d_in[9];
    const float* b1     = (const float*)d_in[10];
    const float* g2     = (const float*)d_in[11];
    const float* b2     = (const float*)d_in[12];
    const float* W1     = (const float*)d_in[13];
    const float* bl1    = (const float*)d_in[14];
    const float* W2     = (const float*)d_in[15];
    const float* bl2    = (const float*)d_in[16];
    float* out = (float*)d_out;
    char* ws = (char*)d_ws;

    // Layout (liveness-overlaid), ~350 MB:
    //   pY  [0, SZ_P):       xb(67MB) -> [after conv1] h2b(100MB)+hidp(16MB)+hid(2MB)
    //   E   [SZ_P, +SZ_E):   fine bucket slots (75.5MB)
    //   pB  [.., +SZ_PB):    ebufA(135.8MB) -> h1p(134MB)
    //   pK:  bcur(16KB), bcurA(256B), smalls(12KB), w1b(3MB)
    const size_t req = SZ_P + SZ_E + SZ_PB + 32768 + SZ_W1B;
    if (ws_size < req) {
        float v = (float)(ws_size >> 20);
        k_diag<<<(out_size + 255) / 256, 256, 0, stream>>>(out, out_size, v);
        return;
    }
    char* pY = ws;
    unsigned* ebuf = (unsigned*)(ws + SZ_P);
    char* pB = ws + SZ_P + SZ_E;
    char* pK = ws + SZ_P + SZ_E + SZ_PB;
    int*  bcur  = (int*)pK;
    int*  bcurA = (int*)(pK + 16384);
    char* smalls = pK + 20480;
    double* st1  = (double*)smalls;
    double* st2  = st1 + 2 * FF1;
    float*  ss1  = (float*)(st2 + 2 * FF2);
    float*  ss2  = ss1 + 2 * FF1;
    int*    flag = (int*)(ss2 + 2 * FF2);
    uint4*  w1b  = (uint4*)(pK + 32768);

    uint4*    xb    = (uint4*)pY;
    unsigned* h2b   = (unsigned*)pY;
    float*    hidp  = (float*)(pY + SZ_HB);
    float*    hid   = (float*)(pY + SZ_HB + 8 * SZ_HID);
    unsigned* ebufA = (unsigned*)pB;
    uint4*    h1p   = (uint4*)pB;

    hipMemsetAsync(smalls, 0, 1024, stream);
    k_init  <<<16, 256, 0, stream>>>(ei, flag, bcur, bcurA);
    k_padx  <<<NNODES / 4 / 256, 256, 0, stream>>>(x, xb);
    k_w1b   <<<HIDD * KDIM / 8 / 256, 256, 0, stream>>>(W1, w1b);
    k_partA <<<512, 512, 0, stream>>>(ei, flag, bcurA, ebufA);
    k_partB <<<NCB * 4, 512, 0, stream>>>(ebufA, bcurA, bcur, ebuf);
    k_conv1 <<<NBKT, 256, 0, stream>>>(bcur, ebuf, xb, Wrel1, brel1, Wroot1, h1p);
    k_statsb<8><<<256, 256, 0, stream>>>((const unsigned*)h1p, st1);
    k_finalize<<<1, 64, 0, stream>>>(st1, g1, b1, ss1);
    k_conv2 <<<NBKT, 256, 0, stream>>>(bcur, ebuf, h1p, ss1, Wrel2, brel2, Wroot2, h2b);
    k_statsb<6><<<256, 256, 0, stream>>>(h2b, st2);
    k_finalize<<<1, 64, 0, stream>>>(st2, g2, b2, ss2);
    k_gemm1m<<<dim3(BATCHSZ / 128, 8), 256, 0, stream>>>((const unsigned short*)h2b, ss2,
                                                         (const unsigned short*)w1b, hidp);
    k_hred <<<BATCHSZ * HIDD / 256, 256, 0, stream>>>(hidp, bl1, hid);
    k_gemm2<<<dim3(BATCHSZ / 128, ODIM / 128), 256, 0, stream>>>(hid, W2, bl2, out);
}

// Round 16
// 1188.272 us; speedup vs baseline: 1.6225x; 1.1643x over previous
//
#include <hip/hip_runtime.h>
#include <hip/hip_bf16.h>

#define NBUS    1024
#define BATCHSZ 4096
#define NNODES  (NBUS*BATCHSZ)      // 4194304 = 2^22
#define NEDGES  (4*NNODES)          // 16777216
#define FIN     7
#define FF1     12
#define FF2     12
#define HIDD    128
#define KDIM    (NBUS*FF2)          // 12288
#define ODIM    (NBUS*2)            // 2048
#define NBKT    4096                // fine buckets of 1024 dst nodes
#define NCB     64                  // coarse buckets of 65536 dst nodes
#define NBLKA   512                 // partA blocks
#define CAPW    648                 // per (cb,blk) capacity: mean 512 + 6 sigma
#define CAPQ    1216                // per (fb,q) capacity: mean 1024 + 6 sigma
#define STCAP   4864                // conv stage capacity (4*CAPQ)

#define SZ_P    ((size_t)NNODES * 32)                   // 134,217,728 (xb -> h2b+hidp+hid)
#define SZ_HB   ((size_t)NNODES * FF2 * 2)              // 100,663,296
#define SZ_HID  ((size_t)BATCHSZ * HIDD * sizeof(float))//   2,097,152
#define SZ_E    ((size_t)NBKT * 4 * CAPQ * 4)           //  79,691,776
#define SZ_A    ((size_t)NCB * NBLKA * CAPW * 8)        // 169,869,312 (ebufA -> h1p)
#define SZ_W1B  ((size_t)HIDD * KDIM * 2)               //   3,145,728

typedef unsigned u32x2v  __attribute__((ext_vector_type(2)));
typedef unsigned u32x4v  __attribute__((ext_vector_type(4)));
typedef __attribute__((ext_vector_type(8))) short bf16x8;
typedef __attribute__((ext_vector_type(4))) float f32x4;

__device__ __forceinline__ float bflo(unsigned p){ return __uint_as_float(p << 16); }
__device__ __forceinline__ float bfhi(unsigned p){ return __uint_as_float(p & 0xffff0000u); }
__device__ __forceinline__ unsigned short f2bf(float f) {
    unsigned u = __float_as_uint(f);
    return (unsigned short)((u + 0x7fffu + ((u >> 16) & 1u)) >> 16);
}
__device__ __forceinline__ void nts_u2(unsigned* p, unsigned a, unsigned b) {
    u32x2v w; w.x = a; w.y = b;
    __builtin_nontemporal_store(w, (u32x2v*)p);
}
__device__ __forceinline__ void nts_u4(uint4* p, uint4 v) {
    u32x4v w; w.x = v.x; w.y = v.y; w.z = v.z; w.w = v.w;
    __builtin_nontemporal_store(w, (u32x4v*)p);
}
__device__ __forceinline__ uint2 ntl_u2(const unsigned* p) {
    u32x2v v = __builtin_nontemporal_load((const u32x2v*)p);
    uint2 r; r.x = v.x; r.y = v.y; return r;
}

__device__ __forceinline__ void acc7(float* agg, uint4 a) {
    agg[0] += bflo(a.x); agg[1] += bfhi(a.x);
    agg[2] += bflo(a.y); agg[3] += bfhi(a.y);
    agg[4] += bflo(a.z); agg[5] += bfhi(a.z);
    agg[6] += bflo(a.w);
}
__device__ __forceinline__ void accY(float* agg, const float* sc, const float* sh,
                                     uint4 r0, uint4 r1) {
    float v[FF1] = {bflo(r0.x), bfhi(r0.x), bflo(r0.y), bfhi(r0.y),
                    bflo(r0.z), bfhi(r0.z), bflo(r0.w), bfhi(r0.w),
                    bflo(r1.x), bfhi(r1.x), bflo(r1.y), bfhi(r1.y)};
    #pragma unroll
    for (int j = 0; j < FF1; ++j) {
        float y = v[j] * sc[j] + sh[j];
        agg[j] += (y > 0.f ? y : 0.f);
    }
}

// ---------------------------------------------------------------------------
__global__ void k_diag(float* __restrict__ out, int n, float v) {
    size_t i = (size_t)blockIdx.x * blockDim.x + threadIdx.x;
    if (i < (size_t)n) out[i] = v;
}

// int64/int32 edge_index detection
__global__ void k_init(const int* __restrict__ w, int* __restrict__ flag) {
    __shared__ int any;
    if (threadIdx.x == 0) any = 0;
    __syncthreads();
    int acc = 0;
    #pragma unroll
    for (int q = 0; q < 4; ++q) acc |= w[1 + 2 * (threadIdx.x * 4 + q)];
    if (acc) atomicOr(&any, 1);
    __syncthreads();
    if (threadIdx.x == 0) *flag = (any == 0) ? 2 : 1;
}

// ---------------------------------------------------------------------------
// partA single-pass: 64 coarse buckets into block-private slots; LDS cursors.
__global__ __launch_bounds__(512) void k_partA(const int* __restrict__ ei,
                                               const int* __restrict__ flag,
                                               unsigned* __restrict__ ebufA,
                                               int* __restrict__ bcntA) {
    __shared__ int lcnt[NCB];
    int t = threadIdx.x;
    if (t < NCB) lcnt[t] = 0;
    __syncthreads();
    int mult = *flag;
    int blk = blockIdx.x;
    size_t base = (size_t)blk * 32768;
    #pragma unroll 4
    for (int u = 0; u < 64; ++u) {
        size_t e = base + (size_t)u * 512 + t;
        int s = __builtin_nontemporal_load(ei + e * mult);
        int d = __builtin_nontemporal_load(ei + ((size_t)NEDGES + e) * mult);
        int cb = d >> 16;
        int pos = atomicAdd(&lcnt[cb], 1);
        if (pos < CAPW) {
            uint2* p = (uint2*)(ebufA + ((size_t)(cb * NBLKA + blk) * CAPW + pos) * 2);
            *p = make_uint2((unsigned)s, (unsigned)d);
        }
    }
    __syncthreads();
    if (t < NCB) bcntA[t * NBLKA + blk] = lcnt[t] > CAPW ? CAPW : lcnt[t];
}

// ---------------------------------------------------------------------------
// partB single-pass: 4 blocks per cb; each consumes 128 source-block segments,
// scatters into per-(fb,q) private slots; LDS cursors.
__global__ __launch_bounds__(512) void k_partB(const unsigned* __restrict__ ebufA,
                                               const int* __restrict__ bcntA,
                                               unsigned* __restrict__ ebuf,
                                               int* __restrict__ bcntB) {
    __shared__ int lcnt[NCB];
    __shared__ int scnt[128];
    int t = threadIdx.x;
    int cb = blockIdx.x >> 2;
    int q  = blockIdx.x & 3;
    if (t < NCB) lcnt[t] = 0;
    if (t < 128) scnt[t] = bcntA[cb * NBLKA + q * 128 + t];
    __syncthreads();
    for (int b = 0; b < 128; ++b) {
        int blk = q * 128 + b;
        int n = scnt[b];
        const unsigned* seg = ebufA + (size_t)(cb * NBLKA + blk) * CAPW * 2;
        for (int k = t; k < n; k += 512) {
            uint2 e = ntl_u2(seg + (size_t)k * 2);
            int lb = (e.y >> 10) & 63;
            int pos = atomicAdd(&lcnt[lb], 1);
            if (pos < CAPQ)
                ebuf[((size_t)((cb * 64 + lb) * 4) + q) * CAPQ + pos] =
                    (e.x << 10) | (e.y & 1023u);
        }
    }
    __syncthreads();
    if (t < NCB) bcntB[(cb * 64 + t) * 4 + q] = lcnt[t] > CAPQ ? CAPQ : lcnt[t];
}

// ---------------------------------------------------------------------------
__global__ __launch_bounds__(256) void k_padx(const float* __restrict__ x,
                                              uint4* __restrict__ xb) {
    size_t q = (size_t)blockIdx.x * blockDim.x + threadIdx.x;
    if (q >= NNODES / 4) return;
    const float4* xr = (const float4*)(x + q * 28);
    float v[28];
    #pragma unroll
    for (int u = 0; u < 7; ++u) {
        float4 f = xr[u];
        v[4*u] = f.x; v[4*u+1] = f.y; v[4*u+2] = f.z; v[4*u+3] = f.w;
    }
    #pragma unroll
    for (int n = 0; n < 4; ++n) {
        unsigned short h[8];
        #pragma unroll
        for (int j = 0; j < 7; ++j) h[j] = f2bf(v[7*n + j]);
        h[7] = 0;
        uint4 o;
        o.x = (unsigned)h[0] | ((unsigned)h[1] << 16);
        o.y = (unsigned)h[2] | ((unsigned)h[3] << 16);
        o.z = (unsigned)h[4] | ((unsigned)h[5] << 16);
        o.w = (unsigned)h[6] | ((unsigned)h[7] << 16);
        xb[q * 4 + n] = o;
    }
}

// W1 (f32 [128][12288]) -> bf16
__global__ __launch_bounds__(256) void k_w1b(const float* __restrict__ W1,
                                             uint4* __restrict__ w1b) {
    size_t q = (size_t)blockIdx.x * blockDim.x + threadIdx.x;
    if (q >= (size_t)HIDD * KDIM / 8) return;
    const float4* r = (const float4*)(W1 + q * 8);
    float4 a = r[0], b = r[1];
    uint4 o;
    o.x = (unsigned)f2bf(a.x) | ((unsigned)f2bf(a.y) << 16);
    o.y = (unsigned)f2bf(a.z) | ((unsigned)f2bf(a.w) << 16);
    o.z = (unsigned)f2bf(b.x) | ((unsigned)f2bf(b.y) << 16);
    o.w = (unsigned)f2bf(b.z) | ((unsigned)f2bf(b.w) << 16);
    w1b[q] = o;
}

// ---------------------------------------------------------------------------
// conv1: in-LDS counting sort of 4 exact-count segments; register gather of xb.
__global__ __launch_bounds__(256, 4) void k_conv1(const int* __restrict__ bcntB,
                                                  const unsigned* __restrict__ ebuf,
                                                  const uint4* __restrict__ xb,
                                                  const float* __restrict__ Wrel,
                                                  const float* __restrict__ brel,
                                                  const float* __restrict__ Wroot,
                                                  uint4* __restrict__ h1p) {
    __shared__ unsigned stage[STCAP];
    __shared__ int hist[1024];
    __shared__ int offL[1024];
    __shared__ int wsum[4];
    __shared__ float sWr[FF1 * FIN], sWo[FF1 * FIN], sb[FF1];
    int t = threadIdx.x;
    if (t < FF1 * FIN) { sWr[t] = Wrel[t]; sWo[t] = Wroot[t]; }
    if (t < FF1) sb[t] = brel[t];
    int bk = blockIdx.x;
    int nq[4]; int ntot = 0;
    #pragma unroll
    for (int q = 0; q < 4; ++q) { nq[q] = bcntB[bk * 4 + q]; ntot += nq[q]; }
    for (int u = t; u < 1024; u += 256) hist[u] = 0;
    __syncthreads();
    #pragma unroll
    for (int q = 0; q < 4; ++q) {
        const unsigned* seg = ebuf + ((size_t)bk * 4 + q) * CAPQ;
        for (int k = t; k < nq[q]; k += 256)
            atomicAdd(&hist[seg[k] & 1023u], 1);
    }
    __syncthreads();
    int v[4]; int s = 0;
    #pragma unroll
    for (int u = 0; u < 4; ++u) { v[u] = hist[t * 4 + u]; s += v[u]; }
    int lane = t & 63, w = t >> 6;
    int iv = s;
    for (int o = 1; o < 64; o <<= 1) { int uu = __shfl_up(iv, o); if (lane >= o) iv += uu; }
    if (lane == 63) wsum[w] = iv;
    __syncthreads();
    int basep = 0;
    #pragma unroll
    for (int ww = 0; ww < 4; ++ww) if (ww < w) basep += wsum[ww];
    int run = basep + iv - s;
    #pragma unroll
    for (int u = 0; u < 4; ++u) {
        offL[t * 4 + u] = run;
        hist[t * 4 + u] = run;
        run += v[u];
    }
    __syncthreads();
    #pragma unroll
    for (int q = 0; q < 4; ++q) {
        const unsigned* seg = ebuf + ((size_t)bk * 4 + q) * CAPQ;
        for (int k = t; k < nq[q]; k += 256) {
            unsigned p = seg[k];
            int pos = atomicAdd(&hist[p & 1023u], 1);
            stage[pos] = p >> 10;
        }
    }
    __syncthreads();
    #pragma unroll
    for (int nn = 0; nn < 4; ++nn) {
        int li = nn * 256 + t;
        size_t i = (size_t)bk * 1024 + li;
        int beg = offL[li];
        int end = (li == 1023) ? ntot : offL[li + 1];
        float agg[FIN] = {0.f, 0.f, 0.f, 0.f, 0.f, 0.f, 0.f};
        int k = beg;
        for (; k + 3 < end; k += 4) {
            unsigned s0 = stage[k], s1 = stage[k+1], s2 = stage[k+2], s3 = stage[k+3];
            uint4 a0 = xb[s0], a1 = xb[s1], a2 = xb[s2], a3 = xb[s3];
            acc7(agg, a0); acc7(agg, a1); acc7(agg, a2); acc7(agg, a3);
        }
        for (; k < end; ++k) acc7(agg, xb[stage[k]]);
        uint4 ow = xb[i];
        float xv[FIN] = {bflo(ow.x), bfhi(ow.x), bflo(ow.y), bfhi(ow.y),
                         bflo(ow.z), bfhi(ow.z), bflo(ow.w)};
        unsigned short hh[FF1];
        #pragma unroll
        for (int j = 0; j < FF1; ++j) {
            float h = sb[j];
            #pragma unroll
            for (int q = 0; q < FIN; ++q) h += sWr[j * FIN + q] * agg[q] + sWo[j * FIN + q] * xv[q];
            hh[j] = f2bf(h);
        }
        uint4 w1, w2;
        w1.x = (unsigned)hh[0] | ((unsigned)hh[1] << 16);
        w1.y = (unsigned)hh[2] | ((unsigned)hh[3] << 16);
        w1.z = (unsigned)hh[4] | ((unsigned)hh[5] << 16);
        w1.w = (unsigned)hh[6] | ((unsigned)hh[7] << 16);
        w2.x = (unsigned)hh[8] | ((unsigned)hh[9] << 16);
        w2.y = (unsigned)hh[10]| ((unsigned)hh[11] << 16);
        w2.z = 0u; w2.w = 0u;
        nts_u4(h1p + i * 2, w1);
        nts_u4(h1p + i * 2 + 1, w2);
    }
}

// ---------------------------------------------------------------------------
template<int STRIDE>
__global__ __launch_bounds__(256) void k_statsb(const unsigned* __restrict__ hb,
                                                double* __restrict__ stats) {
    __shared__ float red[4][FF1], redq[4][FF1];
    int t = threadIdx.x;
    float ps[FF1], pq[FF1];
    #pragma unroll
    for (int j = 0; j < FF1; ++j) { ps[j] = 0.f; pq[j] = 0.f; }
    for (size_t i = (size_t)blockIdx.x * 256 + t; i < NNODES; i += 256 * 256) {
        const uint2* r = (const uint2*)(hb + i * STRIDE);
        uint2 u0 = r[0], u1 = r[1], u2 = r[2];
        float v[FF1] = {bflo(u0.x), bfhi(u0.x), bflo(u0.y), bfhi(u0.y),
                        bflo(u1.x), bfhi(u1.x), bflo(u1.y), bfhi(u1.y),
                        bflo(u2.x), bfhi(u2.x), bflo(u2.y), bfhi(u2.y)};
        #pragma unroll
        for (int j = 0; j < FF1; ++j) { ps[j] += v[j]; pq[j] += v[j] * v[j]; }
    }
    #pragma unroll
    for (int j = 0; j < FF1; ++j)
        for (int o = 1; o < 64; o <<= 1) { ps[j] += __shfl_xor(ps[j], o); pq[j] += __shfl_xor(pq[j], o); }
    int lane = t & 63, wv = t >> 6;
    if (lane == 0) {
        #pragma unroll
        for (int j = 0; j < FF1; ++j) { red[wv][j] = ps[j]; redq[wv][j] = pq[j]; }
    }
    __syncthreads();
    if (t < FF1) {
        float s = red[0][t] + red[1][t] + red[2][t] + red[3][t];
        float q = redq[0][t] + redq[1][t] + redq[2][t] + redq[3][t];
        atomicAdd(&stats[t], (double)s);
        atomicAdd(&stats[FF1 + t], (double)q);
    }
}

// ---------------------------------------------------------------------------
__global__ void k_finalize(const double* __restrict__ stats, const float* __restrict__ g,
                           const float* __restrict__ b, float* __restrict__ ss) {
    int j = threadIdx.x;
    if (j < FF1) {
        double mean = stats[j] * (1.0 / NNODES);
        double var  = stats[FF1 + j] * (1.0 / NNODES) - mean * mean;
        float sc = (float)((double)g[j] / sqrt(var + 1e-5));
        ss[j] = sc;
        ss[FF1 + j] = b[j] - (float)mean * sc;
    }
}

// ---------------------------------------------------------------------------
// conv2: same segment sort; gather h1p (32B rows), bn1+relu inline; h2 bf16 out.
__global__ __launch_bounds__(256, 4) void k_conv2(const int* __restrict__ bcntB,
                                                  const unsigned* __restrict__ ebuf,
                                                  const uint4* __restrict__ h1p,
                                                  const float* __restrict__ ss,
                                                  const float* __restrict__ Wrel,
                                                  const float* __restrict__ brel,
                                                  const float* __restrict__ Wroot,
                                                  unsigned* __restrict__ h2b) {
    __shared__ unsigned stage[STCAP];
    __shared__ int hist[1024];
    __shared__ int offL[1024];
    __shared__ int wsum[4];
    __shared__ float sWr[FF2 * FF1], sWo[FF2 * FF1], sb[FF2], sc[FF1], sh[FF1];
    int t = threadIdx.x;
    if (t < FF2 * FF1) { sWr[t] = Wrel[t]; sWo[t] = Wroot[t]; }
    if (t < FF2) { sb[t] = brel[t]; sc[t] = ss[t]; sh[t] = ss[FF1 + t]; }
    int bk = blockIdx.x;
    int nq[4]; int ntot = 0;
    #pragma unroll
    for (int q = 0; q < 4; ++q) { nq[q] = bcntB[bk * 4 + q]; ntot += nq[q]; }
    for (int u = t; u < 1024; u += 256) hist[u] = 0;
    __syncthreads();
    #pragma unroll
    for (int q = 0; q < 4; ++q) {
        const unsigned* seg = ebuf + ((size_t)bk * 4 + q) * CAPQ;
        for (int k = t; k < nq[q]; k += 256)
            atomicAdd(&hist[seg[k] & 1023u], 1);
    }
    __syncthreads();
    int v[4]; int s = 0;
    #pragma unroll
    for (int u = 0; u < 4; ++u) { v[u] = hist[t * 4 + u]; s += v[u]; }
    int lane = t & 63, w = t >> 6;
    int iv = s;
    for (int o = 1; o < 64; o <<= 1) { int uu = __shfl_up(iv, o); if (lane >= o) iv += uu; }
    if (lane == 63) wsum[w] = iv;
    __syncthreads();
    int basep = 0;
    #pragma unroll
    for (int ww = 0; ww < 4; ++ww) if (ww < w) basep += wsum[ww];
    int run = basep + iv - s;
    #pragma unroll
    for (int u = 0; u < 4; ++u) {
        offL[t * 4 + u] = run;
        hist[t * 4 + u] = run;
        run += v[u];
    }
    __syncthreads();
    #pragma unroll
    for (int q = 0; q < 4; ++q) {
        const unsigned* seg = ebuf + ((size_t)bk * 4 + q) * CAPQ;
        for (int k = t; k < nq[q]; k += 256) {
            unsigned p = seg[k];
            int pos = atomicAdd(&hist[p & 1023u], 1);
            stage[pos] = p >> 10;
        }
    }
    __syncthreads();
    #pragma unroll
    for (int nn = 0; nn < 4; ++nn) {
        int li = nn * 256 + t;
        size_t i = (size_t)bk * 1024 + li;
        int beg = offL[li];
        int end = (li == 1023) ? ntot : offL[li + 1];
        float agg[FF1];
        #pragma unroll
        for (int j = 0; j < FF1; ++j) agg[j] = 0.f;
        int k = beg;
        for (; k + 3 < end; k += 4) {
            unsigned s0 = stage[k], s1 = stage[k+1], s2 = stage[k+2], s3 = stage[k+3];
            uint4 a0 = h1p[(size_t)s0 * 2], a1 = h1p[(size_t)s0 * 2 + 1];
            uint4 b0 = h1p[(size_t)s1 * 2], b1 = h1p[(size_t)s1 * 2 + 1];
            uint4 c0 = h1p[(size_t)s2 * 2], c1 = h1p[(size_t)s2 * 2 + 1];
            uint4 d0 = h1p[(size_t)s3 * 2], d1 = h1p[(size_t)s3 * 2 + 1];
            accY(agg, sc, sh, a0, a1);
            accY(agg, sc, sh, b0, b1);
            accY(agg, sc, sh, c0, c1);
            accY(agg, sc, sh, d0, d1);
        }
        for (; k < end; ++k) {
            unsigned s0 = stage[k];
            accY(agg, sc, sh, h1p[(size_t)s0 * 2], h1p[(size_t)s0 * 2 + 1]);
        }
        uint4 o0 = h1p[i * 2], o1 = h1p[i * 2 + 1];
        float vo[FF1] = {bflo(o0.x), bfhi(o0.x), bflo(o0.y), bfhi(o0.y),
                         bflo(o0.z), bfhi(o0.z), bflo(o0.w), bfhi(o0.w),
                         bflo(o1.x), bfhi(o1.x), bflo(o1.y), bfhi(o1.y)};
        float y[FF1];
        #pragma unroll
        for (int j = 0; j < FF1; ++j) {
            float wv = vo[j] * sc[j] + sh[j];
            y[j] = wv > 0.f ? wv : 0.f;
        }
        unsigned short hh[FF2];
        #pragma unroll
        for (int j = 0; j < FF2; ++j) {
            float h = sb[j];
            #pragma unroll
            for (int q = 0; q < FF1; ++q) h += sWr[j * FF1 + q] * agg[q] + sWo[j * FF1 + q] * y[q];
            hh[j] = f2bf(h);
        }
        unsigned* p = h2b + i * 6;
        nts_u2(p,     (unsigned)hh[0] | ((unsigned)hh[1] << 16),
                      (unsigned)hh[2] | ((unsigned)hh[3] << 16));
        nts_u2(p + 2, (unsigned)hh[4] | ((unsigned)hh[5] << 16),
                      (unsigned)hh[6] | ((unsigned)hh[7] << 16));
        nts_u2(p + 4, (unsigned)hh[8] | ((unsigned)hh[9] << 16),
                      (unsigned)hh[10]| ((unsigned)hh[11] << 16));
    }
}

// ---------------------------------------------------------------------------
// GEMM1 via MFMA bf16 (unchanged from R15)
__global__ __launch_bounds__(256) void k_gemm1m(const unsigned short* __restrict__ h2b,
                                                const float* __restrict__ ss2,
                                                const unsigned short* __restrict__ w1b,
                                                float* __restrict__ hidp) {
    __shared__ float sc[FF2], sh[FF2];
    int t = threadIdx.x;
    if (t < FF2) { sc[t] = ss2[t]; sh[t] = ss2[FF2 + t]; }
    __syncthreads();
    const int KS = KDIM / 8;
    int mb = blockIdx.x;
    int ks = blockIdx.y;
    int wid = t >> 6;
    int lane = t & 63;
    int wm = wid >> 1, wn = wid & 1;
    int m0 = mb * 128 + wm * 64;
    int n0 = wn * 64;
    int lrow = lane & 15;
    int kgrp = lane >> 4;
    f32x4 acc[4][4];
    #pragma unroll
    for (int mi = 0; mi < 4; ++mi)
        #pragma unroll
        for (int ni = 0; ni < 4; ++ni) acc[mi][ni] = (f32x4)(0.f);
    int kbase = ks * KS;
    for (int k0 = 0; k0 < KS; k0 += 32) {
        int kk = kbase + k0 + kgrp * 8;
        bf16x8 af[4], bf[4];
        #pragma unroll
        for (int mi = 0; mi < 4; ++mi) {
            const unsigned short* ap = h2b + (size_t)(m0 + mi * 16 + lrow) * KDIM + kk;
            uint4 av = *(const uint4*)ap;
            unsigned hw[8] = {av.x & 0xffffu, av.x >> 16, av.y & 0xffffu, av.y >> 16,
                              av.z & 0xffffu, av.z >> 16, av.w & 0xffffu, av.w >> 16};
            int j = kk % FF2;
            bf16x8 r;
            #pragma unroll
            for (int u = 0; u < 8; ++u) {
                float f = __uint_as_float(hw[u] << 16);
                float y = f * sc[j] + sh[j];
                y = y > 0.f ? y : 0.f;
                r[u] = (short)f2bf(y);
                ++j; if (j >= FF2) j = 0;
            }
            af[mi] = r;
        }
        #pragma unroll
        for (int ni = 0; ni < 4; ++ni)
            bf[ni] = *(const bf16x8*)(w1b + (size_t)(n0 + ni * 16 + lrow) * KDIM + kk);
        #pragma unroll
        for (int mi = 0; mi < 4; ++mi)
            #pragma unroll
            for (int ni = 0; ni < 4; ++ni)
                acc[mi][ni] = __builtin_amdgcn_mfma_f32_16x16x32_bf16(
                    af[mi], bf[ni], acc[mi][ni], 0, 0, 0);
    }
    float* obase = hidp + (size_t)ks * (BATCHSZ * HIDD);
    #pragma unroll
    for (int mi = 0; mi < 4; ++mi) {
        #pragma unroll
        for (int ni = 0; ni < 4; ++ni) {
            #pragma unroll
            for (int reg = 0; reg < 4; ++reg) {
                int row = m0 + mi * 16 + kgrp * 4 + reg;
                int col = n0 + ni * 16 + lrow;
                obase[(size_t)row * HIDD + col] = acc[mi][ni][reg];
            }
        }
    }
}

__global__ __launch_bounds__(256) void k_hred(const float* __restrict__ hidp,
                                              const float* __restrict__ bl1,
                                              float* __restrict__ hid) {
    int i = blockIdx.x * 256 + threadIdx.x;
    float s = bl1[i & (HIDD - 1)];
    #pragma unroll
    for (int p = 0; p < 8; ++p) s += hidp[(size_t)p * (BATCHSZ * HIDD) + i];
    hid[i] = s > 0.f ? s : 0.f;
}

// ---------------------------------------------------------------------------
__global__ __launch_bounds__(256) void k_gemm2(const float* __restrict__ hid,
                                               const float* __restrict__ W2,
                                               const float* __restrict__ bl2,
                                               float* __restrict__ out) {
    __shared__ float As[32][128];
    __shared__ float Bs[32][128];
    int t = threadIdx.x;
    int m0 = blockIdx.x * 128;
    int n0 = blockIdx.y * 128;
    int r  = t >> 1;
    int kg = t & 1;
    int tr = t >> 4;
    int tc = t & 15;
    float acc[8][8];
    #pragma unroll
    for (int i = 0; i < 8; ++i)
        #pragma unroll
        for (int j = 0; j < 8; ++j) acc[i][j] = 0.f;

    for (int kt = 0; kt < HIDD; kt += 32) {
        int c0 = kt + 16 * kg;
        #pragma unroll
        for (int i = 0; i < 4; ++i) {
            float4 av = *(const float4*)(hid + (size_t)(m0 + r) * HIDD + c0 + 4 * i);
            As[16 * kg + 4 * i + 0][r] = av.x;
            As[16 * kg + 4 * i + 1][r] = av.y;
            As[16 * kg + 4 * i + 2][r] = av.z;
            As[16 * kg + 4 * i + 3][r] = av.w;
            float4 bv = *(const float4*)(W2 + (size_t)(n0 + r) * HIDD + c0 + 4 * i);
            Bs[16 * kg + 4 * i + 0][r] = bv.x;
            Bs[16 * kg + 4 * i + 1][r] = bv.y;
            Bs[16 * kg + 4 * i + 2][r] = bv.z;
            Bs[16 * kg + 4 * i + 3][r] = bv.w;
        }
        __syncthreads();
        #pragma unroll
        for (int k = 0; k < 32; ++k) {
            float a[8], b[8];
            *(float4*)&a[0] = *(const float4*)&As[k][8 * tr];
            *(float4*)&a[4] = *(const float4*)&As[k][8 * tr + 4];
            *(float4*)&b[0] = *(const float4*)&Bs[k][8 * tc];
            *(float4*)&b[4] = *(const float4*)&Bs[k][8 * tc + 4];
            #pragma unroll
            for (int i = 0; i < 8; ++i)
                #pragma unroll
                for (int j = 0; j < 8; ++j) acc[i][j] += a[i] * b[j];
        }
        __syncthreads();
    }
    float4 c0v = *(const float4*)(bl2 + n0 + 8 * tc);
    float4 c1v = *(const float4*)(bl2 + n0 + 8 * tc + 4);
    float bvals[8] = {c0v.x, c0v.y, c0v.z, c0v.w, c1v.x, c1v.y, c1v.z, c1v.w};
    #pragma unroll
    for (int i = 0; i < 8; ++i) {
        size_t ro = (size_t)(m0 + 8 * tr + i) * ODIM + n0 + 8 * tc;
        *(float4*)(out + ro)     = make_float4(acc[i][0] + bvals[0], acc[i][1] + bvals[1],
                                               acc[i][2] + bvals[2], acc[i][3] + bvals[3]);
        *(float4*)(out + ro + 4) = make_float4(acc[i][4] + bvals[4], acc[i][5] + bvals[5],
                                               acc[i][6] + bvals[6], acc[i][7] + bvals[7]);
    }
}

// ---------------------------------------------------------------------------
extern "C" void kernel_launch(void* const* d_in, const int* in_sizes, int n_in,
                              void* d_out, int out_size, void* d_ws, size_t ws_size,
                              hipStream_t stream) {
    const float* x      = (const float*)d_in[0];
    const int*   ei     = (const int*)d_in[1];
    const float* Wrel1  = (const float*)d_in[3];
    const float* brel1  = (const float*)d_in[4];
    const float* Wroot1 = (const float*)d_in[5];
    const float* Wrel2  = (const float*)d_in[6];
    const float* brel2  = (const float*)d_in[7];
    const float* Wroot2 = (const float*)d_in[8];
    const float* g1     = (const float*)d_in[9];
    const float* b1     = (const float*)d_in[10];
    const float* g2     = (const float*)d_in[11];
    const float* b2     = (const float*)d_in[12];
    const float* W1     = (const float*)d_in[13];
    const float* bl1    = (const float*)d_in[14];
    const float* W2     = (const float*)d_in[15];
    const float* bl2    = (const float*)d_in[16];
    float* out = (float*)d_out;
    char* ws = (char*)d_ws;

    // Layout (liveness-overlaid), ~387 MB:
    //   pY  [0, SZ_P):       xb(67MB) -> [after conv1] h2b(100MB)+hidp(16MB)+hid(2MB)
    //   E   [SZ_P, +SZ_E):   fine slots [fb][4][CAPQ] (79.7MB)
    //   pB  [.., +SZ_A):     ebufA [cb][blk][CAPW] (169.9MB) -> h1p(134MB)
    //   pK:  bcntA(128KB), bcntB(64KB), smalls, w1b(3MB)
    const size_t req = SZ_P + SZ_E + SZ_A + 262144 + SZ_W1B;
    if (ws_size < req) {
        float v = (float)(ws_size >> 20);
        k_diag<<<(out_size + 255) / 256, 256, 0, stream>>>(out, out_size, v);
        return;
    }
    char* pY = ws;
    unsigned* ebuf = (unsigned*)(ws + SZ_P);
    char* pB = ws + SZ_P + SZ_E;
    char* pK = ws + SZ_P + SZ_E + SZ_A;
    int*  bcntA = (int*)pK;                       // 64*512 ints = 128KB
    int*  bcntB = (int*)(pK + 131072);            // 4096*4 ints = 64KB
    char* smalls = pK + 131072 + 65536;
    double* st1  = (double*)smalls;
    double* st2  = st1 + 2 * FF1;
    float*  ss1  = (float*)(st2 + 2 * FF2);
    float*  ss2  = ss1 + 2 * FF1;
    int*    flag = (int*)(ss2 + 2 * FF2);
    uint4*  w1b  = (uint4*)(pK + 131072 + 65536 + 4096);

    uint4*    xb    = (uint4*)pY;
    unsigned* h2b   = (unsigned*)pY;
    float*    hidp  = (float*)(pY + SZ_HB);
    float*    hid   = (float*)(pY + SZ_HB + 8 * SZ_HID);
    unsigned* ebufA = (unsigned*)pB;
    uint4*    h1p   = (uint4*)pB;

    hipMemsetAsync(smalls, 0, 1024, stream);
    k_init  <<<1, 256, 0, stream>>>(ei, flag);
    k_padx  <<<NNODES / 4 / 256, 256, 0, stream>>>(x, xb);
    k_w1b   <<<HIDD * KDIM / 8 / 256, 256, 0, stream>>>(W1, w1b);
    k_partA <<<NBLKA, 512, 0, stream>>>(ei, flag, ebufA, bcntA);
    k_partB <<<NCB * 4, 512, 0, stream>>>(ebufA, bcntA, ebuf, bcntB);
    k_conv1 <<<NBKT, 256, 0, stream>>>(bcntB, ebuf, xb, Wrel1, brel1, Wroot1, h1p);
    k_statsb<8><<<256, 256, 0, stream>>>((const unsigned*)h1p, st1);
    k_finalize<<<1, 64, 0, stream>>>(st1, g1, b1, ss1);
    k_conv2 <<<NBKT, 256, 0, stream>>>(bcntB, ebuf, h1p, ss1, Wrel2, brel2, Wroot2, h2b);
    k_statsb<6><<<256, 256, 0, stream>>>(h2b, st2);
    k_finalize<<<1, 64, 0, stream>>>(st2, g2, b2, ss2);
    k_gemm1m<<<dim3(BATCHSZ / 128, 8), 256, 0, stream>>>((const unsigned short*)h2b, ss2,
                                                         (const unsigned short*)w1b, hidp);
    k_hred <<<BATCHSZ * HIDD / 256, 256, 0, stream>>>(hidp, bl1, hid);
    k_gemm2<<<dim3(BATCHSZ / 128, ODIM / 128), 256, 0, stream>>>(hid, W2, bl2, out);
}